// Round 2
// baseline (1100.600 us; speedup 1.0000x reference)
//
#include <hip/hip_runtime.h>
#include <math.h>

#define D 64
#define LOG2E 1.44269504088896340736f
#define QSCALE (0.35355339059327373f * LOG2E)

typedef float f32x4 __attribute__((ext_vector_type(4)));
typedef float vf4 __attribute__((ext_vector_type(4)));
typedef short bf16x8 __attribute__((ext_vector_type(8)));
typedef unsigned short ushort_t;

#define MF(a, b, c) __builtin_amdgcn_mfma_f32_16x16x32_bf16(a, b, c, 0, 0, 0)

// ---------- helpers ----------
__device__ __forceinline__ float bcast(float x, int i) {
  return __int_as_float(__builtin_amdgcn_readlane(__float_as_int(x), i));
}
__device__ __forceinline__ float qsum(float x) {  // sum over the 4 quads (lanes lo, lo+16, lo+32, lo+48)
  x += __shfl_xor(x, 16);
  x += __shfl_xor(x, 32);
  return x;
}
__device__ __forceinline__ ushort_t f2b(float f) {  // fp32 -> bf16 RTNE
  unsigned int u = __float_as_uint(f);
  unsigned int r = (u + 0x7FFFu + ((u >> 16) & 1u)) >> 16;
  return (ushort_t)r;
}
__device__ __forceinline__ float b2f(short s) {  // bf16 -> fp32
  return __uint_as_float(((unsigned int)(unsigned short)s) << 16);
}
__device__ __forceinline__ f32x4 ld4(const float* __restrict__ p) { return *(const f32x4*)p; }
// monotonic unsigned key encoding for float atomicMax
__device__ __forceinline__ unsigned int fkey(float f) {
  unsigned int b = __float_as_uint(f);
  return (b & 0x80000000u) ? ~b : (b | 0x80000000u);
}
__device__ __forceinline__ float funkey(unsigned int k) {
  return __uint_as_float((k & 0x80000000u) ? (k ^ 0x80000000u) : ~k);
}
// pack two C-tiles (even ct, odd ct) into one x32 B-operand pair
__device__ __forceinline__ bf16x8 mkpair(const f32x4& ce, const f32x4& co) {
  bf16x8 b;
#pragma unroll
  for (int j = 0; j < 4; j++) {
    b[j] = (short)f2b(ce[j]);
    b[4 + j] = (short)f2b(co[j]);
  }
  return b;
}
__device__ __forceinline__ f32x4 unpk(bf16x8 p, int half) {  // half 0 = even ct, 1 = odd ct
  f32x4 r;
#pragma unroll
  for (int j = 0; j < 4; j++) r[j] = b2f(p[half * 4 + j]);
  return r;
}

// transposed-layout LayerNorm: x,y are 16 channel values/lane (4 ct-tiles x 4 rr); stats over 64 ch
__device__ __forceinline__ void lnT(const f32x4 (&x)[4], f32x4 (&y)[4],
                                    const float* __restrict__ g, const float* __restrict__ b,
                                    int quad) {
  float s1 = 0.f, s2 = 0.f;
#pragma unroll
  for (int ct = 0; ct < 4; ct++)
#pragma unroll
    for (int r = 0; r < 4; r++) { s1 += x[ct][r]; s2 += x[ct][r] * x[ct][r]; }
  s1 = qsum(s1);
  s2 = qsum(s2);
  float mean = s1 * 0.015625f;
  float var = s2 * 0.015625f - mean * mean;
  float rs = rsqrtf(var + 1e-5f);
#pragma unroll
  for (int ct = 0; ct < 4; ct++) {
    f32x4 gv = ld4(g + 16 * ct + 4 * quad);
    f32x4 bv = ld4(b + 16 * ct + 4 * quad);
#pragma unroll
    for (int r = 0; r < 4; r++) y[ct][r] = (x[ct][r] - mean) * rs * gv[r] + bv[r];
  }
}

// ---------- zero fill ----------
__global__ void zero_kernel(float4* __restrict__ p, int n4) {
  int t = blockIdx.x * blockDim.x + threadIdx.x;
  if (t < n4) p[t] = make_float4(0.f, 0.f, 0.f, 0.f);
}

// ---------- prep: pack weights as x32 A-frags with the k-slot permutation ----------
// ws float layout: [0..32767] T_iw fp32 (k4-packed, head_transform); [32768..33279] u[8][64];
// (ws+33280) as ushort: A-frag packs:
//   SI@0 SO@12288 W1S@16384 W2S@32768 CI@49152 CO@61440 W1C@65536 W2C@81920 (end 98304)
// For W[Cout][K]: frag = ct*T + t (ct = c>>4, T = K/32, t = k>>5); within frag:
//   lane = quad*16 + m (m = c&15, quad = (k>>2)&3), j = 4*((k>>4)&1) + (k&3)
//   (so A k-slot(quad,j) <-> channel 32t + 16*(j>>2) + 4*quad + (j&3), matching the B pairs)
__global__ void prep_kernel(const float* __restrict__ si, const float* __restrict__ so,
                            const float* __restrict__ w1s, const float* __restrict__ w2s,
                            const float* __restrict__ ci, const float* __restrict__ co,
                            const float* __restrict__ w1c, const float* __restrict__ w2c,
                            const float* __restrict__ iw, const float* __restrict__ av,
                            float* __restrict__ ws) {
  int t = blockIdx.x * blockDim.x + threadIdx.x;
  ushort_t* bw = (ushort_t*)(ws + 33280);
  if (t < 98304) {
    const float* src;
    int base, cs;
    int l = t;
    if      (l < 12288) { src = si;  base = 0;     cs = 6; }
    else if (l < 16384) { src = so;  base = 12288; cs = 6; l -= 12288; }
    else if (l < 32768) { src = w1s; base = 16384; cs = 6; l -= 16384; }
    else if (l < 49152) { src = w2s; base = 32768; cs = 8; l -= 32768; }
    else if (l < 61440) { src = ci;  base = 49152; cs = 6; l -= 49152; }
    else if (l < 65536) { src = co;  base = 61440; cs = 6; l -= 61440; }
    else if (l < 81920) { src = w1c; base = 65536; cs = 6; l -= 65536; }
    else                { src = w2c; base = 81920; cs = 8; l -= 81920; }
    int c = l >> cs, k = l & ((1 << cs) - 1);
    int T = (1 << cs) >> 5;
    int ct = c >> 4, m = c & 15, tt = k >> 5, rem = k & 31;
    int quad = (rem >> 2) & 3;
    int j = (((rem >> 4) & 1) << 2) | (rem & 3);
    bw[base + (size_t)((ct * T + tt) * 64 + quad * 16 + m) * 8 + j] = f2b(src[l]);
  } else if (t < 131072) {
    int l = t - 98304;  // T_iw fp32 k-packed: c 0..511, k 0..63 (for head_transform)
    int c = l >> 6, k = l & 63;
    ws[(k >> 2) * 2048 + c * 4 + (k & 3)] = iw[l];
  } else if (t < 131584) {
    int l = t - 131072;
    int h = l >> 6, k = l & 63;
    float acc = 0.f;
    for (int c = 0; c < 64; c++) acc += av[h * 64 + c] * iw[(h * 64 + c) * 64 + k];
    ws[32768 + h * 64 + k] = acc;
  }
}

// ---------- transposed FF block: inst (f32, [ch][edge] tiles) += FF(LN(inst)) ----------
__device__ __forceinline__ void ffnT(f32x4 (&inst)[4],
                                     const float* __restrict__ g, const float* __restrict__ b,
                                     const bf16x8* __restrict__ W1, const bf16x8* __restrict__ W2,
                                     const float* __restrict__ b1, const float* __restrict__ b2,
                                     int lane, int quad) {
  f32x4 y[4];
  lnT(inst, y, g, b, quad);
  bf16x8 x0 = mkpair(y[0], y[1]), x1 = mkpair(y[2], y[3]);
  bf16x8 Hp[8];
#pragma unroll
  for (int ht = 0; ht < 8; ht++) {
    f32x4 h[2];
#pragma unroll
    for (int u = 0; u < 2; u++) {
      int ct = 2 * ht + u;
      f32x4 c = {0.f, 0.f, 0.f, 0.f};
      c = MF(W1[(ct * 2 + 0) * 64 + lane], x0, c);
      c = MF(W1[(ct * 2 + 1) * 64 + lane], x1, c);
      f32x4 bb = ld4(b1 + 16 * ct + 4 * quad);
#pragma unroll
      for (int r = 0; r < 4; r++) {
        float v = c[r] + bb[r];
        h[u][r] = 0.5f * v * (1.0f + erff(v * 0.70710678118654752440f));
      }
    }
    Hp[ht] = mkpair(h[0], h[1]);
  }
#pragma unroll
  for (int ct = 0; ct < 4; ct++) {
    f32x4 c = {0.f, 0.f, 0.f, 0.f};
#pragma unroll
    for (int t = 0; t < 8; t++) c = MF(W2[(ct * 8 + t) * 64 + lane], Hp[t], c);
    f32x4 bb = ld4(b2 + 16 * ct + 4 * quad);
#pragma unroll
    for (int r = 0; r < 4; r++) inst[ct][r] += c[r] + bb[r];
  }
}

// ---------- per-edge transformer: one wave = 16 edges ----------
// Register-pressure restructure vs previous version:
//  * XL[5][2] eliminated — LN'd input recomputed per use (gather hits L1/L2 on re-read)
//  * TP[5][2] lives in LDS (each lane only touches its own 16B slots; contiguous b128 = no conflicts)
//  => peak live regs fits the 256-VGPR budget of launch_bounds(64,2); no scratch spills.
__global__ __launch_bounds__(64, 2)
void edge_kernel(const float* __restrict__ features, const float* __restrict__ pos_emb,
                 const float* __restrict__ self_in_b, const float* __restrict__ self_out_b,
                 const float* __restrict__ cross_in_b, const float* __restrict__ cross_out_b,
                 const float* __restrict__ sa_ln1_g, const float* __restrict__ sa_ln1_b,
                 const float* __restrict__ sa_ln2_g, const float* __restrict__ sa_ln2_b,
                 const float* __restrict__ ca_ln1_g, const float* __restrict__ ca_ln1_b,
                 const float* __restrict__ ca_ln2_g, const float* __restrict__ ca_ln2_b,
                 const float* __restrict__ sa_ff_b1, const float* __restrict__ sa_ff_b2,
                 const float* __restrict__ ca_ff_b1, const float* __restrict__ ca_ff_b2,
                 const int* __restrict__ midx, const int* __restrict__ dstv,
                 const float* __restrict__ ws,
                 float* __restrict__ inst_out, float* __restrict__ a_out,
                 unsigned int* __restrict__ seg_max, int E, int N) {
  const int lane = threadIdx.x;
  const int quad = lane >> 4, lo = lane & 15;
  const int e0 = blockIdx.x * 16;
  // 10240 B: holds TP pairs [5][2][64 lanes] as bf16x8; reused for the output transpose (4352 B)
  __shared__ __align__(16) ushort_t smem[5120];
  bf16x8* tpS = (bf16x8*)smem;
  float* xp = (float*)smem;

  const ushort_t* bw = (const ushort_t*)(ws + 33280);
  const bf16x8* WSI = (const bf16x8*)(bw);
  const bf16x8* WSO = (const bf16x8*)(bw + 12288);
  const bf16x8* W1S = (const bf16x8*)(bw + 16384);
  const bf16x8* W2S = (const bf16x8*)(bw + 32768);
  const bf16x8* WCI = (const bf16x8*)(bw + 49152);
  const bf16x8* WCO = (const bf16x8*)(bw + 61440);
  const bf16x8* W1C = (const bf16x8*)(bw + 65536);
  const bf16x8* W2C = (const bf16x8*)(bw + 81920);
  const float* uvec = ws + 32768;

  // per-lane edge meta: lane (quad, lo) owns edge e0+lo (replicated across quads)
  const bool ge = (e0 + lo) < E;
  const int eIdx = min(e0 + lo, E - 1);
  int ids[5];
#pragma unroll
  for (int s = 0; s < 5; s++) ids[s] = midx[eIdx * 5 + s];
  int vb = 0;
#pragma unroll
  for (int s = 0; s < 5; s++)
    if (ids[s] != N && ge) vb |= (1 << s);
  const int nv = __popc(vb);
  const int lp = max(nv - 1, 0);
  int lid = ids[0];
#pragma unroll
  for (int s = 1; s < 5; s++) lid = (lp == s) ? ids[s] : lid;

  // ---- stage A: per s: gather + pos + LN -> xl (transient); K,V GEMMs ----
  bf16x8 Kp[5][2], Vp[5][2];
#pragma unroll
  for (int s = 0; s < 5; s++) {
    f32x4 t[4], y[4];
    const bool vd = (vb >> s) & 1;
    const float* fp = features + (size_t)min(ids[s], N - 1) * 64;
#pragma unroll
    for (int ct = 0; ct < 4; ct++) {
      f32x4 f = ld4(fp + 16 * ct + 4 * quad);
      f32x4 pv = ld4(pos_emb + s * 64 + 16 * ct + 4 * quad);
#pragma unroll
      for (int r = 0; r < 4; r++) t[ct][r] = vd ? (f[r] + pv[r]) : 0.f;
    }
    lnT(t, y, sa_ln1_g, sa_ln1_b, quad);
    bf16x8 xl0 = mkpair(y[0], y[1]), xl1 = mkpair(y[2], y[3]);
    f32x4 kt[4], vt[4];
#pragma unroll
    for (int ct = 0; ct < 4; ct++) {
      f32x4 c = {0.f, 0.f, 0.f, 0.f};
      c = MF(WSI[((4 + ct) * 2 + 0) * 64 + lane], xl0, c);
      c = MF(WSI[((4 + ct) * 2 + 1) * 64 + lane], xl1, c);
      f32x4 bb = ld4(self_in_b + 64 + 16 * ct + 4 * quad);
#pragma unroll
      for (int r = 0; r < 4; r++) kt[ct][r] = c[r] + bb[r];
      f32x4 c2 = {0.f, 0.f, 0.f, 0.f};
      c2 = MF(WSI[((8 + ct) * 2 + 0) * 64 + lane], xl0, c2);
      c2 = MF(WSI[((8 + ct) * 2 + 1) * 64 + lane], xl1, c2);
      f32x4 bb2 = ld4(self_in_b + 128 + 16 * ct + 4 * quad);
#pragma unroll
      for (int r = 0; r < 4; r++) vt[ct][r] = c2[r] + bb2[r];
    }
    Kp[s][0] = mkpair(kt[0], kt[1]);
    Kp[s][1] = mkpair(kt[2], kt[3]);
    Vp[s][0] = mkpair(vt[0], vt[1]);
    Vp[s][1] = mkpair(vt[2], vt[3]);
  }

  // ---- stage B per qs: regather+LN -> Q GEMM, attention, PV, out-proj, residual, pool, TP->LDS ----
  f32x4 pool[4];
#pragma unroll
  for (int ct = 0; ct < 4; ct++) pool[ct] = (f32x4){0.f, 0.f, 0.f, 0.f};
#pragma unroll
  for (int qs = 0; qs < 5; qs++) {
    const bool vd = (vb >> qs) & 1;
    const float* fp = features + (size_t)min(ids[qs], N - 1) * 64;
    f32x4 t[4], y[4];
#pragma unroll
    for (int ct = 0; ct < 4; ct++) {
      f32x4 f = ld4(fp + 16 * ct + 4 * quad);
      f32x4 pv = ld4(pos_emb + qs * 64 + 16 * ct + 4 * quad);
#pragma unroll
      for (int r = 0; r < 4; r++) t[ct][r] = vd ? (f[r] + pv[r]) : 0.f;
    }
    lnT(t, y, sa_ln1_g, sa_ln1_b, quad);
    bf16x8 xl0 = mkpair(y[0], y[1]), xl1 = mkpair(y[2], y[3]);
    f32x4 qf[4];
#pragma unroll
    for (int ct = 0; ct < 4; ct++) {
      f32x4 c = {0.f, 0.f, 0.f, 0.f};
      c = MF(WSI[(ct * 2 + 0) * 64 + lane], xl0, c);
      c = MF(WSI[(ct * 2 + 1) * 64 + lane], xl1, c);
      f32x4 bb = ld4(self_in_b + 16 * ct + 4 * quad);
#pragma unroll
      for (int r = 0; r < 4; r++) qf[ct][r] = (c[r] + bb[r]) * QSCALE;
    }
    // head h = 2ct + (quad>>1): dot over this lane's 4 ch + partner quad via shfl_xor(16)
    float sc[4][5];
#pragma unroll
    for (int ct = 0; ct < 4; ct++) {
      float mx = -3.0e30f;
#pragma unroll
      for (int ks = 0; ks < 5; ks++) {
        f32x4 kv = unpk(Kp[ks][ct >> 1], ct & 1);
        float sp = qf[ct][0] * kv[0] + qf[ct][1] * kv[1] + qf[ct][2] * kv[2] + qf[ct][3] * kv[3];
        sp += __shfl_xor(sp, 16);
        float sv = ((vb >> ks) & 1) ? sp : -1e30f;
        sc[ct][ks] = sv;
        mx = fmaxf(mx, sv);
      }
      float sum = 0.f;
#pragma unroll
      for (int ks = 0; ks < 5; ks++) { sc[ct][ks] = exp2f(sc[ct][ks] - mx); sum += sc[ct][ks]; }
      float ri = 1.0f / sum;
#pragma unroll
      for (int ks = 0; ks < 5; ks++) sc[ct][ks] *= ri;
    }
    f32x4 o[4];
#pragma unroll
    for (int ct = 0; ct < 4; ct++) {
      o[ct] = (f32x4){0.f, 0.f, 0.f, 0.f};
#pragma unroll
      for (int ks = 0; ks < 5; ks++) {
        f32x4 vv = unpk(Vp[ks][ct >> 1], ct & 1);
#pragma unroll
        for (int r = 0; r < 4; r++) o[ct][r] = fmaf(sc[ct][ks], vv[r], o[ct][r]);
      }
    }
    bf16x8 o0 = mkpair(o[0], o[1]), o1 = mkpair(o[2], o[3]);
    // out-proj + residual (t already holds masked tok) + masked pool; tokPost -> TP pairs in LDS
    f32x4 tpc[4];
#pragma unroll
    for (int ct = 0; ct < 4; ct++) {
      f32x4 c = {0.f, 0.f, 0.f, 0.f};
      c = MF(WSO[(ct * 2 + 0) * 64 + lane], o0, c);
      c = MF(WSO[(ct * 2 + 1) * 64 + lane], o1, c);
      f32x4 bb = ld4(self_out_b + 16 * ct + 4 * quad);
#pragma unroll
      for (int r = 0; r < 4; r++) {
        float tp = c[r] + bb[r] + t[ct][r];
        tpc[ct][r] = tp;
        pool[ct][r] += vd ? tp : 0.f;
      }
    }
    tpS[(qs * 2 + 0) * 64 + lane] = mkpair(tpc[0], tpc[1]);
    tpS[(qs * 2 + 1) * 64 + lane] = mkpair(tpc[2], tpc[3]);
  }

  f32x4 inst[4];
  {
    float rn = 1.0f / (float)max(nv, 1);
#pragma unroll
    for (int ct = 0; ct < 4; ct++)
#pragma unroll
      for (int r = 0; r < 4; r++) inst[ct][r] = pool[ct][r] * rn;
  }

  // ---- FF-sa ----
  ffnT(inst, sa_ln2_g, sa_ln2_b, W1S, W2S, sa_ff_b1, sa_ff_b2, lane, quad);

  // ---- cross attention (TP pairs read back from LDS: each lane reads only its own slots) ----
  {
    f32x4 tf[4], xq[4];
    const bool vdl = lid != N;
    const float* fp = features + (size_t)min(lid, N - 1) * 64;
#pragma unroll
    for (int ct = 0; ct < 4; ct++) {
      f32x4 f = ld4(fp + 16 * ct + 4 * quad);
#pragma unroll
      for (int r = 0; r < 4; r++) tf[ct][r] = vdl ? f[r] : 0.f;
    }
    lnT(tf, xq, ca_ln1_g, ca_ln1_b, quad);
    bf16x8 xq0 = mkpair(xq[0], xq[1]), xq1 = mkpair(xq[2], xq[3]);
    f32x4 qcf[4];
#pragma unroll
    for (int ct = 0; ct < 4; ct++) {
      f32x4 c = {0.f, 0.f, 0.f, 0.f};
      c = MF(WCI[(ct * 2 + 0) * 64 + lane], xq0, c);
      c = MF(WCI[(ct * 2 + 1) * 64 + lane], xq1, c);
      f32x4 bb = ld4(cross_in_b + 16 * ct + 4 * quad);
#pragma unroll
      for (int r = 0; r < 4; r++) qcf[ct][r] = (c[r] + bb[r]) * QSCALE;
    }
    bf16x8 Kc[5][2], Vc[5][2];
#pragma unroll
    for (int s = 0; s < 5; s++) {
      bf16x8 tq0 = tpS[(s * 2 + 0) * 64 + lane];
      bf16x8 tq1 = tpS[(s * 2 + 1) * 64 + lane];
      f32x4 kt[4], vt[4];
#pragma unroll
      for (int ct = 0; ct < 4; ct++) {
        f32x4 c = {0.f, 0.f, 0.f, 0.f};
        c = MF(WCI[((4 + ct) * 2 + 0) * 64 + lane], tq0, c);
        c = MF(WCI[((4 + ct) * 2 + 1) * 64 + lane], tq1, c);
        f32x4 bb = ld4(cross_in_b + 64 + 16 * ct + 4 * quad);
#pragma unroll
        for (int r = 0; r < 4; r++) kt[ct][r] = c[r] + bb[r];
        f32x4 c2 = {0.f, 0.f, 0.f, 0.f};
        c2 = MF(WCI[((8 + ct) * 2 + 0) * 64 + lane], tq0, c2);
        c2 = MF(WCI[((8 + ct) * 2 + 1) * 64 + lane], tq1, c2);
        f32x4 bb2 = ld4(cross_in_b + 128 + 16 * ct + 4 * quad);
#pragma unroll
        for (int r = 0; r < 4; r++) vt[ct][r] = c2[r] + bb2[r];
      }
      Kc[s][0] = mkpair(kt[0], kt[1]);
      Kc[s][1] = mkpair(kt[2], kt[3]);
      Vc[s][0] = mkpair(vt[0], vt[1]);
      Vc[s][1] = mkpair(vt[2], vt[3]);
    }
    float sc[4][5];
#pragma unroll
    for (int ct = 0; ct < 4; ct++) {
      float mx = -3.0e30f;
#pragma unroll
      for (int ks = 0; ks < 5; ks++) {
        f32x4 kv = unpk(Kc[ks][ct >> 1], ct & 1);
        float sp = qcf[ct][0] * kv[0] + qcf[ct][1] * kv[1] + qcf[ct][2] * kv[2] + qcf[ct][3] * kv[3];
        sp += __shfl_xor(sp, 16);
        float sv = ((vb >> ks) & 1) ? sp : -1e30f;
        sc[ct][ks] = sv;
        mx = fmaxf(mx, sv);
      }
      float sum = 0.f;
#pragma unroll
      for (int ks = 0; ks < 5; ks++) { sc[ct][ks] = exp2f(sc[ct][ks] - mx); sum += sc[ct][ks]; }
      float ri = 1.0f / sum;
#pragma unroll
      for (int ks = 0; ks < 5; ks++) sc[ct][ks] *= ri;
    }
    f32x4 co[4];
#pragma unroll
    for (int ct = 0; ct < 4; ct++) {
      co[ct] = (f32x4){0.f, 0.f, 0.f, 0.f};
#pragma unroll
      for (int ks = 0; ks < 5; ks++) {
        f32x4 vv = unpk(Vc[ks][ct >> 1], ct & 1);
#pragma unroll
        for (int r = 0; r < 4; r++) co[ct][r] = fmaf(sc[ct][ks], vv[r], co[ct][r]);
      }
    }
    bf16x8 c0 = mkpair(co[0], co[1]), c1 = mkpair(co[2], co[3]);
#pragma unroll
    for (int ct = 0; ct < 4; ct++) {
      f32x4 c = {0.f, 0.f, 0.f, 0.f};
      c = MF(WCO[(ct * 2 + 0) * 64 + lane], c0, c);
      c = MF(WCO[(ct * 2 + 1) * 64 + lane], c1, c);
      f32x4 bb = ld4(cross_out_b + 16 * ct + 4 * quad);
#pragma unroll
      for (int r = 0; r < 4; r++) inst[ct][r] += c[r] + bb[r];
    }
  }

  // ---- FF-ca ----
  ffnT(inst, ca_ln2_g, ca_ln2_b, W1C, W2C, ca_ff_b1, ca_ff_b2, lane, quad);

  // ---- a-scores: a[e][h] = leakyrelu(inst . u_h) ----
  float a8[8];
#pragma unroll
  for (int h = 0; h < 8; h++) {
    float sp = 0.f;
#pragma unroll
    for (int ct = 0; ct < 4; ct++) {
      f32x4 uu = ld4(uvec + h * 64 + 16 * ct + 4 * quad);
#pragma unroll
      for (int r = 0; r < 4; r++) sp = fmaf(inst[ct][r], uu[r], sp);
    }
    sp = qsum(sp);
    a8[h] = sp > 0.f ? sp : 0.01f * sp;
  }
  if (ge) {
    int dd = dstv[e0 + lo];
    float v0 = quad == 0 ? a8[0] : quad == 1 ? a8[2] : quad == 2 ? a8[4] : a8[6];
    float v1 = quad == 0 ? a8[1] : quad == 1 ? a8[3] : quad == 2 ? a8[5] : a8[7];
    atomicMax(&seg_max[dd * 8 + 2 * quad], fkey(v0));
    atomicMax(&seg_max[dd * 8 + 2 * quad + 1], fkey(v1));
    if (quad < 2) {
      f32x4 st = (quad == 0) ? (f32x4){a8[0], a8[1], a8[2], a8[3]}
                             : (f32x4){a8[4], a8[5], a8[6], a8[7]};
      *(f32x4*)(a_out + (size_t)(e0 + lo) * 8 + 4 * quad) = st;
    }
  }

  // ---- inst_out: small LDS transpose ([ch][edge] -> [edge][ch]) + coalesced store ----
  __syncthreads();  // TP reads done; safe to reuse smem as xp
#pragma unroll
  for (int ct = 0; ct < 4; ct++)
    *(f32x4*)(&xp[lo * 68 + 16 * ct + 4 * quad]) = inst[ct];
  __syncthreads();
  {
    int er = lane >> 2, cb = (lane & 3) * 16;
    if (e0 + er < E) {
#pragma unroll
      for (int u = 0; u < 4; u++) {
        f32x4 v = *(const f32x4*)(&xp[er * 68 + cb + 4 * u]);
        *(f32x4*)(inst_out + (size_t)(e0 + er) * 64 + cb + 4 * u) = v;
      }
    }
  }
}

// ---------- edge softmax denominator ----------
__global__ void expsum_kernel(const float* __restrict__ a, const int* __restrict__ dstv,
                              const unsigned int* __restrict__ seg_max,
                              float* __restrict__ seg_sum, int E8) {
  int t = blockIdx.x * blockDim.x + threadIdx.x;
  if (t >= E8) return;
  int e = t >> 3, h = t & 7;
  int dd = dstv[e];
  float m = funkey(seg_max[dd * 8 + h]);
  atomicAdd(&seg_sum[dd * 8 + h], __expf(a[t] - m));
}

// ---------- scatter att-weighted inst_emb into z = d_out ----------
__global__ __launch_bounds__(256)
void scatter_kernel(const float* __restrict__ inst_emb, const float* __restrict__ a,
                    const unsigned int* __restrict__ seg_max, const float* __restrict__ seg_sum,
                    const int* __restrict__ dstv, float* __restrict__ out, int E) {
  const int wid = (blockIdx.x * blockDim.x + threadIdx.x) >> 6;
  const int lane = threadIdx.x & 63;
  if (wid >= E) return;
  int dd = dstv[wid];
  float iv = inst_emb[(size_t)wid * D + lane];
#pragma unroll
  for (int h = 0; h < 8; h++) {
    float m = funkey(seg_max[dd * 8 + h]);
    float s = seg_sum[dd * 8 + h];
    float att = __expf(a[wid * 8 + h] - m) / s;
    atomicAdd(&out[(size_t)dd * 512 + h * 64 + lane], att * iv);
  }
}

// ---------- in-place per-(n,h) transform: row = inst_w_h @ row, 4 nodes per wave ----------
__global__ __launch_bounds__(256)
void head_transform_kernel(const float* __restrict__ T_iw, float* __restrict__ out, int N) {
  const int wid = (blockIdx.x * blockDim.x + threadIdx.x) >> 6;
  const int lane = threadIdx.x & 63;
  const int h = wid & 7;
  const int n0 = (wid >> 3) * 4;
  if (n0 >= N) return;
  float z[4], acc[4];
#pragma unroll
  for (int j = 0; j < 4; j++) {
    z[j] = (n0 + j < N) ? out[((size_t)(n0 + j) * 8 + h) * D + lane] : 0.f;
    acc[j] = 0.f;
  }
  const vf4* P = (const vf4*)T_iw;
  for (int k4 = 0; k4 < 16; k4++) {
    vf4 w = P[k4 * 512 + h * 64 + lane];
#pragma unroll
    for (int u = 0; u < 4; u++) {
      int i = k4 * 4 + u;
#pragma unroll
      for (int j = 0; j < 4; j++) acc[j] = fmaf(bcast(z[j], i), w[u], acc[j]);
    }
  }
#pragma unroll
  for (int j = 0; j < 4; j++)
    if (n0 + j < N) out[((size_t)(n0 + j) * 8 + h) * D + lane] = acc[j];
}

extern "C" void kernel_launch(void* const* d_in, const int* in_sizes, int n_in,
                              void* d_out, int out_size, void* d_ws, size_t ws_size,
                              hipStream_t stream) {
  const float* features   = (const float*)d_in[0];
  const float* pos_emb    = (const float*)d_in[1];
  const float* self_in_w  = (const float*)d_in[2];
  const float* self_in_b  = (const float*)d_in[3];
  const float* self_out_w = (const float*)d_in[4];
  const float* self_out_b = (const float*)d_in[5];
  const float* cross_in_w = (const float*)d_in[6];
  const float* cross_in_b = (const float*)d_in[7];
  const float* cross_out_w= (const float*)d_in[8];
  const float* cross_out_b= (const float*)d_in[9];
  const float* sa_ln1_g = (const float*)d_in[10];
  const float* sa_ln1_b = (const float*)d_in[11];
  const float* sa_ln2_g = (const float*)d_in[12];
  const float* sa_ln2_b = (const float*)d_in[13];
  const float* ca_ln1_g = (const float*)d_in[14];
  const float* ca_ln1_b = (const float*)d_in[15];
  const float* ca_ln2_g = (const float*)d_in[16];
  const float* ca_ln2_b = (const float*)d_in[17];
  const float* sa_ff_w1 = (const float*)d_in[18];
  const float* sa_ff_b1 = (const float*)d_in[19];
  const float* sa_ff_w2 = (const float*)d_in[20];
  const float* sa_ff_b2 = (const float*)d_in[21];
  const float* ca_ff_w1 = (const float*)d_in[22];
  const float* ca_ff_b1 = (const float*)d_in[23];
  const float* ca_ff_w2 = (const float*)d_in[24];
  const float* ca_ff_b2 = (const float*)d_in[25];
  const float* inst_w   = (const float*)d_in[26];
  const float* attn_vec = (const float*)d_in[27];
  const int* midx = (const int*)d_in[28];
  const int* dstv = (const int*)d_in[29];

  const int N = in_sizes[0] / 64;
  const int E = in_sizes[29];

  // ws floats: [0..32767] T_iw | [32768..33279] u | [33280..82431] bf16 A-frag packs
  //            [131072...] inst_emb[E*64] | a[E*8] | seg_max[N*8] | seg_sum[N*8]
  float* wsf = (float*)d_ws;
  float* inst_emb = wsf + 131072;
  float* a_arr = inst_emb + (size_t)E * 64;
  unsigned int* seg_max = (unsigned int*)(a_arr + (size_t)E * 8);
  float* seg_sum = (float*)(seg_max + (size_t)N * 8);

  {
    int n4 = out_size / 4;
    zero_kernel<<<(n4 + 255) / 256, 256, 0, stream>>>((float4*)d_out, n4);
    int s4 = (N * 16) / 4;  // seg_max + seg_sum contiguous
    zero_kernel<<<(s4 + 255) / 256, 256, 0, stream>>>((float4*)seg_max, s4);
  }

  prep_kernel<<<(131584 + 255) / 256, 256, 0, stream>>>(
      self_in_w, self_out_w, sa_ff_w1, sa_ff_w2, cross_in_w, cross_out_w, ca_ff_w1, ca_ff_w2,
      inst_w, attn_vec, wsf);

  int nblk = (E + 15) / 16;  // 1 wave/block, 16 edges/wave
  edge_kernel<<<nblk, 64, 0, stream>>>(
      features, pos_emb, self_in_b, self_out_b, cross_in_b, cross_out_b, sa_ln1_g, sa_ln1_b,
      sa_ln2_g, sa_ln2_b, ca_ln1_g, ca_ln1_b, ca_ln2_g, ca_ln2_b, sa_ff_b1, sa_ff_b2, ca_ff_b1,
      ca_ff_b2, midx, dstv, wsf, inst_emb, a_arr, seg_max, E, N);

  expsum_kernel<<<(E * 8 + 255) / 256, 256, 0, stream>>>(a_arr, dstv, seg_max, seg_sum, E * 8);

  scatter_kernel<<<(E + 3) / 4, 256, 0, stream>>>(inst_emb, a_arr, seg_max, seg_sum, dstv,
                                                  (float*)d_out, E);

  int hwave = ((N + 3) / 4) * 8;
  head_transform_kernel<<<(hwave + 3) / 4, 256, 0, stream>>>(wsf, (float*)d_out, N);
}

// Round 3
// 1070.925 us; speedup vs baseline: 1.0277x; 1.0277x over previous
//
#include <hip/hip_runtime.h>
#include <math.h>

#define D 64
#define LOG2E 1.44269504088896340736f
#define QSCALE (0.35355339059327373f * LOG2E)

typedef float f32x4 __attribute__((ext_vector_type(4)));
typedef float vf4 __attribute__((ext_vector_type(4)));
typedef short bf16x8 __attribute__((ext_vector_type(8)));
typedef unsigned short ushort_t;

#define MF(a, b, c) __builtin_amdgcn_mfma_f32_16x16x32_bf16(a, b, c, 0, 0, 0)

// ---------- helpers ----------
__device__ __forceinline__ float bcast(float x, int i) {
  return __int_as_float(__builtin_amdgcn_readlane(__float_as_int(x), i));
}
__device__ __forceinline__ float qsum(float x) {  // sum over the 4 quads
  x += __shfl_xor(x, 16);
  x += __shfl_xor(x, 32);
  return x;
}
__device__ __forceinline__ ushort_t f2b(float f) {  // fp32 -> bf16 RTNE
  unsigned int u = __float_as_uint(f);
  unsigned int r = (u + 0x7FFFu + ((u >> 16) & 1u)) >> 16;
  return (ushort_t)r;
}
__device__ __forceinline__ float b2f(short s) {  // bf16 -> fp32
  return __uint_as_float(((unsigned int)(unsigned short)s) << 16);
}
__device__ __forceinline__ f32x4 ld4(const float* __restrict__ p) { return *(const f32x4*)p; }
// monotonic unsigned key encoding for float atomicMax
__device__ __forceinline__ unsigned int fkey(float f) {
  unsigned int b = __float_as_uint(f);
  return (b & 0x80000000u) ? ~b : (b | 0x80000000u);
}
__device__ __forceinline__ float funkey(unsigned int k) {
  return __uint_as_float((k & 0x80000000u) ? (k ^ 0x80000000u) : ~k);
}
// pack two C-tiles (even ct, odd ct) into one x32 B-operand pair
__device__ __forceinline__ bf16x8 mkpair(const f32x4& ce, const f32x4& co) {
  bf16x8 b;
#pragma unroll
  for (int j = 0; j < 4; j++) {
    b[j] = (short)f2b(ce[j]);
    b[4 + j] = (short)f2b(co[j]);
  }
  return b;
}
__device__ __forceinline__ f32x4 unpk(bf16x8 p, int half) {  // half 0 = even ct, 1 = odd ct
  f32x4 r;
#pragma unroll
  for (int j = 0; j < 4; j++) r[j] = b2f(p[half * 4 + j]);
  return r;
}

// transposed-layout LayerNorm: x,y are 16 channel values/lane; stats over 64 ch
__device__ __forceinline__ void lnT(const f32x4 (&x)[4], f32x4 (&y)[4],
                                    const float* __restrict__ g, const float* __restrict__ b,
                                    int quad) {
  float s1 = 0.f, s2 = 0.f;
#pragma unroll
  for (int ct = 0; ct < 4; ct++)
#pragma unroll
    for (int r = 0; r < 4; r++) { s1 += x[ct][r]; s2 += x[ct][r] * x[ct][r]; }
  s1 = qsum(s1);
  s2 = qsum(s2);
  float mean = s1 * 0.015625f;
  float var = s2 * 0.015625f - mean * mean;
  float rs = rsqrtf(var + 1e-5f);
#pragma unroll
  for (int ct = 0; ct < 4; ct++) {
    f32x4 gv = ld4(g + 16 * ct + 4 * quad);
    f32x4 bv = ld4(b + 16 * ct + 4 * quad);
#pragma unroll
    for (int r = 0; r < 4; r++) y[ct][r] = (x[ct][r] - mean) * rs * gv[r] + bv[r];
  }
}

// ---------- zero fill ----------
__global__ void zero_kernel(float4* __restrict__ p, int n4) {
  int t = blockIdx.x * blockDim.x + threadIdx.x;
  if (t < n4) p[t] = make_float4(0.f, 0.f, 0.f, 0.f);
}

// ---------- prep: pack weights as x32 A-frags with the k-slot permutation ----------
__global__ void prep_kernel(const float* __restrict__ si, const float* __restrict__ so,
                            const float* __restrict__ w1s, const float* __restrict__ w2s,
                            const float* __restrict__ ci, const float* __restrict__ co,
                            const float* __restrict__ w1c, const float* __restrict__ w2c,
                            const float* __restrict__ iw, const float* __restrict__ av,
                            float* __restrict__ ws) {
  int t = blockIdx.x * blockDim.x + threadIdx.x;
  ushort_t* bw = (ushort_t*)(ws + 33280);
  if (t < 98304) {
    const float* src;
    int base, cs;
    int l = t;
    if      (l < 12288) { src = si;  base = 0;     cs = 6; }
    else if (l < 16384) { src = so;  base = 12288; cs = 6; l -= 12288; }
    else if (l < 32768) { src = w1s; base = 16384; cs = 6; l -= 16384; }
    else if (l < 49152) { src = w2s; base = 32768; cs = 8; l -= 32768; }
    else if (l < 61440) { src = ci;  base = 49152; cs = 6; l -= 49152; }
    else if (l < 65536) { src = co;  base = 61440; cs = 6; l -= 61440; }
    else if (l < 81920) { src = w1c; base = 65536; cs = 6; l -= 65536; }
    else                { src = w2c; base = 81920; cs = 8; l -= 81920; }
    int c = l >> cs, k = l & ((1 << cs) - 1);
    int T = (1 << cs) >> 5;
    int ct = c >> 4, m = c & 15, tt = k >> 5, rem = k & 31;
    int quad = (rem >> 2) & 3;
    int j = (((rem >> 4) & 1) << 2) | (rem & 3);
    bw[base + (size_t)((ct * T + tt) * 64 + quad * 16 + m) * 8 + j] = f2b(src[l]);
  } else if (t < 131072) {
    int l = t - 98304;
    int c = l >> 6, k = l & 63;
    ws[(k >> 2) * 2048 + c * 4 + (k & 3)] = iw[l];
  } else if (t < 131584) {
    int l = t - 131072;
    int h = l >> 6, k = l & 63;
    float acc = 0.f;
    for (int c = 0; c < 64; c++) acc += av[h * 64 + c] * iw[(h * 64 + c) * 64 + k];
    ws[32768 + h * 64 + k] = acc;
  }
}

// ================== literal-index macros (force SROA promotion; rule-#20 fix) ==================
// score for one (CT, KS): dot over this lane's 4 ch + partner quad via shfl_xor(16)
#define SC1(KARR, QF, CT, KS, P)                                                        \
  { f32x4 kv_ = unpk(KARR[KS][(CT) >> 1], (CT) & 1);                                    \
    float sp_ = QF[CT][0] * kv_[0] + QF[CT][1] * kv_[1] + QF[CT][2] * kv_[2] +          \
                QF[CT][3] * kv_[3];                                                     \
    sp_ += __shfl_xor(sp_, 16);                                                         \
    P = ((vb >> (KS)) & 1) ? sp_ : -1e30f; }

#define PV1(VARR, CT, KS, P, ACC)                                                       \
  { f32x4 vv_ = unpk(VARR[KS][(CT) >> 1], (CT) & 1);                                    \
    _Pragma("unroll") for (int r = 0; r < 4; r++) ACC[r] = fmaf(P, vv_[r], ACC[r]); }

// full attention for one output ct-tile (literal CT); OD is a named f32x4
#define ATT_CT(KARR, VARR, QF, CT, OD)                                                  \
  {                                                                                     \
    float p0, p1, p2, p3, p4;                                                           \
    SC1(KARR, QF, CT, 0, p0); SC1(KARR, QF, CT, 1, p1); SC1(KARR, QF, CT, 2, p2);       \
    SC1(KARR, QF, CT, 3, p3); SC1(KARR, QF, CT, 4, p4);                                 \
    float mx_ = fmaxf(fmaxf(fmaxf(p0, p1), fmaxf(p2, p3)), p4);                         \
    p0 = exp2f(p0 - mx_); p1 = exp2f(p1 - mx_); p2 = exp2f(p2 - mx_);                   \
    p3 = exp2f(p3 - mx_); p4 = exp2f(p4 - mx_);                                         \
    float ri_ = 1.0f / (p0 + p1 + p2 + p3 + p4);                                        \
    p0 *= ri_; p1 *= ri_; p2 *= ri_; p3 *= ri_; p4 *= ri_;                              \
    OD = (f32x4){0.f, 0.f, 0.f, 0.f};                                                   \
    PV1(VARR, CT, 0, p0, OD); PV1(VARR, CT, 1, p1, OD); PV1(VARR, CT, 2, p2, OD);       \
    PV1(VARR, CT, 3, p3, OD); PV1(VARR, CT, 4, p4, OD);                                 \
  }

// stage A for literal S: gather+pos+LN -> K,V packs (literal array writes)
#define KV_STAGE(S)                                                                     \
  {                                                                                     \
    f32x4 t[4], y[4];                                                                   \
    const bool vd = (vb >> (S)) & 1;                                                    \
    const float* fp = features + (size_t)min(ids[S], N - 1) * 64;                       \
    _Pragma("unroll")                                                                   \
    for (int ct = 0; ct < 4; ct++) {                                                    \
      f32x4 f = ld4(fp + 16 * ct + 4 * quad);                                           \
      f32x4 pv = ld4(pos_emb + (S) * 64 + 16 * ct + 4 * quad);                          \
      _Pragma("unroll")                                                                 \
      for (int r = 0; r < 4; r++) t[ct][r] = vd ? (f[r] + pv[r]) : 0.f;                 \
    }                                                                                   \
    lnT(t, y, sa_ln1_g, sa_ln1_b, quad);                                                \
    bf16x8 xl0 = mkpair(y[0], y[1]), xl1 = mkpair(y[2], y[3]);                          \
    f32x4 kt[4], vt[4];                                                                 \
    _Pragma("unroll")                                                                   \
    for (int ct = 0; ct < 4; ct++) {                                                    \
      f32x4 c = {0.f, 0.f, 0.f, 0.f};                                                   \
      c = MF(WSI[((4 + ct) * 2 + 0) * 64 + lane], xl0, c);                              \
      c = MF(WSI[((4 + ct) * 2 + 1) * 64 + lane], xl1, c);                              \
      f32x4 bb = ld4(self_in_b + 64 + 16 * ct + 4 * quad);                              \
      _Pragma("unroll")                                                                 \
      for (int r = 0; r < 4; r++) kt[ct][r] = c[r] + bb[r];                             \
      f32x4 c2 = {0.f, 0.f, 0.f, 0.f};                                                  \
      c2 = MF(WSI[((8 + ct) * 2 + 0) * 64 + lane], xl0, c2);                            \
      c2 = MF(WSI[((8 + ct) * 2 + 1) * 64 + lane], xl1, c2);                            \
      f32x4 bb2 = ld4(self_in_b + 128 + 16 * ct + 4 * quad);                            \
      _Pragma("unroll")                                                                 \
      for (int r = 0; r < 4; r++) vt[ct][r] = c2[r] + bb2[r];                           \
    }                                                                                   \
    Kp[S][0] = mkpair(kt[0], kt[1]); Kp[S][1] = mkpair(kt[2], kt[3]);                   \
    Vp[S][0] = mkpair(vt[0], vt[1]); Vp[S][1] = mkpair(vt[2], vt[3]);                   \
  }

// stage B for literal S: regather+LN -> Q, attention, PV, out-proj, residual, pool, TP
#define Q_STAGE(S)                                                                      \
  {                                                                                     \
    const bool vd = (vb >> (S)) & 1;                                                    \
    const float* fp = features + (size_t)min(ids[S], N - 1) * 64;                       \
    f32x4 t[4], y[4];                                                                   \
    _Pragma("unroll")                                                                   \
    for (int ct = 0; ct < 4; ct++) {                                                    \
      f32x4 f = ld4(fp + 16 * ct + 4 * quad);                                           \
      f32x4 pv = ld4(pos_emb + (S) * 64 + 16 * ct + 4 * quad);                          \
      _Pragma("unroll")                                                                 \
      for (int r = 0; r < 4; r++) t[ct][r] = vd ? (f[r] + pv[r]) : 0.f;                 \
    }                                                                                   \
    lnT(t, y, sa_ln1_g, sa_ln1_b, quad);                                                \
    bf16x8 xl0 = mkpair(y[0], y[1]), xl1 = mkpair(y[2], y[3]);                          \
    f32x4 qf[4];                                                                        \
    _Pragma("unroll")                                                                   \
    for (int ct = 0; ct < 4; ct++) {                                                    \
      f32x4 c = {0.f, 0.f, 0.f, 0.f};                                                   \
      c = MF(WSI[(ct * 2 + 0) * 64 + lane], xl0, c);                                    \
      c = MF(WSI[(ct * 2 + 1) * 64 + lane], xl1, c);                                    \
      f32x4 bb = ld4(self_in_b + 16 * ct + 4 * quad);                                   \
      _Pragma("unroll")                                                                 \
      for (int r = 0; r < 4; r++) qf[ct][r] = (c[r] + bb[r]) * QSCALE;                  \
    }                                                                                   \
    f32x4 oa0, oa1, oa2, oa3;                                                           \
    ATT_CT(Kp, Vp, qf, 0, oa0); ATT_CT(Kp, Vp, qf, 1, oa1);                             \
    ATT_CT(Kp, Vp, qf, 2, oa2); ATT_CT(Kp, Vp, qf, 3, oa3);                             \
    bf16x8 op0 = mkpair(oa0, oa1), op1 = mkpair(oa2, oa3);                              \
    f32x4 tpc[4];                                                                       \
    _Pragma("unroll")                                                                   \
    for (int ct = 0; ct < 4; ct++) {                                                    \
      f32x4 c = {0.f, 0.f, 0.f, 0.f};                                                   \
      c = MF(WSO[(ct * 2 + 0) * 64 + lane], op0, c);                                    \
      c = MF(WSO[(ct * 2 + 1) * 64 + lane], op1, c);                                    \
      f32x4 bb = ld4(self_out_b + 16 * ct + 4 * quad);                                  \
      _Pragma("unroll")                                                                 \
      for (int r = 0; r < 4; r++) {                                                     \
        float tp_ = c[r] + bb[r] + t[ct][r];                                            \
        tpc[ct][r] = tp_;                                                               \
        pool[ct][r] += vd ? tp_ : 0.f;                                                  \
      }                                                                                 \
    }                                                                                   \
    TP[S][0] = mkpair(tpc[0], tpc[1]); TP[S][1] = mkpair(tpc[2], tpc[3]);               \
  }

// cross K/V for literal S (reads TP[S] literal, writes Kc/Vc literal)
#define CKV_STAGE(S)                                                                    \
  {                                                                                     \
    f32x4 kt[4], vt[4];                                                                 \
    _Pragma("unroll")                                                                   \
    for (int ct = 0; ct < 4; ct++) {                                                    \
      f32x4 c = {0.f, 0.f, 0.f, 0.f};                                                   \
      c = MF(WCI[((4 + ct) * 2 + 0) * 64 + lane], TP[S][0], c);                         \
      c = MF(WCI[((4 + ct) * 2 + 1) * 64 + lane], TP[S][1], c);                         \
      f32x4 bb = ld4(cross_in_b + 64 + 16 * ct + 4 * quad);                             \
      _Pragma("unroll")                                                                 \
      for (int r = 0; r < 4; r++) kt[ct][r] = c[r] + bb[r];                             \
      f32x4 c2 = {0.f, 0.f, 0.f, 0.f};                                                  \
      c2 = MF(WCI[((8 + ct) * 2 + 0) * 64 + lane], TP[S][0], c2);                       \
      c2 = MF(WCI[((8 + ct) * 2 + 1) * 64 + lane], TP[S][1], c2);                       \
      f32x4 bb2 = ld4(cross_in_b + 128 + 16 * ct + 4 * quad);                           \
      _Pragma("unroll")                                                                 \
      for (int r = 0; r < 4; r++) vt[ct][r] = c2[r] + bb2[r];                           \
    }                                                                                   \
    Kc[S][0] = mkpair(kt[0], kt[1]); Kc[S][1] = mkpair(kt[2], kt[3]);                   \
    Vc[S][0] = mkpair(vt[0], vt[1]); Vc[S][1] = mkpair(vt[2], vt[3]);                   \
  }

// ffn internals (literal hidden-tile indices; named Hp0..Hp7)
#define FF_H2(CT, HD)                                                                   \
  { f32x4 c = {0.f, 0.f, 0.f, 0.f};                                                     \
    c = MF(W1[((CT) * 2 + 0) * 64 + lane], x0, c);                                      \
    c = MF(W1[((CT) * 2 + 1) * 64 + lane], x1, c);                                      \
    f32x4 bb = ld4(b1 + 16 * (CT) + 4 * quad);                                          \
    _Pragma("unroll")                                                                   \
    for (int r = 0; r < 4; r++) {                                                       \
      float v = c[r] + bb[r];                                                           \
      HD[r] = 0.5f * v * (1.0f + erff(v * 0.70710678118654752440f));                    \
    } }

#define FF_O(CT)                                                                        \
  { f32x4 c = {0.f, 0.f, 0.f, 0.f};                                                     \
    c = MF(W2[((CT) * 8 + 0) * 64 + lane], Hp0, c);                                     \
    c = MF(W2[((CT) * 8 + 1) * 64 + lane], Hp1, c);                                     \
    c = MF(W2[((CT) * 8 + 2) * 64 + lane], Hp2, c);                                     \
    c = MF(W2[((CT) * 8 + 3) * 64 + lane], Hp3, c);                                     \
    c = MF(W2[((CT) * 8 + 4) * 64 + lane], Hp4, c);                                     \
    c = MF(W2[((CT) * 8 + 5) * 64 + lane], Hp5, c);                                     \
    c = MF(W2[((CT) * 8 + 6) * 64 + lane], Hp6, c);                                     \
    c = MF(W2[((CT) * 8 + 7) * 64 + lane], Hp7, c);                                     \
    f32x4 bb = ld4(b2 + 16 * (CT) + 4 * quad);                                          \
    _Pragma("unroll")                                                                   \
    for (int r = 0; r < 4; r++) inst[CT][r] += c[r] + bb[r]; }

// transposed FF block: inst += FF(LN(inst)); all hidden tiles in named registers
__device__ __forceinline__ void ffnT(f32x4 (&inst)[4],
                                     const float* __restrict__ g, const float* __restrict__ b,
                                     const bf16x8* __restrict__ W1, const bf16x8* __restrict__ W2,
                                     const float* __restrict__ b1, const float* __restrict__ b2,
                                     int lane, int quad) {
  f32x4 y[4];
  lnT(inst, y, g, b, quad);
  bf16x8 x0 = mkpair(y[0], y[1]), x1 = mkpair(y[2], y[3]);
  f32x4 ha, hb;
  FF_H2(0, ha);  FF_H2(1, hb);  bf16x8 Hp0 = mkpair(ha, hb);
  FF_H2(2, ha);  FF_H2(3, hb);  bf16x8 Hp1 = mkpair(ha, hb);
  FF_H2(4, ha);  FF_H2(5, hb);  bf16x8 Hp2 = mkpair(ha, hb);
  FF_H2(6, ha);  FF_H2(7, hb);  bf16x8 Hp3 = mkpair(ha, hb);
  FF_H2(8, ha);  FF_H2(9, hb);  bf16x8 Hp4 = mkpair(ha, hb);
  FF_H2(10, ha); FF_H2(11, hb); bf16x8 Hp5 = mkpair(ha, hb);
  FF_H2(12, ha); FF_H2(13, hb); bf16x8 Hp6 = mkpair(ha, hb);
  FF_H2(14, ha); FF_H2(15, hb); bf16x8 Hp7 = mkpair(ha, hb);
  FF_O(0); FF_O(1); FF_O(2); FF_O(3);
}

// a-score for literal H into named float a##H
#define ASC(H)                                                                          \
  { float sp = 0.f;                                                                     \
    _Pragma("unroll")                                                                   \
    for (int ct = 0; ct < 4; ct++) {                                                    \
      f32x4 uu = ld4(uvec + (H) * 64 + 16 * ct + 4 * quad);                             \
      _Pragma("unroll")                                                                 \
      for (int r = 0; r < 4; r++) sp = fmaf(inst[ct][r], uu[r], sp);                    \
    }                                                                                   \
    sp = qsum(sp);                                                                      \
    a##H = sp > 0.f ? sp : 0.01f * sp; }

// ---------- per-edge transformer: one wave = 16 edges, fully register-resident ----------
__global__ __launch_bounds__(64, 2)
void edge_kernel(const float* __restrict__ features, const float* __restrict__ pos_emb,
                 const float* __restrict__ self_in_b, const float* __restrict__ self_out_b,
                 const float* __restrict__ cross_in_b, const float* __restrict__ cross_out_b,
                 const float* __restrict__ sa_ln1_g, const float* __restrict__ sa_ln1_b,
                 const float* __restrict__ sa_ln2_g, const float* __restrict__ sa_ln2_b,
                 const float* __restrict__ ca_ln1_g, const float* __restrict__ ca_ln1_b,
                 const float* __restrict__ ca_ln2_g, const float* __restrict__ ca_ln2_b,
                 const float* __restrict__ sa_ff_b1, const float* __restrict__ sa_ff_b2,
                 const float* __restrict__ ca_ff_b1, const float* __restrict__ ca_ff_b2,
                 const int* __restrict__ midx, const int* __restrict__ dstv,
                 const float* __restrict__ ws,
                 float* __restrict__ inst_out, float* __restrict__ a_out,
                 unsigned int* __restrict__ seg_max, int E, int N) {
  const int lane = threadIdx.x;
  const int quad = lane >> 4, lo = lane & 15;
  const int e0 = blockIdx.x * 16;
  __shared__ float xp[16 * 68];

  const ushort_t* bw = (const ushort_t*)(ws + 33280);
  const bf16x8* WSI = (const bf16x8*)(bw);
  const bf16x8* WSO = (const bf16x8*)(bw + 12288);
  const bf16x8* W1S = (const bf16x8*)(bw + 16384);
  const bf16x8* W2S = (const bf16x8*)(bw + 32768);
  const bf16x8* WCI = (const bf16x8*)(bw + 49152);
  const bf16x8* WCO = (const bf16x8*)(bw + 61440);
  const bf16x8* W1C = (const bf16x8*)(bw + 65536);
  const bf16x8* W2C = (const bf16x8*)(bw + 81920);
  const float* uvec = ws + 32768;

  // per-lane edge meta: lane (quad, lo) owns edge e0+lo (replicated across quads)
  const bool ge = (e0 + lo) < E;
  const int eIdx = min(e0 + lo, E - 1);
  int ids[5];
  ids[0] = midx[eIdx * 5 + 0];
  ids[1] = midx[eIdx * 5 + 1];
  ids[2] = midx[eIdx * 5 + 2];
  ids[3] = midx[eIdx * 5 + 3];
  ids[4] = midx[eIdx * 5 + 4];
  int vb = 0;
  if (ids[0] != N && ge) vb |= 1;
  if (ids[1] != N && ge) vb |= 2;
  if (ids[2] != N && ge) vb |= 4;
  if (ids[3] != N && ge) vb |= 8;
  if (ids[4] != N && ge) vb |= 16;
  const int nv = __popc(vb);
  const int lp = max(nv - 1, 0);
  int lid = ids[0];
  lid = (lp == 1) ? ids[1] : lid;
  lid = (lp == 2) ? ids[2] : lid;
  lid = (lp == 3) ? ids[3] : lid;
  lid = (lp == 4) ? ids[4] : lid;

  // ---- stage A: K, V GEMMs (literal-indexed register arrays) ----
  bf16x8 Kp[5][2], Vp[5][2];
  KV_STAGE(0); KV_STAGE(1); KV_STAGE(2); KV_STAGE(3); KV_STAGE(4);

  // ---- stage B: per-qs attention + out-proj + residual + pool + TP ----
  f32x4 pool[4];
#pragma unroll
  for (int ct = 0; ct < 4; ct++) pool[ct] = (f32x4){0.f, 0.f, 0.f, 0.f};
  bf16x8 TP[5][2];
  Q_STAGE(0); Q_STAGE(1); Q_STAGE(2); Q_STAGE(3); Q_STAGE(4);

  f32x4 inst[4];
  {
    float rn = 1.0f / (float)max(nv, 1);
#pragma unroll
    for (int ct = 0; ct < 4; ct++)
#pragma unroll
      for (int r = 0; r < 4; r++) inst[ct][r] = pool[ct][r] * rn;
  }

  // ---- FF-sa ----
  ffnT(inst, sa_ln2_g, sa_ln2_b, W1S, W2S, sa_ff_b1, sa_ff_b2, lane, quad);

  // ---- cross attention ----
  {
    f32x4 tf[4], xq[4];
    const bool vdl = lid != N;
    const float* fp = features + (size_t)min(lid, N - 1) * 64;
#pragma unroll
    for (int ct = 0; ct < 4; ct++) {
      f32x4 f = ld4(fp + 16 * ct + 4 * quad);
#pragma unroll
      for (int r = 0; r < 4; r++) tf[ct][r] = vdl ? f[r] : 0.f;
    }
    lnT(tf, xq, ca_ln1_g, ca_ln1_b, quad);
    bf16x8 xq0 = mkpair(xq[0], xq[1]), xq1 = mkpair(xq[2], xq[3]);
    f32x4 qcf[4];
#pragma unroll
    for (int ct = 0; ct < 4; ct++) {
      f32x4 c = {0.f, 0.f, 0.f, 0.f};
      c = MF(WCI[(ct * 2 + 0) * 64 + lane], xq0, c);
      c = MF(WCI[(ct * 2 + 1) * 64 + lane], xq1, c);
      f32x4 bb = ld4(cross_in_b + 16 * ct + 4 * quad);
#pragma unroll
      for (int r = 0; r < 4; r++) qcf[ct][r] = (c[r] + bb[r]) * QSCALE;
    }
    bf16x8 Kc[5][2], Vc[5][2];
    CKV_STAGE(0); CKV_STAGE(1); CKV_STAGE(2); CKV_STAGE(3); CKV_STAGE(4);
    f32x4 cc0, cc1, cc2, cc3;
    ATT_CT(Kc, Vc, qcf, 0, cc0); ATT_CT(Kc, Vc, qcf, 1, cc1);
    ATT_CT(Kc, Vc, qcf, 2, cc2); ATT_CT(Kc, Vc, qcf, 3, cc3);
    bf16x8 cp0 = mkpair(cc0, cc1), cp1 = mkpair(cc2, cc3);
#pragma unroll
    for (int ct = 0; ct < 4; ct++) {
      f32x4 c = {0.f, 0.f, 0.f, 0.f};
      c = MF(WCO[(ct * 2 + 0) * 64 + lane], cp0, c);
      c = MF(WCO[(ct * 2 + 1) * 64 + lane], cp1, c);
      f32x4 bb = ld4(cross_out_b + 16 * ct + 4 * quad);
#pragma unroll
      for (int r = 0; r < 4; r++) inst[ct][r] += c[r] + bb[r];
    }
  }

  // ---- FF-ca ----
  ffnT(inst, ca_ln2_g, ca_ln2_b, W1C, W2C, ca_ff_b1, ca_ff_b2, lane, quad);

  // ---- a-scores: a[e][h] = leakyrelu(inst . u_h) (named scalars, literal H) ----
  float a0, a1, a2, a3, a4, a5, a6, a7;
  ASC(0); ASC(1); ASC(2); ASC(3); ASC(4); ASC(5); ASC(6); ASC(7);
  if (ge) {
    int dd = dstv[e0 + lo];
    float v0 = quad == 0 ? a0 : quad == 1 ? a2 : quad == 2 ? a4 : a6;
    float v1 = quad == 0 ? a1 : quad == 1 ? a3 : quad == 2 ? a5 : a7;
    atomicMax(&seg_max[dd * 8 + 2 * quad], fkey(v0));
    atomicMax(&seg_max[dd * 8 + 2 * quad + 1], fkey(v1));
    if (quad < 2) {
      f32x4 st = (quad == 0) ? (f32x4){a0, a1, a2, a3} : (f32x4){a4, a5, a6, a7};
      *(f32x4*)(a_out + (size_t)(e0 + lo) * 8 + 4 * quad) = st;
    }
  }

  // ---- inst_out: small LDS transpose ([ch][edge] -> [edge][ch]) + coalesced store ----
#pragma unroll
  for (int ct = 0; ct < 4; ct++)
    *(f32x4*)(&xp[lo * 68 + 16 * ct + 4 * quad]) = inst[ct];
  __syncthreads();
  {
    int er = lane >> 2, cb = (lane & 3) * 16;
    if (e0 + er < E) {
#pragma unroll
      for (int u = 0; u < 4; u++) {
        f32x4 v = *(const f32x4*)(&xp[er * 68 + cb + 4 * u]);
        *(f32x4*)(inst_out + (size_t)(e0 + er) * 64 + cb + 4 * u) = v;
      }
    }
  }
}

// ---------- edge softmax denominator ----------
__global__ void expsum_kernel(const float* __restrict__ a, const int* __restrict__ dstv,
                              const unsigned int* __restrict__ seg_max,
                              float* __restrict__ seg_sum, int E8) {
  int t = blockIdx.x * blockDim.x + threadIdx.x;
  if (t >= E8) return;
  int e = t >> 3, h = t & 7;
  int dd = dstv[e];
  float m = funkey(seg_max[dd * 8 + h]);
  atomicAdd(&seg_sum[dd * 8 + h], __expf(a[t] - m));
}

// ---------- scatter att-weighted inst_emb into z = d_out ----------
__global__ __launch_bounds__(256)
void scatter_kernel(const float* __restrict__ inst_emb, const float* __restrict__ a,
                    const unsigned int* __restrict__ seg_max, const float* __restrict__ seg_sum,
                    const int* __restrict__ dstv, float* __restrict__ out, int E) {
  const int wid = (blockIdx.x * blockDim.x + threadIdx.x) >> 6;
  const int lane = threadIdx.x & 63;
  if (wid >= E) return;
  int dd = dstv[wid];
  float iv = inst_emb[(size_t)wid * D + lane];
#pragma unroll
  for (int h = 0; h < 8; h++) {
    float m = funkey(seg_max[dd * 8 + h]);
    float s = seg_sum[dd * 8 + h];
    float att = __expf(a[wid * 8 + h] - m) / s;
    atomicAdd(&out[(size_t)dd * 512 + h * 64 + lane], att * iv);
  }
}

// ---------- in-place per-(n,h) transform: row = inst_w_h @ row, 4 nodes per wave ----------
__global__ __launch_bounds__(256)
void head_transform_kernel(const float* __restrict__ T_iw, float* __restrict__ out, int N) {
  const int wid = (blockIdx.x * blockDim.x + threadIdx.x) >> 6;
  const int lane = threadIdx.x & 63;
  const int h = wid & 7;
  const int n0 = (wid >> 3) * 4;
  if (n0 >= N) return;
  float z[4], acc[4];
#pragma unroll
  for (int j = 0; j < 4; j++) {
    z[j] = (n0 + j < N) ? out[((size_t)(n0 + j) * 8 + h) * D + lane] : 0.f;
    acc[j] = 0.f;
  }
  const vf4* P = (const vf4*)T_iw;
  for (int k4 = 0; k4 < 16; k4++) {
    vf4 w = P[k4 * 512 + h * 64 + lane];
#pragma unroll
    for (int u = 0; u < 4; u++) {
      int i = k4 * 4 + u;
#pragma unroll
      for (int j = 0; j < 4; j++) acc[j] = fmaf(bcast(z[j], i), w[u], acc[j]);
    }
  }
#pragma unroll
  for (int j = 0; j < 4; j++)
    if (n0 + j < N) out[((size_t)(n0 + j) * 8 + h) * D + lane] = acc[j];
}

extern "C" void kernel_launch(void* const* d_in, const int* in_sizes, int n_in,
                              void* d_out, int out_size, void* d_ws, size_t ws_size,
                              hipStream_t stream) {
  const float* features   = (const float*)d_in[0];
  const float* pos_emb    = (const float*)d_in[1];
  const float* self_in_w  = (const float*)d_in[2];
  const float* self_in_b  = (const float*)d_in[3];
  const float* self_out_w = (const float*)d_in[4];
  const float* self_out_b = (const float*)d_in[5];
  const float* cross_in_w = (const float*)d_in[6];
  const float* cross_in_b = (const float*)d_in[7];
  const float* cross_out_w= (const float*)d_in[8];
  const float* cross_out_b= (const float*)d_in[9];
  const float* sa_ln1_g = (const float*)d_in[10];
  const float* sa_ln1_b = (const float*)d_in[11];
  const float* sa_ln2_g = (const float*)d_in[12];
  const float* sa_ln2_b = (const float*)d_in[13];
  const float* ca_ln1_g = (const float*)d_in[14];
  const float* ca_ln1_b = (const float*)d_in[15];
  const float* ca_ln2_g = (const float*)d_in[16];
  const float* ca_ln2_b = (const float*)d_in[17];
  const float* sa_ff_w1 = (const float*)d_in[18];
  const float* sa_ff_b1 = (const float*)d_in[19];
  const float* sa_ff_w2 = (const float*)d_in[20];
  const float* sa_ff_b2 = (const float*)d_in[21];
  const float* ca_ff_w1 = (const float*)d_in[22];
  const float* ca_ff_b1 = (const float*)d_in[23];
  const float* ca_ff_w2 = (const float*)d_in[24];
  const float* ca_ff_b2 = (const float*)d_in[25];
  const float* inst_w   = (const float*)d_in[26];
  const float* attn_vec = (const float*)d_in[27];
  const int* midx = (const int*)d_in[28];
  const int* dstv = (const int*)d_in[29];

  const int N = in_sizes[0] / 64;
  const int E = in_sizes[29];

  // ws floats: [0..32767] T_iw | [32768..33279] u | [33280..82431] bf16 A-frag packs
  //            [131072...] inst_emb[E*64] | a[E*8] | seg_max[N*8] | seg_sum[N*8]
  float* wsf = (float*)d_ws;
  float* inst_emb = wsf + 131072;
  float* a_arr = inst_emb + (size_t)E * 64;
  unsigned int* seg_max = (unsigned int*)(a_arr + (size_t)E * 8);
  float* seg_sum = (float*)(seg_max + (size_t)N * 8);

  {
    int n4 = out_size / 4;
    zero_kernel<<<(n4 + 255) / 256, 256, 0, stream>>>((float4*)d_out, n4);
    int s4 = (N * 16) / 4;  // seg_max + seg_sum contiguous
    zero_kernel<<<(s4 + 255) / 256, 256, 0, stream>>>((float4*)seg_max, s4);
  }

  prep_kernel<<<(131584 + 255) / 256, 256, 0, stream>>>(
      self_in_w, self_out_w, sa_ff_w1, sa_ff_w2, cross_in_w, cross_out_w, ca_ff_w1, ca_ff_w2,
      inst_w, attn_vec, wsf);

  int nblk = (E + 15) / 16;  // 1 wave/block, 16 edges/wave
  edge_kernel<<<nblk, 64, 0, stream>>>(
      features, pos_emb, self_in_b, self_out_b, cross_in_b, cross_out_b, sa_ln1_g, sa_ln1_b,
      sa_ln2_g, sa_ln2_b, ca_ln1_g, ca_ln1_b, ca_ln2_g, ca_ln2_b, sa_ff_b1, sa_ff_b2, ca_ff_b1,
      ca_ff_b2, midx, dstv, wsf, inst_emb, a_arr, seg_max, E, N);

  expsum_kernel<<<(E * 8 + 255) / 256, 256, 0, stream>>>(a_arr, dstv, seg_max, seg_sum, E * 8);

  scatter_kernel<<<(E + 3) / 4, 256, 0, stream>>>(inst_emb, a_arr, seg_max, seg_sum, dstv,
                                                  (float*)d_out, E);

  int hwave = ((N + 3) / 4) * 8;
  head_transform_kernel<<<(hwave + 3) / 4, 256, 0, stream>>>(wsf, (float*)d_out, N);
}

// Round 4
// 1042.016 us; speedup vs baseline: 1.0562x; 1.0277x over previous
//
#include <hip/hip_runtime.h>
#include <math.h>

#define D 64
#define LOG2E 1.44269504088896340736f
#define QSCALE (0.35355339059327373f * LOG2E)

typedef float f32x4 __attribute__((ext_vector_type(4)));
typedef float vf4 __attribute__((ext_vector_type(4)));
typedef short bf16x8 __attribute__((ext_vector_type(8)));
typedef unsigned short ushort_t;

#define MF(a, b, c) __builtin_amdgcn_mfma_f32_16x16x32_bf16(a, b, c, 0, 0, 0)

// ---------- helpers ----------
__device__ __forceinline__ float bcast(float x, int i) {
  return __int_as_float(__builtin_amdgcn_readlane(__float_as_int(x), i));
}
__device__ __forceinline__ float qsum(float x) {  // sum over the 4 quads
  x += __shfl_xor(x, 16);
  x += __shfl_xor(x, 32);
  return x;
}
__device__ __forceinline__ ushort_t f2b(float f) {  // fp32 -> bf16 RTNE
  unsigned int u = __float_as_uint(f);
  unsigned int r = (u + 0x7FFFu + ((u >> 16) & 1u)) >> 16;
  return (ushort_t)r;
}
__device__ __forceinline__ float b2f(short s) {  // bf16 -> fp32
  return __uint_as_float(((unsigned int)(unsigned short)s) << 16);
}
__device__ __forceinline__ f32x4 ld4(const float* __restrict__ p) { return *(const f32x4*)p; }
// monotonic unsigned key encoding for float atomicMax
__device__ __forceinline__ unsigned int fkey(float f) {
  unsigned int b = __float_as_uint(f);
  return (b & 0x80000000u) ? ~b : (b | 0x80000000u);
}
__device__ __forceinline__ float funkey(unsigned int k) {
  return __uint_as_float((k & 0x80000000u) ? (k ^ 0x80000000u) : ~k);
}
// pack two C-tiles (even ct, odd ct) into one x32 B-operand pair
__device__ __forceinline__ bf16x8 mkpair(const f32x4& ce, const f32x4& co) {
  bf16x8 b;
#pragma unroll
  for (int j = 0; j < 4; j++) {
    b[j] = (short)f2b(ce[j]);
    b[4 + j] = (short)f2b(co[j]);
  }
  return b;
}
__device__ __forceinline__ f32x4 unpk(bf16x8 p, int half) {  // half 0 = even ct, 1 = odd ct
  f32x4 r;
#pragma unroll
  for (int j = 0; j < 4; j++) r[j] = b2f(p[half * 4 + j]);
  return r;
}

// transposed-layout LayerNorm: x,y are 16 channel values/lane; stats over 64 ch
__device__ __forceinline__ void lnT(const f32x4 (&x)[4], f32x4 (&y)[4],
                                    const float* __restrict__ g, const float* __restrict__ b,
                                    int quad) {
  float s1 = 0.f, s2 = 0.f;
#pragma unroll
  for (int ct = 0; ct < 4; ct++)
#pragma unroll
    for (int r = 0; r < 4; r++) { s1 += x[ct][r]; s2 += x[ct][r] * x[ct][r]; }
  s1 = qsum(s1);
  s2 = qsum(s2);
  float mean = s1 * 0.015625f;
  float var = s2 * 0.015625f - mean * mean;
  float rs = rsqrtf(var + 1e-5f);
#pragma unroll
  for (int ct = 0; ct < 4; ct++) {
    f32x4 gv = ld4(g + 16 * ct + 4 * quad);
    f32x4 bv = ld4(b + 16 * ct + 4 * quad);
#pragma unroll
    for (int r = 0; r < 4; r++) y[ct][r] = (x[ct][r] - mean) * rs * gv[r] + bv[r];
  }
}

// ---------- zero fill ----------
__global__ void zero_kernel(float4* __restrict__ p, int n4) {
  int t = blockIdx.x * blockDim.x + threadIdx.x;
  if (t < n4) p[t] = make_float4(0.f, 0.f, 0.f, 0.f);
}

// ---------- prep: pack weights as x32 A-frags with the k-slot permutation ----------
__global__ void prep_kernel(const float* __restrict__ si, const float* __restrict__ so,
                            const float* __restrict__ w1s, const float* __restrict__ w2s,
                            const float* __restrict__ ci, const float* __restrict__ co,
                            const float* __restrict__ w1c, const float* __restrict__ w2c,
                            const float* __restrict__ iw, const float* __restrict__ av,
                            float* __restrict__ ws) {
  int t = blockIdx.x * blockDim.x + threadIdx.x;
  ushort_t* bw = (ushort_t*)(ws + 33280);
  if (t < 98304) {
    const float* src;
    int base, cs;
    int l = t;
    if      (l < 12288) { src = si;  base = 0;     cs = 6; }
    else if (l < 16384) { src = so;  base = 12288; cs = 6; l -= 12288; }
    else if (l < 32768) { src = w1s; base = 16384; cs = 6; l -= 16384; }
    else if (l < 49152) { src = w2s; base = 32768; cs = 8; l -= 32768; }
    else if (l < 61440) { src = ci;  base = 49152; cs = 6; l -= 49152; }
    else if (l < 65536) { src = co;  base = 61440; cs = 6; l -= 61440; }
    else if (l < 81920) { src = w1c; base = 65536; cs = 6; l -= 65536; }
    else                { src = w2c; base = 81920; cs = 8; l -= 81920; }
    int c = l >> cs, k = l & ((1 << cs) - 1);
    int T = (1 << cs) >> 5;
    int ct = c >> 4, m = c & 15, tt = k >> 5, rem = k & 31;
    int quad = (rem >> 2) & 3;
    int j = (((rem >> 4) & 1) << 2) | (rem & 3);
    bw[base + (size_t)((ct * T + tt) * 64 + quad * 16 + m) * 8 + j] = f2b(src[l]);
  } else if (t < 131072) {
    int l = t - 98304;
    int c = l >> 6, k = l & 63;
    ws[(k >> 2) * 2048 + c * 4 + (k & 3)] = iw[l];
  } else if (t < 131584) {
    int l = t - 131072;
    int h = l >> 6, k = l & 63;
    float acc = 0.f;
    for (int c = 0; c < 64; c++) acc += av[h * 64 + c] * iw[(h * 64 + c) * 64 + k];
    ws[32768 + h * 64 + k] = acc;
  }
}

// ================== literal-index macros (straight-line code, no dynamic indexing) ==================
// score for one (CT, KS): dot over this lane's 4 ch + partner quad via shfl_xor(16)
#define SC1(KARR, QF, CT, KS, P)                                                        \
  { f32x4 kv_ = unpk(KARR[KS][(CT) >> 1], (CT) & 1);                                    \
    float sp_ = QF[CT][0] * kv_[0] + QF[CT][1] * kv_[1] + QF[CT][2] * kv_[2] +          \
                QF[CT][3] * kv_[3];                                                     \
    sp_ += __shfl_xor(sp_, 16);                                                         \
    P = ((vb >> (KS)) & 1) ? sp_ : -1e30f; }

#define PV1(VARR, CT, KS, P, ACC)                                                       \
  { f32x4 vv_ = unpk(VARR[KS][(CT) >> 1], (CT) & 1);                                    \
    _Pragma("unroll") for (int r = 0; r < 4; r++) ACC[r] = fmaf(P, vv_[r], ACC[r]); }

// full attention for one output ct-tile (literal CT); OD is a named f32x4
#define ATT_CT(KARR, VARR, QF, CT, OD)                                                  \
  {                                                                                     \
    float p0, p1, p2, p3, p4;                                                           \
    SC1(KARR, QF, CT, 0, p0); SC1(KARR, QF, CT, 1, p1); SC1(KARR, QF, CT, 2, p2);       \
    SC1(KARR, QF, CT, 3, p3); SC1(KARR, QF, CT, 4, p4);                                 \
    float mx_ = fmaxf(fmaxf(fmaxf(p0, p1), fmaxf(p2, p3)), p4);                         \
    p0 = exp2f(p0 - mx_); p1 = exp2f(p1 - mx_); p2 = exp2f(p2 - mx_);                   \
    p3 = exp2f(p3 - mx_); p4 = exp2f(p4 - mx_);                                         \
    float ri_ = 1.0f / (p0 + p1 + p2 + p3 + p4);                                        \
    p0 *= ri_; p1 *= ri_; p2 *= ri_; p3 *= ri_; p4 *= ri_;                              \
    OD = (f32x4){0.f, 0.f, 0.f, 0.f};                                                   \
    PV1(VARR, CT, 0, p0, OD); PV1(VARR, CT, 1, p1, OD); PV1(VARR, CT, 2, p2, OD);       \
    PV1(VARR, CT, 3, p3, OD); PV1(VARR, CT, 4, p4, OD);                                 \
  }

// stage A for literal S: gather+pos+LN -> K,V packs (literal array writes)
#define KV_STAGE(S)                                                                     \
  {                                                                                     \
    f32x4 t[4], y[4];                                                                   \
    const bool vd = (vb >> (S)) & 1;                                                    \
    const float* fp = features + (size_t)min(ids[S], N - 1) * 64;                       \
    _Pragma("unroll")                                                                   \
    for (int ct = 0; ct < 4; ct++) {                                                    \
      f32x4 f = ld4(fp + 16 * ct + 4 * quad);                                           \
      f32x4 pv = ld4(pos_emb + (S) * 64 + 16 * ct + 4 * quad);                          \
      _Pragma("unroll")                                                                 \
      for (int r = 0; r < 4; r++) t[ct][r] = vd ? (f[r] + pv[r]) : 0.f;                 \
    }                                                                                   \
    lnT(t, y, sa_ln1_g, sa_ln1_b, quad);                                                \
    bf16x8 xl0 = mkpair(y[0], y[1]), xl1 = mkpair(y[2], y[3]);                          \
    f32x4 kt[4], vt[4];                                                                 \
    _Pragma("unroll")                                                                   \
    for (int ct = 0; ct < 4; ct++) {                                                    \
      f32x4 c = {0.f, 0.f, 0.f, 0.f};                                                   \
      c = MF(WSI[((4 + ct) * 2 + 0) * 64 + lane], xl0, c);                              \
      c = MF(WSI[((4 + ct) * 2 + 1) * 64 + lane], xl1, c);                              \
      f32x4 bb = ld4(self_in_b + 64 + 16 * ct + 4 * quad);                              \
      _Pragma("unroll")                                                                 \
      for (int r = 0; r < 4; r++) kt[ct][r] = c[r] + bb[r];                             \
      f32x4 c2 = {0.f, 0.f, 0.f, 0.f};                                                  \
      c2 = MF(WSI[((8 + ct) * 2 + 0) * 64 + lane], xl0, c2);                            \
      c2 = MF(WSI[((8 + ct) * 2 + 1) * 64 + lane], xl1, c2);                            \
      f32x4 bb2 = ld4(self_in_b + 128 + 16 * ct + 4 * quad);                            \
      _Pragma("unroll")                                                                 \
      for (int r = 0; r < 4; r++) vt[ct][r] = c2[r] + bb2[r];                           \
    }                                                                                   \
    Kp[S][0] = mkpair(kt[0], kt[1]); Kp[S][1] = mkpair(kt[2], kt[3]);                   \
    Vp[S][0] = mkpair(vt[0], vt[1]); Vp[S][1] = mkpair(vt[2], vt[3]);                   \
  }

// stage B for literal S: regather+LN -> Q, attention, PV, out-proj, residual, pool, TP
#define Q_STAGE(S)                                                                      \
  {                                                                                     \
    const bool vd = (vb >> (S)) & 1;                                                    \
    const float* fp = features + (size_t)min(ids[S], N - 1) * 64;                       \
    f32x4 t[4], y[4];                                                                   \
    _Pragma("unroll")                                                                   \
    for (int ct = 0; ct < 4; ct++) {                                                    \
      f32x4 f = ld4(fp + 16 * ct + 4 * quad);                                           \
      f32x4 pv = ld4(pos_emb + (S) * 64 + 16 * ct + 4 * quad);                          \
      _Pragma("unroll")                                                                 \
      for (int r = 0; r < 4; r++) t[ct][r] = vd ? (f[r] + pv[r]) : 0.f;                 \
    }                                                                                   \
    lnT(t, y, sa_ln1_g, sa_ln1_b, quad);                                                \
    bf16x8 xl0 = mkpair(y[0], y[1]), xl1 = mkpair(y[2], y[3]);                          \
    f32x4 qf[4];                                                                        \
    _Pragma("unroll")                                                                   \
    for (int ct = 0; ct < 4; ct++) {                                                    \
      f32x4 c = {0.f, 0.f, 0.f, 0.f};                                                   \
      c = MF(WSI[(ct * 2 + 0) * 64 + lane], xl0, c);                                    \
      c = MF(WSI[(ct * 2 + 1) * 64 + lane], xl1, c);                                    \
      f32x4 bb = ld4(self_in_b + 16 * ct + 4 * quad);                                   \
      _Pragma("unroll")                                                                 \
      for (int r = 0; r < 4; r++) qf[ct][r] = (c[r] + bb[r]) * QSCALE;                  \
    }                                                                                   \
    f32x4 oa0, oa1, oa2, oa3;                                                           \
    ATT_CT(Kp, Vp, qf, 0, oa0); ATT_CT(Kp, Vp, qf, 1, oa1);                             \
    ATT_CT(Kp, Vp, qf, 2, oa2); ATT_CT(Kp, Vp, qf, 3, oa3);                             \
    bf16x8 op0 = mkpair(oa0, oa1), op1 = mkpair(oa2, oa3);                              \
    f32x4 tpc[4];                                                                       \
    _Pragma("unroll")                                                                   \
    for (int ct = 0; ct < 4; ct++) {                                                    \
      f32x4 c = {0.f, 0.f, 0.f, 0.f};                                                   \
      c = MF(WSO[(ct * 2 + 0) * 64 + lane], op0, c);                                    \
      c = MF(WSO[(ct * 2 + 1) * 64 + lane], op1, c);                                    \
      f32x4 bb = ld4(self_out_b + 16 * ct + 4 * quad);                                  \
      _Pragma("unroll")                                                                 \
      for (int r = 0; r < 4; r++) {                                                     \
        float tp_ = c[r] + bb[r] + t[ct][r];                                            \
        tpc[ct][r] = tp_;                                                               \
        pool[ct][r] += vd ? tp_ : 0.f;                                                  \
      }                                                                                 \
    }                                                                                   \
    TP[S][0] = mkpair(tpc[0], tpc[1]); TP[S][1] = mkpair(tpc[2], tpc[3]);               \
  }

// cross K/V for literal S (reads TP[S] literal, writes Kc/Vc literal)
#define CKV_STAGE(S)                                                                    \
  {                                                                                     \
    f32x4 kt[4], vt[4];                                                                 \
    _Pragma("unroll")                                                                   \
    for (int ct = 0; ct < 4; ct++) {                                                    \
      f32x4 c = {0.f, 0.f, 0.f, 0.f};                                                   \
      c = MF(WCI[((4 + ct) * 2 + 0) * 64 + lane], TP[S][0], c);                         \
      c = MF(WCI[((4 + ct) * 2 + 1) * 64 + lane], TP[S][1], c);                         \
      f32x4 bb = ld4(cross_in_b + 64 + 16 * ct + 4 * quad);                             \
      _Pragma("unroll")                                                                 \
      for (int r = 0; r < 4; r++) kt[ct][r] = c[r] + bb[r];                             \
      f32x4 c2 = {0.f, 0.f, 0.f, 0.f};                                                  \
      c2 = MF(WCI[((8 + ct) * 2 + 0) * 64 + lane], TP[S][0], c2);                       \
      c2 = MF(WCI[((8 + ct) * 2 + 1) * 64 + lane], TP[S][1], c2);                       \
      f32x4 bb2 = ld4(cross_in_b + 128 + 16 * ct + 4 * quad);                           \
      _Pragma("unroll")                                                                 \
      for (int r = 0; r < 4; r++) vt[ct][r] = c2[r] + bb2[r];                           \
    }                                                                                   \
    Kc[S][0] = mkpair(kt[0], kt[1]); Kc[S][1] = mkpair(kt[2], kt[3]);                   \
    Vc[S][0] = mkpair(vt[0], vt[1]); Vc[S][1] = mkpair(vt[2], vt[3]);                   \
  }

// ffn internals (literal hidden-tile indices; named Hp0..Hp7)
#define FF_H2(CT, HD)                                                                   \
  { f32x4 c = {0.f, 0.f, 0.f, 0.f};                                                     \
    c = MF(W1[((CT) * 2 + 0) * 64 + lane], x0, c);                                      \
    c = MF(W1[((CT) * 2 + 1) * 64 + lane], x1, c);                                      \
    f32x4 bb = ld4(b1 + 16 * (CT) + 4 * quad);                                          \
    _Pragma("unroll")                                                                   \
    for (int r = 0; r < 4; r++) {                                                       \
      float v = c[r] + bb[r];                                                           \
      HD[r] = 0.5f * v * (1.0f + erff(v * 0.70710678118654752440f));                    \
    } }

#define FF_O(CT)                                                                        \
  { f32x4 c = {0.f, 0.f, 0.f, 0.f};                                                     \
    c = MF(W2[((CT) * 8 + 0) * 64 + lane], Hp0, c);                                     \
    c = MF(W2[((CT) * 8 + 1) * 64 + lane], Hp1, c);                                     \
    c = MF(W2[((CT) * 8 + 2) * 64 + lane], Hp2, c);                                     \
    c = MF(W2[((CT) * 8 + 3) * 64 + lane], Hp3, c);                                     \
    c = MF(W2[((CT) * 8 + 4) * 64 + lane], Hp4, c);                                     \
    c = MF(W2[((CT) * 8 + 5) * 64 + lane], Hp5, c);                                     \
    c = MF(W2[((CT) * 8 + 6) * 64 + lane], Hp6, c);                                     \
    c = MF(W2[((CT) * 8 + 7) * 64 + lane], Hp7, c);                                     \
    f32x4 bb = ld4(b2 + 16 * (CT) + 4 * quad);                                          \
    _Pragma("unroll")                                                                   \
    for (int r = 0; r < 4; r++) inst[CT][r] += c[r] + bb[r]; }

// transposed FF block: inst += FF(LN(inst)); all hidden tiles in named registers
__device__ __forceinline__ void ffnT(f32x4 (&inst)[4],
                                     const float* __restrict__ g, const float* __restrict__ b,
                                     const bf16x8* __restrict__ W1, const bf16x8* __restrict__ W2,
                                     const float* __restrict__ b1, const float* __restrict__ b2,
                                     int lane, int quad) {
  f32x4 y[4];
  lnT(inst, y, g, b, quad);
  bf16x8 x0 = mkpair(y[0], y[1]), x1 = mkpair(y[2], y[3]);
  f32x4 ha, hb;
  FF_H2(0, ha);  FF_H2(1, hb);  bf16x8 Hp0 = mkpair(ha, hb);
  FF_H2(2, ha);  FF_H2(3, hb);  bf16x8 Hp1 = mkpair(ha, hb);
  FF_H2(4, ha);  FF_H2(5, hb);  bf16x8 Hp2 = mkpair(ha, hb);
  FF_H2(6, ha);  FF_H2(7, hb);  bf16x8 Hp3 = mkpair(ha, hb);
  FF_H2(8, ha);  FF_H2(9, hb);  bf16x8 Hp4 = mkpair(ha, hb);
  FF_H2(10, ha); FF_H2(11, hb); bf16x8 Hp5 = mkpair(ha, hb);
  FF_H2(12, ha); FF_H2(13, hb); bf16x8 Hp6 = mkpair(ha, hb);
  FF_H2(14, ha); FF_H2(15, hb); bf16x8 Hp7 = mkpair(ha, hb);
  FF_O(0); FF_O(1); FF_O(2); FF_O(3);
}

// a-score for literal H into named float a##H
#define ASC(H)                                                                          \
  { float sp = 0.f;                                                                     \
    _Pragma("unroll")                                                                   \
    for (int ct = 0; ct < 4; ct++) {                                                    \
      f32x4 uu = ld4(uvec + (H) * 64 + 16 * ct + 4 * quad);                             \
      _Pragma("unroll")                                                                 \
      for (int r = 0; r < 4; r++) sp = fmaf(inst[ct][r], uu[r], sp);                    \
    }                                                                                   \
    sp = qsum(sp);                                                                      \
    a##H = sp > 0.f ? sp : 0.01f * sp; }

// ---------- per-edge transformer: one wave = 16 edges, fully register-resident ----------
// __launch_bounds__(64, 1): 512-VGPR budget per wave (gfx950 unified file; no spill
// through ~450 regs). The (64,2) variant capped arch VGPRs at 128 and spilled ~1.1KB
// per thread to scratch -> ~700MB of HBM writeback per dispatch (rounds 0-2 evidence:
// VGPR_Count pinned at 128, WRITE_SIZE ~700-850MB across 3 structural variants).
__global__ __launch_bounds__(64, 1)
void edge_kernel(const float* __restrict__ features, const float* __restrict__ pos_emb,
                 const float* __restrict__ self_in_b, const float* __restrict__ self_out_b,
                 const float* __restrict__ cross_in_b, const float* __restrict__ cross_out_b,
                 const float* __restrict__ sa_ln1_g, const float* __restrict__ sa_ln1_b,
                 const float* __restrict__ sa_ln2_g, const float* __restrict__ sa_ln2_b,
                 const float* __restrict__ ca_ln1_g, const float* __restrict__ ca_ln1_b,
                 const float* __restrict__ ca_ln2_g, const float* __restrict__ ca_ln2_b,
                 const float* __restrict__ sa_ff_b1, const float* __restrict__ sa_ff_b2,
                 const float* __restrict__ ca_ff_b1, const float* __restrict__ ca_ff_b2,
                 const int* __restrict__ midx, const int* __restrict__ dstv,
                 const float* __restrict__ ws,
                 float* __restrict__ inst_out, float* __restrict__ a_out,
                 unsigned int* __restrict__ seg_max, int E, int N) {
  const int lane = threadIdx.x;
  const int quad = lane >> 4, lo = lane & 15;
  const int e0 = blockIdx.x * 16;
  __shared__ float xp[16 * 68];

  const ushort_t* bw = (const ushort_t*)(ws + 33280);
  const bf16x8* WSI = (const bf16x8*)(bw);
  const bf16x8* WSO = (const bf16x8*)(bw + 12288);
  const bf16x8* W1S = (const bf16x8*)(bw + 16384);
  const bf16x8* W2S = (const bf16x8*)(bw + 32768);
  const bf16x8* WCI = (const bf16x8*)(bw + 49152);
  const bf16x8* WCO = (const bf16x8*)(bw + 61440);
  const bf16x8* W1C = (const bf16x8*)(bw + 65536);
  const bf16x8* W2C = (const bf16x8*)(bw + 81920);
  const float* uvec = ws + 32768;

  // per-lane edge meta: lane (quad, lo) owns edge e0+lo (replicated across quads)
  const bool ge = (e0 + lo) < E;
  const int eIdx = min(e0 + lo, E - 1);
  int ids[5];
  ids[0] = midx[eIdx * 5 + 0];
  ids[1] = midx[eIdx * 5 + 1];
  ids[2] = midx[eIdx * 5 + 2];
  ids[3] = midx[eIdx * 5 + 3];
  ids[4] = midx[eIdx * 5 + 4];
  int vb = 0;
  if (ids[0] != N && ge) vb |= 1;
  if (ids[1] != N && ge) vb |= 2;
  if (ids[2] != N && ge) vb |= 4;
  if (ids[3] != N && ge) vb |= 8;
  if (ids[4] != N && ge) vb |= 16;
  const int nv = __popc(vb);
  const int lp = max(nv - 1, 0);
  int lid = ids[0];
  lid = (lp == 1) ? ids[1] : lid;
  lid = (lp == 2) ? ids[2] : lid;
  lid = (lp == 3) ? ids[3] : lid;
  lid = (lp == 4) ? ids[4] : lid;

  // ---- stage A: K, V GEMMs (literal-indexed register arrays) ----
  bf16x8 Kp[5][2], Vp[5][2];
  KV_STAGE(0); KV_STAGE(1); KV_STAGE(2); KV_STAGE(3); KV_STAGE(4);

  // ---- stage B: per-qs attention + out-proj + residual + pool + TP ----
  f32x4 pool[4];
#pragma unroll
  for (int ct = 0; ct < 4; ct++) pool[ct] = (f32x4){0.f, 0.f, 0.f, 0.f};
  bf16x8 TP[5][2];
  Q_STAGE(0); Q_STAGE(1); Q_STAGE(2); Q_STAGE(3); Q_STAGE(4);

  f32x4 inst[4];
  {
    float rn = 1.0f / (float)max(nv, 1);
#pragma unroll
    for (int ct = 0; ct < 4; ct++)
#pragma unroll
      for (int r = 0; r < 4; r++) inst[ct][r] = pool[ct][r] * rn;
  }

  // ---- FF-sa ----
  ffnT(inst, sa_ln2_g, sa_ln2_b, W1S, W2S, sa_ff_b1, sa_ff_b2, lane, quad);

  // ---- cross attention ----
  {
    f32x4 tf[4], xq[4];
    const bool vdl = lid != N;
    const float* fp = features + (size_t)min(lid, N - 1) * 64;
#pragma unroll
    for (int ct = 0; ct < 4; ct++) {
      f32x4 f = ld4(fp + 16 * ct + 4 * quad);
#pragma unroll
      for (int r = 0; r < 4; r++) tf[ct][r] = vdl ? f[r] : 0.f;
    }
    lnT(tf, xq, ca_ln1_g, ca_ln1_b, quad);
    bf16x8 xq0 = mkpair(xq[0], xq[1]), xq1 = mkpair(xq[2], xq[3]);
    f32x4 qcf[4];
#pragma unroll
    for (int ct = 0; ct < 4; ct++) {
      f32x4 c = {0.f, 0.f, 0.f, 0.f};
      c = MF(WCI[(ct * 2 + 0) * 64 + lane], xq0, c);
      c = MF(WCI[(ct * 2 + 1) * 64 + lane], xq1, c);
      f32x4 bb = ld4(cross_in_b + 16 * ct + 4 * quad);
#pragma unroll
      for (int r = 0; r < 4; r++) qcf[ct][r] = (c[r] + bb[r]) * QSCALE;
    }
    bf16x8 Kc[5][2], Vc[5][2];
    CKV_STAGE(0); CKV_STAGE(1); CKV_STAGE(2); CKV_STAGE(3); CKV_STAGE(4);
    f32x4 cc0, cc1, cc2, cc3;
    ATT_CT(Kc, Vc, qcf, 0, cc0); ATT_CT(Kc, Vc, qcf, 1, cc1);
    ATT_CT(Kc, Vc, qcf, 2, cc2); ATT_CT(Kc, Vc, qcf, 3, cc3);
    bf16x8 cp0 = mkpair(cc0, cc1), cp1 = mkpair(cc2, cc3);
#pragma unroll
    for (int ct = 0; ct < 4; ct++) {
      f32x4 c = {0.f, 0.f, 0.f, 0.f};
      c = MF(WCO[(ct * 2 + 0) * 64 + lane], cp0, c);
      c = MF(WCO[(ct * 2 + 1) * 64 + lane], cp1, c);
      f32x4 bb = ld4(cross_out_b + 16 * ct + 4 * quad);
#pragma unroll
      for (int r = 0; r < 4; r++) inst[ct][r] += c[r] + bb[r];
    }
  }

  // ---- FF-ca ----
  ffnT(inst, ca_ln2_g, ca_ln2_b, W1C, W2C, ca_ff_b1, ca_ff_b2, lane, quad);

  // ---- a-scores: a[e][h] = leakyrelu(inst . u_h) (named scalars, literal H) ----
  float a0, a1, a2, a3, a4, a5, a6, a7;
  ASC(0); ASC(1); ASC(2); ASC(3); ASC(4); ASC(5); ASC(6); ASC(7);
  if (ge) {
    int dd = dstv[e0 + lo];
    float v0 = quad == 0 ? a0 : quad == 1 ? a2 : quad == 2 ? a4 : a6;
    float v1 = quad == 0 ? a1 : quad == 1 ? a3 : quad == 2 ? a5 : a7;
    atomicMax(&seg_max[dd * 8 + 2 * quad], fkey(v0));
    atomicMax(&seg_max[dd * 8 + 2 * quad + 1], fkey(v1));
    if (quad < 2) {
      f32x4 st = (quad == 0) ? (f32x4){a0, a1, a2, a3} : (f32x4){a4, a5, a6, a7};
      *(f32x4*)(a_out + (size_t)(e0 + lo) * 8 + 4 * quad) = st;
    }
  }

  // ---- inst_out: small LDS transpose ([ch][edge] -> [edge][ch]) + coalesced store ----
#pragma unroll
  for (int ct = 0; ct < 4; ct++)
    *(f32x4*)(&xp[lo * 68 + 16 * ct + 4 * quad]) = inst[ct];
  __syncthreads();
  {
    int er = lane >> 2, cb = (lane & 3) * 16;
    if (e0 + er < E) {
#pragma unroll
      for (int u = 0; u < 4; u++) {
        f32x4 v = *(const f32x4*)(&xp[er * 68 + cb + 4 * u]);
        *(f32x4*)(inst_out + (size_t)(e0 + er) * 64 + cb + 4 * u) = v;
      }
    }
  }
}

// ---------- edge softmax denominator ----------
__global__ void expsum_kernel(const float* __restrict__ a, const int* __restrict__ dstv,
                              const unsigned int* __restrict__ seg_max,
                              float* __restrict__ seg_sum, int E8) {
  int t = blockIdx.x * blockDim.x + threadIdx.x;
  if (t >= E8) return;
  int e = t >> 3, h = t & 7;
  int dd = dstv[e];
  float m = funkey(seg_max[dd * 8 + h]);
  atomicAdd(&seg_sum[dd * 8 + h], __expf(a[t] - m));
}

// ---------- scatter att-weighted inst_emb into z = d_out ----------
__global__ __launch_bounds__(256)
void scatter_kernel(const float* __restrict__ inst_emb, const float* __restrict__ a,
                    const unsigned int* __restrict__ seg_max, const float* __restrict__ seg_sum,
                    const int* __restrict__ dstv, float* __restrict__ out, int E) {
  const int wid = (blockIdx.x * blockDim.x + threadIdx.x) >> 6;
  const int lane = threadIdx.x & 63;
  if (wid >= E) return;
  int dd = dstv[wid];
  float iv = inst_emb[(size_t)wid * D + lane];
#pragma unroll
  for (int h = 0; h < 8; h++) {
    float m = funkey(seg_max[dd * 8 + h]);
    float s = seg_sum[dd * 8 + h];
    float att = __expf(a[wid * 8 + h] - m) / s;
    atomicAdd(&out[(size_t)dd * 512 + h * 64 + lane], att * iv);
  }
}

// ---------- in-place per-(n,h) transform: row = inst_w_h @ row, 4 nodes per wave ----------
__global__ __launch_bounds__(256)
void head_transform_kernel(const float* __restrict__ T_iw, float* __restrict__ out, int N) {
  const int wid = (blockIdx.x * blockDim.x + threadIdx.x) >> 6;
  const int lane = threadIdx.x & 63;
  const int h = wid & 7;
  const int n0 = (wid >> 3) * 4;
  if (n0 >= N) return;
  float z[4], acc[4];
#pragma unroll
  for (int j = 0; j < 4; j++) {
    z[j] = (n0 + j < N) ? out[((size_t)(n0 + j) * 8 + h) * D + lane] : 0.f;
    acc[j] = 0.f;
  }
  const vf4* P = (const vf4*)T_iw;
  for (int k4 = 0; k4 < 16; k4++) {
    vf4 w = P[k4 * 512 + h * 64 + lane];
#pragma unroll
    for (int u = 0; u < 4; u++) {
      int i = k4 * 4 + u;
#pragma unroll
      for (int j = 0; j < 4; j++) acc[j] = fmaf(bcast(z[j], i), w[u], acc[j]);
    }
  }
#pragma unroll
  for (int j = 0; j < 4; j++)
    if (n0 + j < N) out[((size_t)(n0 + j) * 8 + h) * D + lane] = acc[j];
}

extern "C" void kernel_launch(void* const* d_in, const int* in_sizes, int n_in,
                              void* d_out, int out_size, void* d_ws, size_t ws_size,
                              hipStream_t stream) {
  const float* features   = (const float*)d_in[0];
  const float* pos_emb    = (const float*)d_in[1];
  const float* self_in_w  = (const float*)d_in[2];
  const float* self_in_b  = (const float*)d_in[3];
  const float* self_out_w = (const float*)d_in[4];
  const float* self_out_b = (const float*)d_in[5];
  const float* cross_in_w = (const float*)d_in[6];
  const float* cross_in_b = (const float*)d_in[7];
  const float* cross_out_w= (const float*)d_in[8];
  const float* cross_out_b= (const float*)d_in[9];
  const float* sa_ln1_g = (const float*)d_in[10];
  const float* sa_ln1_b = (const float*)d_in[11];
  const float* sa_ln2_g = (const float*)d_in[12];
  const float* sa_ln2_b = (const float*)d_in[13];
  const float* ca_ln1_g = (const float*)d_in[14];
  const float* ca_ln1_b = (const float*)d_in[15];
  const float* ca_ln2_g = (const float*)d_in[16];
  const float* ca_ln2_b = (const float*)d_in[17];
  const float* sa_ff_w1 = (const float*)d_in[18];
  const float* sa_ff_b1 = (const float*)d_in[19];
  const float* sa_ff_w2 = (const float*)d_in[20];
  const float* sa_ff_b2 = (const float*)d_in[21];
  const float* ca_ff_w1 = (const float*)d_in[22];
  const float* ca_ff_b1 = (const float*)d_in[23];
  const float* ca_ff_w2 = (const float*)d_in[24];
  const float* ca_ff_b2 = (const float*)d_in[25];
  const float* inst_w   = (const float*)d_in[26];
  const float* attn_vec = (const float*)d_in[27];
  const int* midx = (const int*)d_in[28];
  const int* dstv = (const int*)d_in[29];

  const int N = in_sizes[0] / 64;
  const int E = in_sizes[29];

  // ws floats: [0..32767] T_iw | [32768..33279] u | [33280..82431] bf16 A-frag packs
  //            [131072...] inst_emb[E*64] | a[E*8] | seg_max[N*8] | seg_sum[N*8]
  float* wsf = (float*)d_ws;
  float* inst_emb = wsf + 131072;
  float* a_arr = inst_emb + (size_t)E * 64;
  unsigned int* seg_max = (unsigned int*)(a_arr + (size_t)E * 8);
  float* seg_sum = (float*)(seg_max + (size_t)N * 8);

  {
    int n4 = out_size / 4;
    zero_kernel<<<(n4 + 255) / 256, 256, 0, stream>>>((float4*)d_out, n4);
    int s4 = (N * 16) / 4;  // seg_max + seg_sum contiguous
    zero_kernel<<<(s4 + 255) / 256, 256, 0, stream>>>((float4*)seg_max, s4);
  }

  prep_kernel<<<(131584 + 255) / 256, 256, 0, stream>>>(
      self_in_w, self_out_w, sa_ff_w1, sa_ff_w2, cross_in_w, cross_out_w, ca_ff_w1, ca_ff_w2,
      inst_w, attn_vec, wsf);

  int nblk = (E + 15) / 16;  // 1 wave/block, 16 edges/wave
  edge_kernel<<<nblk, 64, 0, stream>>>(
      features, pos_emb, self_in_b, self_out_b, cross_in_b, cross_out_b, sa_ln1_g, sa_ln1_b,
      sa_ln2_g, sa_ln2_b, ca_ln1_g, ca_ln1_b, ca_ln2_g, ca_ln2_b, sa_ff_b1, sa_ff_b2, ca_ff_b1,
      ca_ff_b2, midx, dstv, wsf, inst_emb, a_arr, seg_max, E, N);

  expsum_kernel<<<(E * 8 + 255) / 256, 256, 0, stream>>>(a_arr, dstv, seg_max, seg_sum, E * 8);

  scatter_kernel<<<(E + 3) / 4, 256, 0, stream>>>(inst_emb, a_arr, seg_max, seg_sum, dstv,
                                                  (float*)d_out, E);

  int hwave = ((N + 3) / 4) * 8;
  head_transform_kernel<<<(hwave + 3) / 4, 256, 0, stream>>>(wsf, (float*)d_out, N);
}

// Round 7
// 1038.528 us; speedup vs baseline: 1.0598x; 1.0034x over previous
//
#include <hip/hip_runtime.h>
#include <math.h>

#define D 64
#define LOG2E 1.44269504088896340736f
#define QSCALE (0.35355339059327373f * LOG2E)

typedef float f32x4 __attribute__((ext_vector_type(4)));
typedef float vf4 __attribute__((ext_vector_type(4)));
typedef short bf16x8 __attribute__((ext_vector_type(8)));
typedef unsigned short ushort_t;
typedef unsigned int uint2v __attribute__((ext_vector_type(2)));

#define MF(a, b, c) __builtin_amdgcn_mfma_f32_16x16x32_bf16(a, b, c, 0, 0, 0)

// ---------- helpers ----------
__device__ __forceinline__ float bcast(float x, int i) {
  return __int_as_float(__builtin_amdgcn_readlane(__float_as_int(x), i));
}

// xor-16 partner sum (VALU permlane, no LDS round-trip). For A=B=x the two
// results are lane-wise {x[l&~16], x[l|16]}, so r0+r1 is the partner sum
// (bit-identical to x[l]+x[l^16] by IEEE commutativity).
__device__ __forceinline__ float xs16(float x) {
#if __has_builtin(__builtin_amdgcn_permlane16_swap)
  uint2v a = __builtin_amdgcn_permlane16_swap(__float_as_uint(x), __float_as_uint(x), false, false);
  return __uint_as_float(a[0]) + __uint_as_float(a[1]);
#else
  return x + __shfl_xor(x, 16);
#endif
}
__device__ __forceinline__ float xs32(float x) {
#if __has_builtin(__builtin_amdgcn_permlane32_swap)
  uint2v a = __builtin_amdgcn_permlane32_swap(__float_as_uint(x), __float_as_uint(x), false, false);
  return __uint_as_float(a[0]) + __uint_as_float(a[1]);
#else
  return x + __shfl_xor(x, 32);
#endif
}
__device__ __forceinline__ float qsum(float x) {  // sum over the 4 quads
  return xs32(xs16(x));
}

__device__ __forceinline__ ushort_t f2b(float f) {  // fp32 -> bf16 RTNE (prep only)
  unsigned int u = __float_as_uint(f);
  unsigned int r = (u + 0x7FFFu + ((u >> 16) & 1u)) >> 16;
  return (ushort_t)r;
}
// exact-RTNE packed bf16x2: round both words in-register, merge high halves
// with one v_perm_b32. Bit-identical to the scalar f2b path (cvt_pk was NOT:
// round-4 absmax regression 0.297 vs 0.0156).
__device__ __forceinline__ unsigned int pkrtne(float lo, float hi) {
  unsigned int a = __float_as_uint(lo);
  unsigned int b = __float_as_uint(hi);
  a = a + 0x7FFFu + ((a >> 16) & 1u);
  b = b + 0x7FFFu + ((b >> 16) & 1u);
  // dst bytes: [0]=a.b2 [1]=a.b3 [2]=b.b2 [3]=b.b3  ->  (f2b(hi)<<16)|f2b(lo)
  return __builtin_amdgcn_perm(b, a, 0x07060302u);
}
__device__ __forceinline__ f32x4 ld4(const float* __restrict__ p) { return *(const f32x4*)p; }
// monotonic unsigned key encoding for float atomicMax
__device__ __forceinline__ unsigned int fkey(float f) {
  unsigned int b = __float_as_uint(f);
  return (b & 0x80000000u) ? ~b : (b | 0x80000000u);
}
__device__ __forceinline__ float funkey(unsigned int k) {
  return __uint_as_float((k & 0x80000000u) ? (k ^ 0x80000000u) : ~k);
}
// pack two C-tiles (even ct, odd ct) into one x32 B-operand pair (4 words, exact RTNE)
__device__ __forceinline__ bf16x8 mkpair(const f32x4& ce, const f32x4& co) {
  union { bf16x8 v; unsigned int w[4]; } u;
  u.w[0] = pkrtne(ce[0], ce[1]);
  u.w[1] = pkrtne(ce[2], ce[3]);
  u.w[2] = pkrtne(co[0], co[1]);
  u.w[3] = pkrtne(co[2], co[3]);
  return u.v;
}
__device__ __forceinline__ f32x4 unpk(bf16x8 p, int half) {  // half 0 = even ct, 1 = odd ct
  union { bf16x8 v; unsigned int w[4]; } u;
  u.v = p;
  unsigned int w0 = u.w[half * 2], w1 = u.w[half * 2 + 1];
  f32x4 r;
  r[0] = __uint_as_float(w0 << 16);
  r[1] = __uint_as_float(w0 & 0xFFFF0000u);
  r[2] = __uint_as_float(w1 << 16);
  r[3] = __uint_as_float(w1 & 0xFFFF0000u);
  return r;
}

// transposed-layout LayerNorm: x,y are 16 channel values/lane; stats over 64 ch
__device__ __forceinline__ void lnT(const f32x4 (&x)[4], f32x4 (&y)[4],
                                    const float* __restrict__ g, const float* __restrict__ b,
                                    int quad) {
  float s1 = 0.f, s2 = 0.f;
#pragma unroll
  for (int ct = 0; ct < 4; ct++)
#pragma unroll
    for (int r = 0; r < 4; r++) { s1 += x[ct][r]; s2 += x[ct][r] * x[ct][r]; }
  s1 = qsum(s1);
  s2 = qsum(s2);
  float mean = s1 * 0.015625f;
  float var = s2 * 0.015625f - mean * mean;
  float rs = rsqrtf(var + 1e-5f);
#pragma unroll
  for (int ct = 0; ct < 4; ct++) {
    f32x4 gv = ld4(g + 16 * ct + 4 * quad);
    f32x4 bv = ld4(b + 16 * ct + 4 * quad);
#pragma unroll
    for (int r = 0; r < 4; r++) y[ct][r] = (x[ct][r] - mean) * rs * gv[r] + bv[r];
  }
}

// ---------- zero fill ----------
__global__ void zero_kernel(float4* __restrict__ p, int n4) {
  int t = blockIdx.x * blockDim.x + threadIdx.x;
  if (t < n4) p[t] = make_float4(0.f, 0.f, 0.f, 0.f);
}

// ---------- prep: pack weights as x32 A-frags with the k-slot permutation ----------
__global__ void prep_kernel(const float* __restrict__ si, const float* __restrict__ so,
                            const float* __restrict__ w1s, const float* __restrict__ w2s,
                            const float* __restrict__ ci, const float* __restrict__ co,
                            const float* __restrict__ w1c, const float* __restrict__ w2c,
                            const float* __restrict__ iw, const float* __restrict__ av,
                            float* __restrict__ ws) {
  int t = blockIdx.x * blockDim.x + threadIdx.x;
  ushort_t* bw = (ushort_t*)(ws + 33280);
  if (t < 98304) {
    const float* src;
    int base, cs;
    int l = t;
    if      (l < 12288) { src = si;  base = 0;     cs = 6; }
    else if (l < 16384) { src = so;  base = 12288; cs = 6; l -= 12288; }
    else if (l < 32768) { src = w1s; base = 16384; cs = 6; l -= 16384; }
    else if (l < 49152) { src = w2s; base = 32768; cs = 8; l -= 32768; }
    else if (l < 61440) { src = ci;  base = 49152; cs = 6; l -= 49152; }
    else if (l < 65536) { src = co;  base = 61440; cs = 6; l -= 61440; }
    else if (l < 81920) { src = w1c; base = 65536; cs = 6; l -= 65536; }
    else                { src = w2c; base = 81920; cs = 8; l -= 81920; }
    int c = l >> cs, k = l & ((1 << cs) - 1);
    int T = (1 << cs) >> 5;
    int ct = c >> 4, m = c & 15, tt = k >> 5, rem = k & 31;
    int quad = (rem >> 2) & 3;
    int j = (((rem >> 4) & 1) << 2) | (rem & 3);
    bw[base + (size_t)((ct * T + tt) * 64 + quad * 16 + m) * 8 + j] = f2b(src[l]);
  } else if (t < 131072) {
    int l = t - 98304;
    int c = l >> 6, k = l & 63;
    ws[(k >> 2) * 2048 + c * 4 + (k & 3)] = iw[l];
  } else if (t < 131584) {
    int l = t - 131072;
    int h = l >> 6, k = l & 63;
    float acc = 0.f;
    for (int c = 0; c < 64; c++) acc += av[h * 64 + c] * iw[(h * 64 + c) * 64 + k];
    ws[32768 + h * 64 + k] = acc;
  }
}

// ================== literal-index macros (straight-line code, no dynamic indexing) ==================
// score for one (CT, KS): dot over this lane's 4 ch + partner quad via permlane16 sum
#define SC1(KARR, QF, CT, KS, P)                                                        \
  { f32x4 kv_ = unpk(KARR[KS][(CT) >> 1], (CT) & 1);                                    \
    float sp_ = QF[CT][0] * kv_[0] + QF[CT][1] * kv_[1] + QF[CT][2] * kv_[2] +          \
                QF[CT][3] * kv_[3];                                                     \
    sp_ = xs16(sp_);                                                                    \
    P = ((vb >> (KS)) & 1) ? sp_ : -1e30f; }

#define PV1(VARR, CT, KS, P, ACC)                                                       \
  { f32x4 vv_ = unpk(VARR[KS][(CT) >> 1], (CT) & 1);                                    \
    _Pragma("unroll") for (int r = 0; r < 4; r++) ACC[r] = fmaf(P, vv_[r], ACC[r]); }

// full attention for one output ct-tile (literal CT); OD is a named f32x4
#define ATT_CT(KARR, VARR, QF, CT, OD)                                                  \
  {                                                                                     \
    float p0, p1, p2, p3, p4;                                                           \
    SC1(KARR, QF, CT, 0, p0); SC1(KARR, QF, CT, 1, p1); SC1(KARR, QF, CT, 2, p2);       \
    SC1(KARR, QF, CT, 3, p3); SC1(KARR, QF, CT, 4, p4);                                 \
    float mx_ = fmaxf(fmaxf(fmaxf(p0, p1), fmaxf(p2, p3)), p4);                         \
    p0 = exp2f(p0 - mx_); p1 = exp2f(p1 - mx_); p2 = exp2f(p2 - mx_);                   \
    p3 = exp2f(p3 - mx_); p4 = exp2f(p4 - mx_);                                         \
    float ri_ = 1.0f / (p0 + p1 + p2 + p3 + p4);                                        \
    p0 *= ri_; p1 *= ri_; p2 *= ri_; p3 *= ri_; p4 *= ri_;                              \
    OD = (f32x4){0.f, 0.f, 0.f, 0.f};                                                   \
    PV1(VARR, CT, 0, p0, OD); PV1(VARR, CT, 1, p1, OD); PV1(VARR, CT, 2, p2, OD);       \
    PV1(VARR, CT, 3, p3, OD); PV1(VARR, CT, 4, p4, OD);                                 \
  }

// stage A for literal S: gather+pos+LN -> K,V packs (literal array writes)
#define KV_STAGE(S)                                                                     \
  {                                                                                     \
    f32x4 t[4], y[4];                                                                   \
    const bool vd = (vb >> (S)) & 1;                                                    \
    const float* fp = features + (size_t)min(ids[S], N - 1) * 64;                       \
    _Pragma("unroll")                                                                   \
    for (int ct = 0; ct < 4; ct++) {                                                    \
      f32x4 f = ld4(fp + 16 * ct + 4 * quad);                                           \
      f32x4 pv = ld4(pos_emb + (S) * 64 + 16 * ct + 4 * quad);                          \
      _Pragma("unroll")                                                                 \
      for (int r = 0; r < 4; r++) t[ct][r] = vd ? (f[r] + pv[r]) : 0.f;                 \
    }                                                                                   \
    lnT(t, y, sa_ln1_g, sa_ln1_b, quad);                                                \
    bf16x8 xl0 = mkpair(y[0], y[1]), xl1 = mkpair(y[2], y[3]);                          \
    f32x4 kt[4], vt[4];                                                                 \
    _Pragma("unroll")                                                                   \
    for (int ct = 0; ct < 4; ct++) {                                                    \
      f32x4 c = {0.f, 0.f, 0.f, 0.f};                                                   \
      c = MF(WSI[((4 + ct) * 2 + 0) * 64 + lane], xl0, c);                              \
      c = MF(WSI[((4 + ct) * 2 + 1) * 64 + lane], xl1, c);                              \
      f32x4 bb = ld4(self_in_b + 64 + 16 * ct + 4 * quad);                              \
      _Pragma("unroll")                                                                 \
      for (int r = 0; r < 4; r++) kt[ct][r] = c[r] + bb[r];                             \
      f32x4 c2 = {0.f, 0.f, 0.f, 0.f};                                                  \
      c2 = MF(WSI[((8 + ct) * 2 + 0) * 64 + lane], xl0, c2);                            \
      c2 = MF(WSI[((8 + ct) * 2 + 1) * 64 + lane], xl1, c2);                            \
      f32x4 bb2 = ld4(self_in_b + 128 + 16 * ct + 4 * quad);                            \
      _Pragma("unroll")                                                                 \
      for (int r = 0; r < 4; r++) vt[ct][r] = c2[r] + bb2[r];                           \
    }                                                                                   \
    Kp[S][0] = mkpair(kt[0], kt[1]); Kp[S][1] = mkpair(kt[2], kt[3]);                   \
    Vp[S][0] = mkpair(vt[0], vt[1]); Vp[S][1] = mkpair(vt[2], vt[3]);                   \
  }

// stage B for literal S: regather+LN -> Q, attention, PV, out-proj, residual, pool, TP
#define Q_STAGE(S)                                                                      \
  {                                                                                     \
    const bool vd = (vb >> (S)) & 1;                                                    \
    const float* fp = features + (size_t)min(ids[S], N - 1) * 64;                       \
    f32x4 t[4], y[4];                                                                   \
    _Pragma("unroll")                                                                   \
    for (int ct = 0; ct < 4; ct++) {                                                    \
      f32x4 f = ld4(fp + 16 * ct + 4 * quad);                                           \
      f32x4 pv = ld4(pos_emb + (S) * 64 + 16 * ct + 4 * quad);                          \
      _Pragma("unroll")                                                                 \
      for (int r = 0; r < 4; r++) t[ct][r] = vd ? (f[r] + pv[r]) : 0.f;                 \
    }                                                                                   \
    lnT(t, y, sa_ln1_g, sa_ln1_b, quad);                                                \
    bf16x8 xl0 = mkpair(y[0], y[1]), xl1 = mkpair(y[2], y[3]);                          \
    f32x4 qf[4];                                                                        \
    _Pragma("unroll")                                                                   \
    for (int ct = 0; ct < 4; ct++) {                                                    \
      f32x4 c = {0.f, 0.f, 0.f, 0.f};                                                   \
      c = MF(WSI[(ct * 2 + 0) * 64 + lane], xl0, c);                                    \
      c = MF(WSI[(ct * 2 + 1) * 64 + lane], xl1, c);                                    \
      f32x4 bb = ld4(self_in_b + 16 * ct + 4 * quad);                                   \
      _Pragma("unroll")                                                                 \
      for (int r = 0; r < 4; r++) qf[ct][r] = (c[r] + bb[r]) * QSCALE;                  \
    }                                                                                   \
    f32x4 oa0, oa1, oa2, oa3;                                                           \
    ATT_CT(Kp, Vp, qf, 0, oa0); ATT_CT(Kp, Vp, qf, 1, oa1);                             \
    ATT_CT(Kp, Vp, qf, 2, oa2); ATT_CT(Kp, Vp, qf, 3, oa3);                             \
    bf16x8 op0 = mkpair(oa0, oa1), op1 = mkpair(oa2, oa3);                              \
    f32x4 tpc[4];                                                                       \
    _Pragma("unroll")                                                                   \
    for (int ct = 0; ct < 4; ct++) {                                                    \
      f32x4 c = {0.f, 0.f, 0.f, 0.f};                                                   \
      c = MF(WSO[(ct * 2 + 0) * 64 + lane], op0, c);                                    \
      c = MF(WSO[(ct * 2 + 1) * 64 + lane], op1, c);                                    \
      f32x4 bb = ld4(self_out_b + 16 * ct + 4 * quad);                                  \
      _Pragma("unroll")                                                                 \
      for (int r = 0; r < 4; r++) {                                                     \
        float tp_ = c[r] + bb[r] + t[ct][r];                                            \
        tpc[ct][r] = tp_;                                                               \
        pool[ct][r] += vd ? tp_ : 0.f;                                                  \
      }                                                                                 \
    }                                                                                   \
    TP[S][0] = mkpair(tpc[0], tpc[1]); TP[S][1] = mkpair(tpc[2], tpc[3]);               \
  }

// cross K/V for literal S (reads TP[S] literal, writes Kc/Vc literal)
#define CKV_STAGE(S)                                                                    \
  {                                                                                     \
    f32x4 kt[4], vt[4];                                                                 \
    _Pragma("unroll")                                                                   \
    for (int ct = 0; ct < 4; ct++) {                                                    \
      f32x4 c = {0.f, 0.f, 0.f, 0.f};                                                   \
      c = MF(WCI[((4 + ct) * 2 + 0) * 64 + lane], TP[S][0], c);                         \
      c = MF(WCI[((4 + ct) * 2 + 1) * 64 + lane], TP[S][1], c);                         \
      f32x4 bb = ld4(cross_in_b + 64 + 16 * ct + 4 * quad);                             \
      _Pragma("unroll")                                                                 \
      for (int r = 0; r < 4; r++) kt[ct][r] = c[r] + bb[r];                             \
      f32x4 c2 = {0.f, 0.f, 0.f, 0.f};                                                  \
      c2 = MF(WCI[((8 + ct) * 2 + 0) * 64 + lane], TP[S][0], c2);                       \
      c2 = MF(WCI[((8 + ct) * 2 + 1) * 64 + lane], TP[S][1], c2);                       \
      f32x4 bb2 = ld4(cross_in_b + 128 + 16 * ct + 4 * quad);                           \
      _Pragma("unroll")                                                                 \
      for (int r = 0; r < 4; r++) vt[ct][r] = c2[r] + bb2[r];                           \
    }                                                                                   \
    Kc[S][0] = mkpair(kt[0], kt[1]); Kc[S][1] = mkpair(kt[2], kt[3]);                   \
    Vc[S][0] = mkpair(vt[0], vt[1]); Vc[S][1] = mkpair(vt[2], vt[3]);                   \
  }

// ffn internals (literal hidden-tile indices; named Hp0..Hp7)
#define FF_H2(CT, HD)                                                                   \
  { f32x4 c = {0.f, 0.f, 0.f, 0.f};                                                     \
    c = MF(W1[((CT) * 2 + 0) * 64 + lane], x0, c);                                      \
    c = MF(W1[((CT) * 2 + 1) * 64 + lane], x1, c);                                      \
    f32x4 bb = ld4(b1 + 16 * (CT) + 4 * quad);                                          \
    _Pragma("unroll")                                                                   \
    for (int r = 0; r < 4; r++) {                                                       \
      float v = c[r] + bb[r];                                                           \
      HD[r] = 0.5f * v * (1.0f + erff(v * 0.70710678118654752440f));                    \
    } }

#define FF_O(CT)                                                                        \
  { f32x4 c = {0.f, 0.f, 0.f, 0.f};                                                     \
    c = MF(W2[((CT) * 8 + 0) * 64 + lane], Hp0, c);                                     \
    c = MF(W2[((CT) * 8 + 1) * 64 + lane], Hp1, c);                                     \
    c = MF(W2[((CT) * 8 + 2) * 64 + lane], Hp2, c);                                     \
    c = MF(W2[((CT) * 8 + 3) * 64 + lane], Hp3, c);                                     \
    c = MF(W2[((CT) * 8 + 4) * 64 + lane], Hp4, c);                                     \
    c = MF(W2[((CT) * 8 + 5) * 64 + lane], Hp5, c);                                     \
    c = MF(W2[((CT) * 8 + 6) * 64 + lane], Hp6, c);                                     \
    c = MF(W2[((CT) * 8 + 7) * 64 + lane], Hp7, c);                                     \
    f32x4 bb = ld4(b2 + 16 * (CT) + 4 * quad);                                          \
    _Pragma("unroll")                                                                   \
    for (int r = 0; r < 4; r++) inst[CT][r] += c[r] + bb[r]; }

// transposed FF block: inst += FF(LN(inst)); all hidden tiles in named registers
__device__ __forceinline__ void ffnT(f32x4 (&inst)[4],
                                     const float* __restrict__ g, const float* __restrict__ b,
                                     const bf16x8* __restrict__ W1, const bf16x8* __restrict__ W2,
                                     const float* __restrict__ b1, const float* __restrict__ b2,
                                     int lane, int quad) {
  f32x4 y[4];
  lnT(inst, y, g, b, quad);
  bf16x8 x0 = mkpair(y[0], y[1]), x1 = mkpair(y[2], y[3]);
  f32x4 ha, hb;
  FF_H2(0, ha);  FF_H2(1, hb);  bf16x8 Hp0 = mkpair(ha, hb);
  FF_H2(2, ha);  FF_H2(3, hb);  bf16x8 Hp1 = mkpair(ha, hb);
  FF_H2(4, ha);  FF_H2(5, hb);  bf16x8 Hp2 = mkpair(ha, hb);
  FF_H2(6, ha);  FF_H2(7, hb);  bf16x8 Hp3 = mkpair(ha, hb);
  FF_H2(8, ha);  FF_H2(9, hb);  bf16x8 Hp4 = mkpair(ha, hb);
  FF_H2(10, ha); FF_H2(11, hb); bf16x8 Hp5 = mkpair(ha, hb);
  FF_H2(12, ha); FF_H2(13, hb); bf16x8 Hp6 = mkpair(ha, hb);
  FF_H2(14, ha); FF_H2(15, hb); bf16x8 Hp7 = mkpair(ha, hb);
  FF_O(0); FF_O(1); FF_O(2); FF_O(3);
}

// a-score for literal H into named float a##H
#define ASC(H)                                                                          \
  { float sp = 0.f;                                                                     \
    _Pragma("unroll")                                                                   \
    for (int ct = 0; ct < 4; ct++) {                                                    \
      f32x4 uu = ld4(uvec + (H) * 64 + 16 * ct + 4 * quad);                             \
      _Pragma("unroll")                                                                 \
      for (int r = 0; r < 4; r++) sp = fmaf(inst[ct][r], uu[r], sp);                    \
    }                                                                                   \
    sp = qsum(sp);                                                                      \
    a##H = sp > 0.f ? sp : 0.01f * sp; }

// ---------- per-edge transformer: one wave = 16 edges, fully register-resident ----------
// __launch_bounds__(64, 1): 512-VGPR budget; round-3 evidence: VGPR 256, zero spill
// (WRITE_SIZE 738MB -> 79MB). VALU reduction via exact-RTNE perm-pack, word-wise
// unpack, and permlane swaps (all bit-identical to the round-3 passing math).
__global__ __launch_bounds__(64, 1)
void edge_kernel(const float* __restrict__ features, const float* __restrict__ pos_emb,
                 const float* __restrict__ self_in_b, const float* __restrict__ self_out_b,
                 const float* __restrict__ cross_in_b, const float* __restrict__ cross_out_b,
                 const float* __restrict__ sa_ln1_g, const float* __restrict__ sa_ln1_b,
                 const float* __restrict__ sa_ln2_g, const float* __restrict__ sa_ln2_b,
                 const float* __restrict__ ca_ln1_g, const float* __restrict__ ca_ln1_b,
                 const float* __restrict__ ca_ln2_g, const float* __restrict__ ca_ln2_b,
                 const float* __restrict__ sa_ff_b1, const float* __restrict__ sa_ff_b2,
                 const float* __restrict__ ca_ff_b1, const float* __restrict__ ca_ff_b2,
                 const int* __restrict__ midx, const int* __restrict__ dstv,
                 const float* __restrict__ ws,
                 float* __restrict__ inst_out, float* __restrict__ a_out,
                 unsigned int* __restrict__ seg_max, int E, int N) {
  const int lane = threadIdx.x;
  const int quad = lane >> 4, lo = lane & 15;
  const int e0 = blockIdx.x * 16;
  __shared__ float xp[16 * 68];

  const ushort_t* bw = (const ushort_t*)(ws + 33280);
  const bf16x8* WSI = (const bf16x8*)(bw);
  const bf16x8* WSO = (const bf16x8*)(bw + 12288);
  const bf16x8* W1S = (const bf16x8*)(bw + 16384);
  const bf16x8* W2S = (const bf16x8*)(bw + 32768);
  const bf16x8* WCI = (const bf16x8*)(bw + 49152);
  const bf16x8* WCO = (const bf16x8*)(bw + 61440);
  const bf16x8* W1C = (const bf16x8*)(bw + 65536);
  const bf16x8* W2C = (const bf16x8*)(bw + 81920);
  const float* uvec = ws + 32768;

  // per-lane edge meta: lane (quad, lo) owns edge e0+lo (replicated across quads)
  const bool ge = (e0 + lo) < E;
  const int eIdx = min(e0 + lo, E - 1);
  int ids[5];
  ids[0] = midx[eIdx * 5 + 0];
  ids[1] = midx[eIdx * 5 + 1];
  ids[2] = midx[eIdx * 5 + 2];
  ids[3] = midx[eIdx * 5 + 3];
  ids[4] = midx[eIdx * 5 + 4];
  int vb = 0;
  if (ids[0] != N && ge) vb |= 1;
  if (ids[1] != N && ge) vb |= 2;
  if (ids[2] != N && ge) vb |= 4;
  if (ids[3] != N && ge) vb |= 8;
  if (ids[4] != N && ge) vb |= 16;
  const int nv = __popc(vb);
  const int lp = max(nv - 1, 0);
  int lid = ids[0];
  lid = (lp == 1) ? ids[1] : lid;
  lid = (lp == 2) ? ids[2] : lid;
  lid = (lp == 3) ? ids[3] : lid;
  lid = (lp == 4) ? ids[4] : lid;

  // ---- stage A: K, V GEMMs (literal-indexed register arrays) ----
  bf16x8 Kp[5][2], Vp[5][2];
  KV_STAGE(0); KV_STAGE(1); KV_STAGE(2); KV_STAGE(3); KV_STAGE(4);

  // ---- stage B: per-qs attention + out-proj + residual + pool + TP ----
  f32x4 pool[4];
#pragma unroll
  for (int ct = 0; ct < 4; ct++) pool[ct] = (f32x4){0.f, 0.f, 0.f, 0.f};
  bf16x8 TP[5][2];
  Q_STAGE(0); Q_STAGE(1); Q_STAGE(2); Q_STAGE(3); Q_STAGE(4);

  f32x4 inst[4];
  {
    float rn = 1.0f / (float)max(nv, 1);
#pragma unroll
    for (int ct = 0; ct < 4; ct++)
#pragma unroll
      for (int r = 0; r < 4; r++) inst[ct][r] = pool[ct][r] * rn;
  }

  // ---- FF-sa ----
  ffnT(inst, sa_ln2_g, sa_ln2_b, W1S, W2S, sa_ff_b1, sa_ff_b2, lane, quad);

  // ---- cross attention ----
  {
    f32x4 tf[4], xq[4];
    const bool vdl = lid != N;
    const float* fp = features + (size_t)min(lid, N - 1) * 64;
#pragma unroll
    for (int ct = 0; ct < 4; ct++) {
      f32x4 f = ld4(fp + 16 * ct + 4 * quad);
#pragma unroll
      for (int r = 0; r < 4; r++) tf[ct][r] = vdl ? f[r] : 0.f;
    }
    lnT(tf, xq, ca_ln1_g, ca_ln1_b, quad);
    bf16x8 xq0 = mkpair(xq[0], xq[1]), xq1 = mkpair(xq[2], xq[3]);
    f32x4 qcf[4];
#pragma unroll
    for (int ct = 0; ct < 4; ct++) {
      f32x4 c = {0.f, 0.f, 0.f, 0.f};
      c = MF(WCI[(ct * 2 + 0) * 64 + lane], xq0, c);
      c = MF(WCI[(ct * 2 + 1) * 64 + lane], xq1, c);
      f32x4 bb = ld4(cross_in_b + 16 * ct + 4 * quad);
#pragma unroll
      for (int r = 0; r < 4; r++) qcf[ct][r] = (c[r] + bb[r]) * QSCALE;
    }
    bf16x8 Kc[5][2], Vc[5][2];
    CKV_STAGE(0); CKV_STAGE(1); CKV_STAGE(2); CKV_STAGE(3); CKV_STAGE(4);
    f32x4 cc0, cc1, cc2, cc3;
    ATT_CT(Kc, Vc, qcf, 0, cc0); ATT_CT(Kc, Vc, qcf, 1, cc1);
    ATT_CT(Kc, Vc, qcf, 2, cc2); ATT_CT(Kc, Vc, qcf, 3, cc3);
    bf16x8 cp0 = mkpair(cc0, cc1), cp1 = mkpair(cc2, cc3);
#pragma unroll
    for (int ct = 0; ct < 4; ct++) {
      f32x4 c = {0.f, 0.f, 0.f, 0.f};
      c = MF(WCO[(ct * 2 + 0) * 64 + lane], cp0, c);
      c = MF(WCO[(ct * 2 + 1) * 64 + lane], cp1, c);
      f32x4 bb = ld4(cross_out_b + 16 * ct + 4 * quad);
#pragma unroll
      for (int r = 0; r < 4; r++) inst[ct][r] += c[r] + bb[r];
    }
  }

  // ---- FF-ca ----
  ffnT(inst, ca_ln2_g, ca_ln2_b, W1C, W2C, ca_ff_b1, ca_ff_b2, lane, quad);

  // ---- a-scores: a[e][h] = leakyrelu(inst . u_h) (named scalars, literal H) ----
  float a0, a1, a2, a3, a4, a5, a6, a7;
  ASC(0); ASC(1); ASC(2); ASC(3); ASC(4); ASC(5); ASC(6); ASC(7);
  if (ge) {
    int dd = dstv[e0 + lo];
    float v0 = quad == 0 ? a0 : quad == 1 ? a2 : quad == 2 ? a4 : a6;
    float v1 = quad == 0 ? a1 : quad == 1 ? a3 : quad == 2 ? a5 : a7;
    atomicMax(&seg_max[dd * 8 + 2 * quad], fkey(v0));
    atomicMax(&seg_max[dd * 8 + 2 * quad + 1], fkey(v1));
    if (quad < 2) {
      f32x4 st = (quad == 0) ? (f32x4){a0, a1, a2, a3} : (f32x4){a4, a5, a6, a7};
      *(f32x4*)(a_out + (size_t)(e0 + lo) * 8 + 4 * quad) = st;
    }
  }

  // ---- inst_out: small LDS transpose ([ch][edge] -> [edge][ch]) + coalesced store ----
#pragma unroll
  for (int ct = 0; ct < 4; ct++)
    *(f32x4*)(&xp[lo * 68 + 16 * ct + 4 * quad]) = inst[ct];
  __syncthreads();
  {
    int er = lane >> 2, cb = (lane & 3) * 16;
    if (e0 + er < E) {
#pragma unroll
      for (int u = 0; u < 4; u++) {
        f32x4 v = *(const f32x4*)(&xp[er * 68 + cb + 4 * u]);
        *(f32x4*)(inst_out + (size_t)(e0 + er) * 64 + cb + 4 * u) = v;
      }
    }
  }
}

// ---------- edge softmax denominator ----------
__global__ void expsum_kernel(const float* __restrict__ a, const int* __restrict__ dstv,
                              const unsigned int* __restrict__ seg_max,
                              float* __restrict__ seg_sum, int E8) {
  int t = blockIdx.x * blockDim.x + threadIdx.x;
  if (t >= E8) return;
  int e = t >> 3, h = t & 7;
  int dd = dstv[e];
  float m = funkey(seg_max[dd * 8 + h]);
  atomicAdd(&seg_sum[dd * 8 + h], __expf(a[t] - m));
}

// ---------- scatter att-weighted inst_emb into z = d_out ----------
__global__ __launch_bounds__(256)
void scatter_kernel(const float* __restrict__ inst_emb, const float* __restrict__ a,
                    const unsigned int* __restrict__ seg_max, const float* __restrict__ seg_sum,
                    const int* __restrict__ dstv, float* __restrict__ out, int E) {
  const int wid = (blockIdx.x * blockDim.x + threadIdx.x) >> 6;
  const int lane = threadIdx.x & 63;
  if (wid >= E) return;
  int dd = dstv[wid];
  float iv = inst_emb[(size_t)wid * D + lane];
#pragma unroll
  for (int h = 0; h < 8; h++) {
    float m = funkey(seg_max[dd * 8 + h]);
    float s = seg_sum[dd * 8 + h];
    float att = __expf(a[wid * 8 + h] - m) / s;
    atomicAdd(&out[(size_t)dd * 512 + h * 64 + lane], att * iv);
  }
}

// ---------- in-place per-(n,h) transform: row = inst_w_h @ row, 4 nodes per wave ----------
__global__ __launch_bounds__(256)
void head_transform_kernel(const float* __restrict__ T_iw, float* __restrict__ out, int N) {
  const int wid = (blockIdx.x * blockDim.x + threadIdx.x) >> 6;
  const int lane = threadIdx.x & 63;
  const int h = wid & 7;
  const int n0 = (wid >> 3) * 4;
  if (n0 >= N) return;
  float z[4], acc[4];
#pragma unroll
  for (int j = 0; j < 4; j++) {
    z[j] = (n0 + j < N) ? out[((size_t)(n0 + j) * 8 + h) * D + lane] : 0.f;
    acc[j] = 0.f;
  }
  const vf4* P = (const vf4*)T_iw;
  for (int k4 = 0; k4 < 16; k4++) {
    vf4 w = P[k4 * 512 + h * 64 + lane];
#pragma unroll
    for (int u = 0; u < 4; u++) {
      int i = k4 * 4 + u;
#pragma unroll
      for (int j = 0; j < 4; j++) acc[j] = fmaf(bcast(z[j], i), w[u], acc[j]);
    }
  }
#pragma unroll
  for (int j = 0; j < 4; j++)
    if (n0 + j < N) out[((size_t)(n0 + j) * 8 + h) * D + lane] = acc[j];
}

extern "C" void kernel_launch(void* const* d_in, const int* in_sizes, int n_in,
                              void* d_out, int out_size, void* d_ws, size_t ws_size,
                              hipStream_t stream) {
  const float* features   = (const float*)d_in[0];
  const float* pos_emb    = (const float*)d_in[1];
  const float* self_in_w  = (const float*)d_in[2];
  const float* self_in_b  = (const float*)d_in[3];
  const float* self_out_w = (const float*)d_in[4];
  const float* self_out_b = (const float*)d_in[5];
  const float* cross_in_w = (const float*)d_in[6];
  const float* cross_in_b = (const float*)d_in[7];
  const float* cross_out_w= (const float*)d_in[8];
  const float* cross_out_b= (const float*)d_in[9];
  const float* sa_ln1_g = (const float*)d_in[10];
  const float* sa_ln1_b = (const float*)d_in[11];
  const float* sa_ln2_g = (const float*)d_in[12];
  const float* sa_ln2_b = (const float*)d_in[13];
  const float* ca_ln1_g = (const float*)d_in[14];
  const float* ca_ln1_b = (const float*)d_in[15];
  const float* ca_ln2_g = (const float*)d_in[16];
  const float* ca_ln2_b = (const float*)d_in[17];
  const float* sa_ff_w1 = (const float*)d_in[18];
  const float* sa_ff_b1 = (const float*)d_in[19];
  const float* sa_ff_w2 = (const float*)d_in[20];
  const float* sa_ff_b2 = (const float*)d_in[21];
  const float* ca_ff_w1 = (const float*)d_in[22];
  const float* ca_ff_b1 = (const float*)d_in[23];
  const float* ca_ff_w2 = (const float*)d_in[24];
  const float* ca_ff_b2 = (const float*)d_in[25];
  const float* inst_w   = (const float*)d_in[26];
  const float* attn_vec = (const float*)d_in[27];
  const int* midx = (const int*)d_in[28];
  const int* dstv = (const int*)d_in[29];

  const int N = in_sizes[0] / 64;
  const int E = in_sizes[29];

  // ws floats: [0..32767] T_iw | [32768..33279] u | [33280..82431] bf16 A-frag packs
  //            [131072...] inst_emb[E*64] | a[E*8] | seg_max[N*8] | seg_sum[N*8]
  float* wsf = (float*)d_ws;
  float* inst_emb = wsf + 131072;
  float* a_arr = inst_emb + (size_t)E * 64;
  unsigned int* seg_max = (unsigned int*)(a_arr + (size_t)E * 8);
  float* seg_sum = (float*)(seg_max + (size_t)N * 8);

  {
    int n4 = out_size / 4;
    zero_kernel<<<(n4 + 255) / 256, 256, 0, stream>>>((float4*)d_out, n4);
    int s4 = (N * 16) / 4;  // seg_max + seg_sum contiguous
    zero_kernel<<<(s4 + 255) / 256, 256, 0, stream>>>((float4*)seg_max, s4);
  }

  prep_kernel<<<(131584 + 255) / 256, 256, 0, stream>>>(
      self_in_w, self_out_w, sa_ff_w1, sa_ff_w2, cross_in_w, cross_out_w, ca_ff_w1, ca_ff_w2,
      inst_w, attn_vec, wsf);

  int nblk = (E + 15) / 16;  // 1 wave/block, 16 edges/wave
  edge_kernel<<<nblk, 64, 0, stream>>>(
      features, pos_emb, self_in_b, self_out_b, cross_in_b, cross_out_b, sa_ln1_g, sa_ln1_b,
      sa_ln2_g, sa_ln2_b, ca_ln1_g, ca_ln1_b, ca_ln2_g, ca_ln2_b, sa_ff_b1, sa_ff_b2, ca_ff_b1,
      ca_ff_b2, midx, dstv, wsf, inst_emb, a_arr, seg_max, E, N);

  expsum_kernel<<<(E * 8 + 255) / 256, 256, 0, stream>>>(a_arr, dstv, seg_max, seg_sum, E * 8);

  scatter_kernel<<<(E + 3) / 4, 256, 0, stream>>>(inst_emb, a_arr, seg_max, seg_sum, dstv,
                                                  (float*)d_out, E);

  int hwave = ((N + 3) / 4) * 8;
  head_transform_kernel<<<(hwave + 3) / 4, 256, 0, stream>>>(wsf, (float*)d_out, N);
}

// Round 8
// 984.905 us; speedup vs baseline: 1.1175x; 1.0544x over previous
//
#include <hip/hip_runtime.h>
#include <math.h>

#define D 64
#define LOG2E 1.44269504088896340736f
#define QSCALE (0.35355339059327373f * LOG2E)

typedef float f32x4 __attribute__((ext_vector_type(4)));
typedef float vf4 __attribute__((ext_vector_type(4)));
typedef short bf16x8 __attribute__((ext_vector_type(8)));
typedef unsigned short ushort_t;
typedef unsigned int uint2v __attribute__((ext_vector_type(2)));

#define MF(a, b, c) __builtin_amdgcn_mfma_f32_16x16x32_bf16(a, b, c, 0, 0, 0)

// ---------- helpers ----------
__device__ __forceinline__ float bcast(float x, int i) {
  return __int_as_float(__builtin_amdgcn_readlane(__float_as_int(x), i));
}

// xor-16 partner sum (VALU permlane, no LDS round-trip); bit-exact vs shfl_xor sum.
__device__ __forceinline__ float xs16(float x) {
#if __has_builtin(__builtin_amdgcn_permlane16_swap)
  uint2v a = __builtin_amdgcn_permlane16_swap(__float_as_uint(x), __float_as_uint(x), false, false);
  return __uint_as_float(a[0]) + __uint_as_float(a[1]);
#else
  return x + __shfl_xor(x, 16);
#endif
}
__device__ __forceinline__ float xs32(float x) {
#if __has_builtin(__builtin_amdgcn_permlane32_swap)
  uint2v a = __builtin_amdgcn_permlane32_swap(__float_as_uint(x), __float_as_uint(x), false, false);
  return __uint_as_float(a[0]) + __uint_as_float(a[1]);
#else
  return x + __shfl_xor(x, 32);
#endif
}
__device__ __forceinline__ float qsum(float x) {  // sum over the 4 quads
  return xs32(xs16(x));
}

__device__ __forceinline__ ushort_t f2b(float f) {  // fp32 -> bf16 RTNE (prep only)
  unsigned int u = __float_as_uint(f);
  unsigned int r = (u + 0x7FFFu + ((u >> 16) & 1u)) >> 16;
  return (ushort_t)r;
}
// exact-RTNE packed bf16x2 (bit-identical to scalar f2b; round-4 showed cvt_pk is NOT)
__device__ __forceinline__ unsigned int pkrtne(float lo, float hi) {
  unsigned int a = __float_as_uint(lo);
  unsigned int b = __float_as_uint(hi);
  a = a + 0x7FFFu + ((a >> 16) & 1u);
  b = b + 0x7FFFu + ((b >> 16) & 1u);
  return __builtin_amdgcn_perm(b, a, 0x07060302u);
}
__device__ __forceinline__ f32x4 ld4(const float* __restrict__ p) { return *(const f32x4*)p; }
// pack two C-tiles (even ct, odd ct) into one x32 B-operand pair
__device__ __forceinline__ bf16x8 mkpair(const f32x4& ce, const f32x4& co) {
  union { bf16x8 v; unsigned int w[4]; } u;
  u.w[0] = pkrtne(ce[0], ce[1]);
  u.w[1] = pkrtne(ce[2], ce[3]);
  u.w[2] = pkrtne(co[0], co[1]);
  u.w[3] = pkrtne(co[2], co[3]);
  return u.v;
}
__device__ __forceinline__ f32x4 unpk(bf16x8 p, int half) {  // half 0 = even ct, 1 = odd ct
  union { bf16x8 v; unsigned int w[4]; } u;
  u.v = p;
  unsigned int w0 = u.w[half * 2], w1 = u.w[half * 2 + 1];
  f32x4 r;
  r[0] = __uint_as_float(w0 << 16);
  r[1] = __uint_as_float(w0 & 0xFFFF0000u);
  r[2] = __uint_as_float(w1 << 16);
  r[3] = __uint_as_float(w1 & 0xFFFF0000u);
  return r;
}

// transposed-layout LayerNorm: x,y are 16 channel values/lane; stats over 64 ch
__device__ __forceinline__ void lnT(const f32x4 (&x)[4], f32x4 (&y)[4],
                                    const float* __restrict__ g, const float* __restrict__ b,
                                    int quad) {
  float s1 = 0.f, s2 = 0.f;
#pragma unroll
  for (int ct = 0; ct < 4; ct++)
#pragma unroll
    for (int r = 0; r < 4; r++) { s1 += x[ct][r]; s2 += x[ct][r] * x[ct][r]; }
  s1 = qsum(s1);
  s2 = qsum(s2);
  float mean = s1 * 0.015625f;
  float var = s2 * 0.015625f - mean * mean;
  float rs = rsqrtf(var + 1e-5f);
#pragma unroll
  for (int ct = 0; ct < 4; ct++) {
    f32x4 gv = ld4(g + 16 * ct + 4 * quad);
    f32x4 bv = ld4(b + 16 * ct + 4 * quad);
#pragma unroll
    for (int r = 0; r < 4; r++) y[ct][r] = (x[ct][r] - mean) * rs * gv[r] + bv[r];
  }
}

// ---------- zero fill ----------
__global__ void zero_kernel(float4* __restrict__ p, int n4) {
  int t = blockIdx.x * blockDim.x + threadIdx.x;
  if (t < n4) p[t] = make_float4(0.f, 0.f, 0.f, 0.f);
}

// ---------- prep: pack weights as x32 A-frags with the k-slot permutation ----------
__global__ void prep_kernel(const float* __restrict__ si, const float* __restrict__ so,
                            const float* __restrict__ w1s, const float* __restrict__ w2s,
                            const float* __restrict__ ci, const float* __restrict__ co,
                            const float* __restrict__ w1c, const float* __restrict__ w2c,
                            const float* __restrict__ iw, const float* __restrict__ av,
                            float* __restrict__ ws) {
  int t = blockIdx.x * blockDim.x + threadIdx.x;
  ushort_t* bw = (ushort_t*)(ws + 33280);
  if (t < 98304) {
    const float* src;
    int base, cs;
    int l = t;
    if      (l < 12288) { src = si;  base = 0;     cs = 6; }
    else if (l < 16384) { src = so;  base = 12288; cs = 6; l -= 12288; }
    else if (l < 32768) { src = w1s; base = 16384; cs = 6; l -= 16384; }
    else if (l < 49152) { src = w2s; base = 32768; cs = 8; l -= 32768; }
    else if (l < 61440) { src = ci;  base = 49152; cs = 6; l -= 49152; }
    else if (l < 65536) { src = co;  base = 61440; cs = 6; l -= 61440; }
    else if (l < 81920) { src = w1c; base = 65536; cs = 6; l -= 65536; }
    else                { src = w2c; base = 81920; cs = 8; l -= 81920; }
    int c = l >> cs, k = l & ((1 << cs) - 1);
    int T = (1 << cs) >> 5;
    int ct = c >> 4, m = c & 15, tt = k >> 5, rem = k & 31;
    int quad = (rem >> 2) & 3;
    int j = (((rem >> 4) & 1) << 2) | (rem & 3);
    bw[base + (size_t)((ct * T + tt) * 64 + quad * 16 + m) * 8 + j] = f2b(src[l]);
  } else if (t < 131072) {
    int l = t - 98304;
    int c = l >> 6, k = l & 63;
    ws[(k >> 2) * 2048 + c * 4 + (k & 3)] = iw[l];
  } else if (t < 131584) {
    int l = t - 131072;
    int h = l >> 6, k = l & 63;
    float acc = 0.f;
    for (int c = 0; c < 64; c++) acc += av[h * 64 + c] * iw[(h * 64 + c) * 64 + k];
    ws[32768 + h * 64 + k] = acc;
  }
}

// ================== literal-index macros (straight-line code, no dynamic indexing) ==================
#define SC1(KARR, QF, CT, KS, P)                                                        \
  { f32x4 kv_ = unpk(KARR[KS][(CT) >> 1], (CT) & 1);                                    \
    float sp_ = QF[CT][0] * kv_[0] + QF[CT][1] * kv_[1] + QF[CT][2] * kv_[2] +          \
                QF[CT][3] * kv_[3];                                                     \
    sp_ = xs16(sp_);                                                                    \
    P = ((vb >> (KS)) & 1) ? sp_ : -1e30f; }

#define PV1(VARR, CT, KS, P, ACC)                                                       \
  { f32x4 vv_ = unpk(VARR[KS][(CT) >> 1], (CT) & 1);                                    \
    _Pragma("unroll") for (int r = 0; r < 4; r++) ACC[r] = fmaf(P, vv_[r], ACC[r]); }

#define ATT_CT(KARR, VARR, QF, CT, OD)                                                  \
  {                                                                                     \
    float p0, p1, p2, p3, p4;                                                           \
    SC1(KARR, QF, CT, 0, p0); SC1(KARR, QF, CT, 1, p1); SC1(KARR, QF, CT, 2, p2);       \
    SC1(KARR, QF, CT, 3, p3); SC1(KARR, QF, CT, 4, p4);                                 \
    float mx_ = fmaxf(fmaxf(fmaxf(p0, p1), fmaxf(p2, p3)), p4);                         \
    p0 = exp2f(p0 - mx_); p1 = exp2f(p1 - mx_); p2 = exp2f(p2 - mx_);                   \
    p3 = exp2f(p3 - mx_); p4 = exp2f(p4 - mx_);                                         \
    float ri_ = 1.0f / (p0 + p1 + p2 + p3 + p4);                                        \
    p0 *= ri_; p1 *= ri_; p2 *= ri_; p3 *= ri_; p4 *= ri_;                              \
    OD = (f32x4){0.f, 0.f, 0.f, 0.f};                                                   \
    PV1(VARR, CT, 0, p0, OD); PV1(VARR, CT, 1, p1, OD); PV1(VARR, CT, 2, p2, OD);       \
    PV1(VARR, CT, 3, p3, OD); PV1(VARR, CT, 4, p4, OD);                                 \
  }

#define KV_STAGE(S)                                                                     \
  {                                                                                     \
    f32x4 t[4], y[4];                                                                   \
    const bool vd = (vb >> (S)) & 1;                                                    \
    const float* fp = features + (size_t)min(ids[S], N - 1) * 64;                       \
    _Pragma("unroll")                                                                   \
    for (int ct = 0; ct < 4; ct++) {                                                    \
      f32x4 f = ld4(fp + 16 * ct + 4 * quad);                                           \
      f32x4 pv = ld4(pos_emb + (S) * 64 + 16 * ct + 4 * quad);                          \
      _Pragma("unroll")                                                                 \
      for (int r = 0; r < 4; r++) t[ct][r] = vd ? (f[r] + pv[r]) : 0.f;                 \
    }                                                                                   \
    lnT(t, y, sa_ln1_g, sa_ln1_b, quad);                                                \
    bf16x8 xl0 = mkpair(y[0], y[1]), xl1 = mkpair(y[2], y[3]);                          \
    f32x4 kt[4], vt[4];                                                                 \
    _Pragma("unroll")                                                                   \
    for (int ct = 0; ct < 4; ct++) {                                                    \
      f32x4 c = {0.f, 0.f, 0.f, 0.f};                                                   \
      c = MF(WSI[((4 + ct) * 2 + 0) * 64 + lane], xl0, c);                              \
      c = MF(WSI[((4 + ct) * 2 + 1) * 64 + lane], xl1, c);                              \
      f32x4 bb = ld4(self_in_b + 64 + 16 * ct + 4 * quad);                              \
      _Pragma("unroll")                                                                 \
      for (int r = 0; r < 4; r++) kt[ct][r] = c[r] + bb[r];                             \
      f32x4 c2 = {0.f, 0.f, 0.f, 0.f};                                                  \
      c2 = MF(WSI[((8 + ct) * 2 + 0) * 64 + lane], xl0, c2);                            \
      c2 = MF(WSI[((8 + ct) * 2 + 1) * 64 + lane], xl1, c2);                            \
      f32x4 bb2 = ld4(self_in_b + 128 + 16 * ct + 4 * quad);                            \
      _Pragma("unroll")                                                                 \
      for (int r = 0; r < 4; r++) vt[ct][r] = c2[r] + bb2[r];                           \
    }                                                                                   \
    Kp[S][0] = mkpair(kt[0], kt[1]); Kp[S][1] = mkpair(kt[2], kt[3]);                   \
    Vp[S][0] = mkpair(vt[0], vt[1]); Vp[S][1] = mkpair(vt[2], vt[3]);                   \
  }

#define Q_STAGE(S)                                                                      \
  {                                                                                     \
    const bool vd = (vb >> (S)) & 1;                                                    \
    const float* fp = features + (size_t)min(ids[S], N - 1) * 64;                       \
    f32x4 t[4], y[4];                                                                   \
    _Pragma("unroll")                                                                   \
    for (int ct = 0; ct < 4; ct++) {                                                    \
      f32x4 f = ld4(fp + 16 * ct + 4 * quad);                                           \
      f32x4 pv = ld4(pos_emb + (S) * 64 + 16 * ct + 4 * quad);                          \
      _Pragma("unroll")                                                                 \
      for (int r = 0; r < 4; r++) t[ct][r] = vd ? (f[r] + pv[r]) : 0.f;                 \
    }                                                                                   \
    lnT(t, y, sa_ln1_g, sa_ln1_b, quad);                                                \
    bf16x8 xl0 = mkpair(y[0], y[1]), xl1 = mkpair(y[2], y[3]);                          \
    f32x4 qf[4];                                                                        \
    _Pragma("unroll")                                                                   \
    for (int ct = 0; ct < 4; ct++) {                                                    \
      f32x4 c = {0.f, 0.f, 0.f, 0.f};                                                   \
      c = MF(WSI[(ct * 2 + 0) * 64 + lane], xl0, c);                                    \
      c = MF(WSI[(ct * 2 + 1) * 64 + lane], xl1, c);                                    \
      f32x4 bb = ld4(self_in_b + 16 * ct + 4 * quad);                                   \
      _Pragma("unroll")                                                                 \
      for (int r = 0; r < 4; r++) qf[ct][r] = (c[r] + bb[r]) * QSCALE;                  \
    }                                                                                   \
    f32x4 oa0, oa1, oa2, oa3;                                                           \
    ATT_CT(Kp, Vp, qf, 0, oa0); ATT_CT(Kp, Vp, qf, 1, oa1);                             \
    ATT_CT(Kp, Vp, qf, 2, oa2); ATT_CT(Kp, Vp, qf, 3, oa3);                             \
    bf16x8 op0 = mkpair(oa0, oa1), op1 = mkpair(oa2, oa3);                              \
    f32x4 tpc[4];                                                                       \
    _Pragma("unroll")                                                                   \
    for (int ct = 0; ct < 4; ct++) {                                                    \
      f32x4 c = {0.f, 0.f, 0.f, 0.f};                                                   \
      c = MF(WSO[(ct * 2 + 0) * 64 + lane], op0, c);                                    \
      c = MF(WSO[(ct * 2 + 1) * 64 + lane], op1, c);                                    \
      f32x4 bb = ld4(self_out_b + 16 * ct + 4 * quad);                                  \
      _Pragma("unroll")                                                                 \
      for (int r = 0; r < 4; r++) {                                                     \
        float tp_ = c[r] + bb[r] + t[ct][r];                                            \
        tpc[ct][r] = tp_;                                                               \
        pool[ct][r] += vd ? tp_ : 0.f;                                                  \
      }                                                                                 \
    }                                                                                   \
    TP[S][0] = mkpair(tpc[0], tpc[1]); TP[S][1] = mkpair(tpc[2], tpc[3]);               \
  }

#define CKV_STAGE(S)                                                                    \
  {                                                                                     \
    f32x4 kt[4], vt[4];                                                                 \
    _Pragma("unroll")                                                                   \
    for (int ct = 0; ct < 4; ct++) {                                                    \
      f32x4 c = {0.f, 0.f, 0.f, 0.f};                                                   \
      c = MF(WCI[((4 + ct) * 2 + 0) * 64 + lane], TP[S][0], c);                         \
      c = MF(WCI[((4 + ct) * 2 + 1) * 64 + lane], TP[S][1], c);                         \
      f32x4 bb = ld4(cross_in_b + 64 + 16 * ct + 4 * quad);                             \
      _Pragma("unroll")                                                                 \
      for (int r = 0; r < 4; r++) kt[ct][r] = c[r] + bb[r];                             \
      f32x4 c2 = {0.f, 0.f, 0.f, 0.f};                                                  \
      c2 = MF(WCI[((8 + ct) * 2 + 0) * 64 + lane], TP[S][0], c2);                       \
      c2 = MF(WCI[((8 + ct) * 2 + 1) * 64 + lane], TP[S][1], c2);                       \
      f32x4 bb2 = ld4(cross_in_b + 128 + 16 * ct + 4 * quad);                           \
      _Pragma("unroll")                                                                 \
      for (int r = 0; r < 4; r++) vt[ct][r] = c2[r] + bb2[r];                           \
    }                                                                                   \
    Kc[S][0] = mkpair(kt[0], kt[1]); Kc[S][1] = mkpair(kt[2], kt[3]);                   \
    Vc[S][0] = mkpair(vt[0], vt[1]); Vc[S][1] = mkpair(vt[2], vt[3]);                   \
  }

#define FF_H2(CT, HD)                                                                   \
  { f32x4 c = {0.f, 0.f, 0.f, 0.f};                                                     \
    c = MF(W1[((CT) * 2 + 0) * 64 + lane], x0, c);                                      \
    c = MF(W1[((CT) * 2 + 1) * 64 + lane], x1, c);                                      \
    f32x4 bb = ld4(b1 + 16 * (CT) + 4 * quad);                                          \
    _Pragma("unroll")                                                                   \
    for (int r = 0; r < 4; r++) {                                                       \
      float v = c[r] + bb[r];                                                           \
      HD[r] = 0.5f * v * (1.0f + erff(v * 0.70710678118654752440f));                    \
    } }

#define FF_O(CT)                                                                        \
  { f32x4 c = {0.f, 0.f, 0.f, 0.f};                                                     \
    c = MF(W2[((CT) * 8 + 0) * 64 + lane], Hp0, c);                                     \
    c = MF(W2[((CT) * 8 + 1) * 64 + lane], Hp1, c);                                     \
    c = MF(W2[((CT) * 8 + 2) * 64 + lane], Hp2, c);                                     \
    c = MF(W2[((CT) * 8 + 3) * 64 + lane], Hp3, c);                                     \
    c = MF(W2[((CT) * 8 + 4) * 64 + lane], Hp4, c);                                     \
    c = MF(W2[((CT) * 8 + 5) * 64 + lane], Hp5, c);                                     \
    c = MF(W2[((CT) * 8 + 6) * 64 + lane], Hp6, c);                                     \
    c = MF(W2[((CT) * 8 + 7) * 64 + lane], Hp7, c);                                     \
    f32x4 bb = ld4(b2 + 16 * (CT) + 4 * quad);                                          \
    _Pragma("unroll")                                                                   \
    for (int r = 0; r < 4; r++) inst[CT][r] += c[r] + bb[r]; }

__device__ __forceinline__ void ffnT(f32x4 (&inst)[4],
                                     const float* __restrict__ g, const float* __restrict__ b,
                                     const bf16x8* __restrict__ W1, const bf16x8* __restrict__ W2,
                                     const float* __restrict__ b1, const float* __restrict__ b2,
                                     int lane, int quad) {
  f32x4 y[4];
  lnT(inst, y, g, b, quad);
  bf16x8 x0 = mkpair(y[0], y[1]), x1 = mkpair(y[2], y[3]);
  f32x4 ha, hb;
  FF_H2(0, ha);  FF_H2(1, hb);  bf16x8 Hp0 = mkpair(ha, hb);
  FF_H2(2, ha);  FF_H2(3, hb);  bf16x8 Hp1 = mkpair(ha, hb);
  FF_H2(4, ha);  FF_H2(5, hb);  bf16x8 Hp2 = mkpair(ha, hb);
  FF_H2(6, ha);  FF_H2(7, hb);  bf16x8 Hp3 = mkpair(ha, hb);
  FF_H2(8, ha);  FF_H2(9, hb);  bf16x8 Hp4 = mkpair(ha, hb);
  FF_H2(10, ha); FF_H2(11, hb); bf16x8 Hp5 = mkpair(ha, hb);
  FF_H2(12, ha); FF_H2(13, hb); bf16x8 Hp6 = mkpair(ha, hb);
  FF_H2(14, ha); FF_H2(15, hb); bf16x8 Hp7 = mkpair(ha, hb);
  FF_O(0); FF_O(1); FF_O(2); FF_O(3);
}

#define ASC(H)                                                                          \
  { float sp = 0.f;                                                                     \
    _Pragma("unroll")                                                                   \
    for (int ct = 0; ct < 4; ct++) {                                                    \
      f32x4 uu = ld4(uvec + (H) * 64 + 16 * ct + 4 * quad);                             \
      _Pragma("unroll")                                                                 \
      for (int r = 0; r < 4; r++) sp = fmaf(inst[ct][r], uu[r], sp);                    \
    }                                                                                   \
    sp = qsum(sp);                                                                      \
    a##H = sp > 0.f ? sp : 0.01f * sp; }

// ---------- per-edge transformer: one wave = 16 edges, fully register-resident ----------
// seg_max atomics removed (back half now computes exact per-segment max from a[] via CSR).
__global__ __launch_bounds__(64, 1)
void edge_kernel(const float* __restrict__ features, const float* __restrict__ pos_emb,
                 const float* __restrict__ self_in_b, const float* __restrict__ self_out_b,
                 const float* __restrict__ cross_in_b, const float* __restrict__ cross_out_b,
                 const float* __restrict__ sa_ln1_g, const float* __restrict__ sa_ln1_b,
                 const float* __restrict__ sa_ln2_g, const float* __restrict__ sa_ln2_b,
                 const float* __restrict__ ca_ln1_g, const float* __restrict__ ca_ln1_b,
                 const float* __restrict__ ca_ln2_g, const float* __restrict__ ca_ln2_b,
                 const float* __restrict__ sa_ff_b1, const float* __restrict__ sa_ff_b2,
                 const float* __restrict__ ca_ff_b1, const float* __restrict__ ca_ff_b2,
                 const int* __restrict__ midx, const int* __restrict__ dstv,
                 const float* __restrict__ ws,
                 float* __restrict__ inst_out, float* __restrict__ a_out, int E, int N) {
  const int lane = threadIdx.x;
  const int quad = lane >> 4, lo = lane & 15;
  const int e0 = blockIdx.x * 16;
  __shared__ float xp[16 * 68];

  const ushort_t* bw = (const ushort_t*)(ws + 33280);
  const bf16x8* WSI = (const bf16x8*)(bw);
  const bf16x8* WSO = (const bf16x8*)(bw + 12288);
  const bf16x8* W1S = (const bf16x8*)(bw + 16384);
  const bf16x8* W2S = (const bf16x8*)(bw + 32768);
  const bf16x8* WCI = (const bf16x8*)(bw + 49152);
  const bf16x8* WCO = (const bf16x8*)(bw + 61440);
  const bf16x8* W1C = (const bf16x8*)(bw + 65536);
  const bf16x8* W2C = (const bf16x8*)(bw + 81920);
  const float* uvec = ws + 32768;

  const bool ge = (e0 + lo) < E;
  const int eIdx = min(e0 + lo, E - 1);
  int ids[5];
  ids[0] = midx[eIdx * 5 + 0];
  ids[1] = midx[eIdx * 5 + 1];
  ids[2] = midx[eIdx * 5 + 2];
  ids[3] = midx[eIdx * 5 + 3];
  ids[4] = midx[eIdx * 5 + 4];
  int vb = 0;
  if (ids[0] != N && ge) vb |= 1;
  if (ids[1] != N && ge) vb |= 2;
  if (ids[2] != N && ge) vb |= 4;
  if (ids[3] != N && ge) vb |= 8;
  if (ids[4] != N && ge) vb |= 16;
  const int nv = __popc(vb);
  const int lp = max(nv - 1, 0);
  int lid = ids[0];
  lid = (lp == 1) ? ids[1] : lid;
  lid = (lp == 2) ? ids[2] : lid;
  lid = (lp == 3) ? ids[3] : lid;
  lid = (lp == 4) ? ids[4] : lid;

  bf16x8 Kp[5][2], Vp[5][2];
  KV_STAGE(0); KV_STAGE(1); KV_STAGE(2); KV_STAGE(3); KV_STAGE(4);

  f32x4 pool[4];
#pragma unroll
  for (int ct = 0; ct < 4; ct++) pool[ct] = (f32x4){0.f, 0.f, 0.f, 0.f};
  bf16x8 TP[5][2];
  Q_STAGE(0); Q_STAGE(1); Q_STAGE(2); Q_STAGE(3); Q_STAGE(4);

  f32x4 inst[4];
  {
    float rn = 1.0f / (float)max(nv, 1);
#pragma unroll
    for (int ct = 0; ct < 4; ct++)
#pragma unroll
      for (int r = 0; r < 4; r++) inst[ct][r] = pool[ct][r] * rn;
  }

  ffnT(inst, sa_ln2_g, sa_ln2_b, W1S, W2S, sa_ff_b1, sa_ff_b2, lane, quad);

  {
    f32x4 tf[4], xq[4];
    const bool vdl = lid != N;
    const float* fp = features + (size_t)min(lid, N - 1) * 64;
#pragma unroll
    for (int ct = 0; ct < 4; ct++) {
      f32x4 f = ld4(fp + 16 * ct + 4 * quad);
#pragma unroll
      for (int r = 0; r < 4; r++) tf[ct][r] = vdl ? f[r] : 0.f;
    }
    lnT(tf, xq, ca_ln1_g, ca_ln1_b, quad);
    bf16x8 xq0 = mkpair(xq[0], xq[1]), xq1 = mkpair(xq[2], xq[3]);
    f32x4 qcf[4];
#pragma unroll
    for (int ct = 0; ct < 4; ct++) {
      f32x4 c = {0.f, 0.f, 0.f, 0.f};
      c = MF(WCI[(ct * 2 + 0) * 64 + lane], xq0, c);
      c = MF(WCI[(ct * 2 + 1) * 64 + lane], xq1, c);
      f32x4 bb = ld4(cross_in_b + 16 * ct + 4 * quad);
#pragma unroll
      for (int r = 0; r < 4; r++) qcf[ct][r] = (c[r] + bb[r]) * QSCALE;
    }
    bf16x8 Kc[5][2], Vc[5][2];
    CKV_STAGE(0); CKV_STAGE(1); CKV_STAGE(2); CKV_STAGE(3); CKV_STAGE(4);
    f32x4 cc0, cc1, cc2, cc3;
    ATT_CT(Kc, Vc, qcf, 0, cc0); ATT_CT(Kc, Vc, qcf, 1, cc1);
    ATT_CT(Kc, Vc, qcf, 2, cc2); ATT_CT(Kc, Vc, qcf, 3, cc3);
    bf16x8 cp0 = mkpair(cc0, cc1), cp1 = mkpair(cc2, cc3);
#pragma unroll
    for (int ct = 0; ct < 4; ct++) {
      f32x4 c = {0.f, 0.f, 0.f, 0.f};
      c = MF(WCO[(ct * 2 + 0) * 64 + lane], cp0, c);
      c = MF(WCO[(ct * 2 + 1) * 64 + lane], cp1, c);
      f32x4 bb = ld4(cross_out_b + 16 * ct + 4 * quad);
#pragma unroll
      for (int r = 0; r < 4; r++) inst[ct][r] += c[r] + bb[r];
    }
  }

  ffnT(inst, ca_ln2_g, ca_ln2_b, W1C, W2C, ca_ff_b1, ca_ff_b2, lane, quad);

  float a0, a1, a2, a3, a4, a5, a6, a7;
  ASC(0); ASC(1); ASC(2); ASC(3); ASC(4); ASC(5); ASC(6); ASC(7);
  if (ge && quad < 2) {
    f32x4 st = (quad == 0) ? (f32x4){a0, a1, a2, a3} : (f32x4){a4, a5, a6, a7};
    *(f32x4*)(a_out + (size_t)(e0 + lo) * 8 + 4 * quad) = st;
  }

#pragma unroll
  for (int ct = 0; ct < 4; ct++)
    *(f32x4*)(&xp[lo * 68 + 16 * ct + 4 * quad]) = inst[ct];
  __syncthreads();
  {
    int er = lane >> 2, cb = (lane & 3) * 16;
    if (e0 + er < E) {
#pragma unroll
      for (int u = 0; u < 4; u++) {
        f32x4 v = *(const f32x4*)(&xp[er * 68 + cb + 4 * u]);
        *(f32x4*)(inst_out + (size_t)(e0 + er) * 64 + cb + 4 * u) = v;
      }
    }
  }
}

// ================== CSR-by-dst build ==================
__global__ void csr_count_kernel(const int* __restrict__ dstv, unsigned int* __restrict__ cnt,
                                 int E) {
  int e = blockIdx.x * blockDim.x + threadIdx.x;
  if (e < E) atomicAdd(&cnt[dstv[e]], 1u);
}

// block-local exclusive scan of cnt -> off (in place ok: read own elem before write)
__global__ void scan1_kernel(unsigned int* __restrict__ off, unsigned int* __restrict__ bsum,
                             int N) {
  __shared__ unsigned int sd[256];
  int t = threadIdx.x, n = blockIdx.x * 256 + t;
  unsigned int v = (n < N) ? off[n] : 0u;
  sd[t] = v;
  __syncthreads();
  for (int o = 1; o < 256; o <<= 1) {
    unsigned int x = (t >= o) ? sd[t - o] : 0u;
    __syncthreads();
    sd[t] += x;
    __syncthreads();
  }
  if (n < N) off[n] = sd[t] - v;  // local exclusive
  if (t == 255) bsum[blockIdx.x] = sd[255];
}

__global__ void scan2_kernel(unsigned int* __restrict__ bsum, int nb) {
  __shared__ unsigned int sd[1024];
  int t = threadIdx.x;
  unsigned int v = (t < nb) ? bsum[t] : 0u;
  sd[t] = v;
  __syncthreads();
  for (int o = 1; o < 1024; o <<= 1) {
    unsigned int x = (t >= o) ? sd[t - o] : 0u;
    __syncthreads();
    sd[t] += x;
    __syncthreads();
  }
  if (t < nb) bsum[t] = sd[t] - v;  // exclusive
}

__global__ void scan3_kernel(unsigned int* __restrict__ off, unsigned int* __restrict__ cur,
                             const unsigned int* __restrict__ bsum, int N, int E) {
  int n = blockIdx.x * 256 + threadIdx.x;
  if (n < N) {
    unsigned int o = off[n] + bsum[blockIdx.x];
    off[n] = o;
    cur[n] = o;
  }
  if (n == 0) off[N] = (unsigned int)E;
}

__global__ void csr_fill_kernel(const int* __restrict__ dstv, unsigned int* __restrict__ cur,
                                unsigned int* __restrict__ elist, int E) {
  int e = blockIdx.x * blockDim.x + threadIdx.x;
  if (e < E) {
    unsigned int p = atomicAdd(&cur[dstv[e]], 1u);
    elist[p] = (unsigned int)e;
  }
}

// ================== fused gather: per (h, node) softmax + weighted sum + head transform ==================
// Replaces expsum (1.2M atomics) + scatter (76.8M atomics) + head_transform (6.5GB L2
// weight re-reads) + zero(out). Wave = one node for fixed h; W_h rows held in 64 VGPRs,
// amortized over ~N/1024 nodes per wave. Writes every (n,h) row -> out needs no pre-zero.
__global__ __launch_bounds__(256)
void gather_kernel(const float* __restrict__ T_iw, const unsigned int* __restrict__ off,
                   const unsigned int* __restrict__ elist, const float* __restrict__ a,
                   const float* __restrict__ inst_emb, float* __restrict__ out, int N) {
  const int lane = threadIdx.x & 63;
  const int widx = threadIdx.x >> 6;
  const int h = blockIdx.y;
  const vf4* P = (const vf4*)T_iw;
  vf4 wr[16];
#pragma unroll
  for (int k = 0; k < 16; k++) wr[k] = P[k * 512 + h * 64 + lane];  // W_h[lane][4k..4k+3]
  const int stride = gridDim.x * 4;
  for (int n = blockIdx.x * 4 + widx; n < N; n += stride) {
    const unsigned int s0 = off[n], s1 = off[n + 1];
    float m = -3.0e38f;
    for (unsigned int i = s0; i < s1; i++) m = fmaxf(m, a[(size_t)elist[i] * 8 + h]);
    float s = 0.f, z = 0.f;
    for (unsigned int i = s0; i < s1; i++) {
      unsigned int e = elist[i];
      float w = __expf(a[(size_t)e * 8 + h] - m);
      s += w;
      z = fmaf(w, inst_emb[(size_t)e * 64 + lane], z);
    }
    float ri = (s > 0.f) ? 1.0f / s : 0.f;
    z *= ri;
    float o = 0.f;
#pragma unroll
    for (int k = 0; k < 16; k++) {
#pragma unroll
      for (int u = 0; u < 4; u++) o = fmaf(bcast(z, k * 4 + u), wr[k][u], o);
    }
    out[(size_t)n * 512 + h * 64 + lane] = o;
  }
}

extern "C" void kernel_launch(void* const* d_in, const int* in_sizes, int n_in,
                              void* d_out, int out_size, void* d_ws, size_t ws_size,
                              hipStream_t stream) {
  const float* features   = (const float*)d_in[0];
  const float* pos_emb    = (const float*)d_in[1];
  const float* self_in_w  = (const float*)d_in[2];
  const float* self_in_b  = (const float*)d_in[3];
  const float* self_out_w = (const float*)d_in[4];
  const float* self_out_b = (const float*)d_in[5];
  const float* cross_in_w = (const float*)d_in[6];
  const float* cross_in_b = (const float*)d_in[7];
  const float* cross_out_w= (const float*)d_in[8];
  const float* cross_out_b= (const float*)d_in[9];
  const float* sa_ln1_g = (const float*)d_in[10];
  const float* sa_ln1_b = (const float*)d_in[11];
  const float* sa_ln2_g = (const float*)d_in[12];
  const float* sa_ln2_b = (const float*)d_in[13];
  const float* ca_ln1_g = (const float*)d_in[14];
  const float* ca_ln1_b = (const float*)d_in[15];
  const float* ca_ln2_g = (const float*)d_in[16];
  const float* ca_ln2_b = (const float*)d_in[17];
  const float* sa_ff_w1 = (const float*)d_in[18];
  const float* sa_ff_b1 = (const float*)d_in[19];
  const float* sa_ff_w2 = (const float*)d_in[20];
  const float* sa_ff_b2 = (const float*)d_in[21];
  const float* ca_ff_w1 = (const float*)d_in[22];
  const float* ca_ff_b1 = (const float*)d_in[23];
  const float* ca_ff_w2 = (const float*)d_in[24];
  const float* ca_ff_b2 = (const float*)d_in[25];
  const float* inst_w   = (const float*)d_in[26];
  const float* attn_vec = (const float*)d_in[27];
  const int* midx = (const int*)d_in[28];
  const int* dstv = (const int*)d_in[29];

  const int N = in_sizes[0] / 64;
  const int E = in_sizes[29];

  // ws floats: [0..32767] T_iw | [32768..33279] u | [33280..82431] bf16 A-frag packs
  //            [131072...] inst_emb[E*64] | a[E*8] | CSR region (reuses old seg space):
  //            off[N+1] | cur[N] | bsum[1024] | elist[E]   (251k uints << N*16=800k)
  float* wsf = (float*)d_ws;
  float* inst_emb = wsf + 131072;
  float* a_arr = inst_emb + (size_t)E * 64;
  unsigned int* off = (unsigned int*)(a_arr + (size_t)E * 8);
  unsigned int* cur = off + (size_t)(N + 1);
  unsigned int* bsum = cur + (size_t)N;
  unsigned int* elist = bsum + 1024;

  const int nb1 = (N + 255) / 256;

  {
    // zero off (= cnt) region; rounding up into cur is harmless (cur set in scan3)
    int n4 = (N + 1 + 3) / 4;
    zero_kernel<<<(n4 + 255) / 256, 256, 0, stream>>>((float4*)off, n4);
  }

  prep_kernel<<<(131584 + 255) / 256, 256, 0, stream>>>(
      self_in_w, self_out_w, sa_ff_w1, sa_ff_w2, cross_in_w, cross_out_w, ca_ff_w1, ca_ff_w2,
      inst_w, attn_vec, wsf);

  // CSR build (independent of edge_kernel results)
  csr_count_kernel<<<(E + 255) / 256, 256, 0, stream>>>(dstv, off, E);
  scan1_kernel<<<nb1, 256, 0, stream>>>(off, bsum, N);
  scan2_kernel<<<1, 1024, 0, stream>>>(bsum, nb1);
  scan3_kernel<<<nb1, 256, 0, stream>>>(off, cur, bsum, N, E);
  csr_fill_kernel<<<(E + 255) / 256, 256, 0, stream>>>(dstv, cur, elist, E);

  int nblk = (E + 15) / 16;  // 1 wave/block, 16 edges/wave
  edge_kernel<<<nblk, 64, 0, stream>>>(
      features, pos_emb, self_in_b, self_out_b, cross_in_b, cross_out_b, sa_ln1_g, sa_ln1_b,
      sa_ln2_g, sa_ln2_b, ca_ln1_g, ca_ln1_b, ca_ln2_g, ca_ln2_b, sa_ff_b1, sa_ff_b2, ca_ff_b1,
      ca_ff_b2, midx, dstv, wsf, inst_emb, a_arr, E, N);

  dim3 ggrid(256, 8);
  gather_kernel<<<ggrid, 256, 0, stream>>>(wsf, off, elist, a_arr, inst_emb, (float*)d_out, N);
}

// Round 9
// 915.012 us; speedup vs baseline: 1.2028x; 1.0764x over previous
//
#include <hip/hip_runtime.h>
#include <math.h>

#define D 64
#define LOG2E 1.44269504088896340736f
#define QSCALE (0.35355339059327373f * LOG2E)

typedef float f32x4 __attribute__((ext_vector_type(4)));
typedef float vf4 __attribute__((ext_vector_type(4)));
typedef short bf16x8 __attribute__((ext_vector_type(8)));
typedef unsigned short ushort_t;
typedef unsigned int uint2v __attribute__((ext_vector_type(2)));

#define MF(a, b, c) __builtin_amdgcn_mfma_f32_16x16x32_bf16(a, b, c, 0, 0, 0)

// ---------- helpers ----------
__device__ __forceinline__ float bcast(float x, int i) {
  return __int_as_float(__builtin_amdgcn_readlane(__float_as_int(x), i));
}

// xor-16 partner sum (VALU permlane, no LDS round-trip); bit-exact vs shfl_xor sum.
__device__ __forceinline__ float xs16(float x) {
#if __has_builtin(__builtin_amdgcn_permlane16_swap)
  uint2v a = __builtin_amdgcn_permlane16_swap(__float_as_uint(x), __float_as_uint(x), false, false);
  return __uint_as_float(a[0]) + __uint_as_float(a[1]);
#else
  return x + __shfl_xor(x, 16);
#endif
}
__device__ __forceinline__ float xs32(float x) {
#if __has_builtin(__builtin_amdgcn_permlane32_swap)
  uint2v a = __builtin_amdgcn_permlane32_swap(__float_as_uint(x), __float_as_uint(x), false, false);
  return __uint_as_float(a[0]) + __uint_as_float(a[1]);
#else
  return x + __shfl_xor(x, 32);
#endif
}
__device__ __forceinline__ float qsum(float x) {  // sum over the 4 quads
  return xs32(xs16(x));
}

__device__ __forceinline__ ushort_t f2b(float f) {  // fp32 -> bf16 RTNE (prep only)
  unsigned int u = __float_as_uint(f);
  unsigned int r = (u + 0x7FFFu + ((u >> 16) & 1u)) >> 16;
  return (ushort_t)r;
}
// exact-RTNE packed bf16x2 (bit-identical to scalar f2b; round-4 showed cvt_pk is NOT)
__device__ __forceinline__ unsigned int pkrtne(float lo, float hi) {
  unsigned int a = __float_as_uint(lo);
  unsigned int b = __float_as_uint(hi);
  a = a + 0x7FFFu + ((a >> 16) & 1u);
  b = b + 0x7FFFu + ((b >> 16) & 1u);
  return __builtin_amdgcn_perm(b, a, 0x07060302u);
}
__device__ __forceinline__ f32x4 ld4(const float* __restrict__ p) { return *(const f32x4*)p; }
// pack two C-tiles (even ct, odd ct) into one x32 B-operand pair
__device__ __forceinline__ bf16x8 mkpair(const f32x4& ce, const f32x4& co) {
  union { bf16x8 v; unsigned int w[4]; } u;
  u.w[0] = pkrtne(ce[0], ce[1]);
  u.w[1] = pkrtne(ce[2], ce[3]);
  u.w[2] = pkrtne(co[0], co[1]);
  u.w[3] = pkrtne(co[2], co[3]);
  return u.v;
}
__device__ __forceinline__ f32x4 unpk(bf16x8 p, int half) {  // half 0 = even ct, 1 = odd ct
  union { bf16x8 v; unsigned int w[4]; } u;
  u.v = p;
  unsigned int w0 = u.w[half * 2], w1 = u.w[half * 2 + 1];
  f32x4 r;
  r[0] = __uint_as_float(w0 << 16);
  r[1] = __uint_as_float(w0 & 0xFFFF0000u);
  r[2] = __uint_as_float(w1 << 16);
  r[3] = __uint_as_float(w1 & 0xFFFF0000u);
  return r;
}

// transposed-layout LayerNorm: x,y are 16 channel values/lane; stats over 64 ch
__device__ __forceinline__ void lnT(const f32x4 (&x)[4], f32x4 (&y)[4],
                                    const float* __restrict__ g, const float* __restrict__ b,
                                    int quad) {
  float s1 = 0.f, s2 = 0.f;
#pragma unroll
  for (int ct = 0; ct < 4; ct++)
#pragma unroll
    for (int r = 0; r < 4; r++) { s1 += x[ct][r]; s2 += x[ct][r] * x[ct][r]; }
  s1 = qsum(s1);
  s2 = qsum(s2);
  float mean = s1 * 0.015625f;
  float var = s2 * 0.015625f - mean * mean;
  float rs = rsqrtf(var + 1e-5f);
#pragma unroll
  for (int ct = 0; ct < 4; ct++) {
    f32x4 gv = ld4(g + 16 * ct + 4 * quad);
    f32x4 bv = ld4(b + 16 * ct + 4 * quad);
#pragma unroll
    for (int r = 0; r < 4; r++) y[ct][r] = (x[ct][r] - mean) * rs * gv[r] + bv[r];
  }
}

// ---------- zero fill ----------
__global__ void zero_kernel(float4* __restrict__ p, int n4) {
  int t = blockIdx.x * blockDim.x + threadIdx.x;
  if (t < n4) p[t] = make_float4(0.f, 0.f, 0.f, 0.f);
}

// ---------- prep: pack weights as x32 A-frags with the k-slot permutation ----------
__global__ void prep_kernel(const float* __restrict__ si, const float* __restrict__ so,
                            const float* __restrict__ w1s, const float* __restrict__ w2s,
                            const float* __restrict__ ci, const float* __restrict__ co,
                            const float* __restrict__ w1c, const float* __restrict__ w2c,
                            const float* __restrict__ iw, const float* __restrict__ av,
                            float* __restrict__ ws) {
  int t = blockIdx.x * blockDim.x + threadIdx.x;
  ushort_t* bw = (ushort_t*)(ws + 33280);
  if (t < 98304) {
    const float* src;
    int base, cs;
    int l = t;
    if      (l < 12288) { src = si;  base = 0;     cs = 6; }
    else if (l < 16384) { src = so;  base = 12288; cs = 6; l -= 12288; }
    else if (l < 32768) { src = w1s; base = 16384; cs = 6; l -= 16384; }
    else if (l < 49152) { src = w2s; base = 32768; cs = 8; l -= 32768; }
    else if (l < 61440) { src = ci;  base = 49152; cs = 6; l -= 49152; }
    else if (l < 65536) { src = co;  base = 61440; cs = 6; l -= 61440; }
    else if (l < 81920) { src = w1c; base = 65536; cs = 6; l -= 65536; }
    else                { src = w2c; base = 81920; cs = 8; l -= 81920; }
    int c = l >> cs, k = l & ((1 << cs) - 1);
    int T = (1 << cs) >> 5;
    int ct = c >> 4, m = c & 15, tt = k >> 5, rem = k & 31;
    int quad = (rem >> 2) & 3;
    int j = (((rem >> 4) & 1) << 2) | (rem & 3);
    bw[base + (size_t)((ct * T + tt) * 64 + quad * 16 + m) * 8 + j] = f2b(src[l]);
  } else if (t < 131072) {
    int l = t - 98304;
    int c = l >> 6, k = l & 63;
    ws[(k >> 2) * 2048 + c * 4 + (k & 3)] = iw[l];
  } else if (t < 131584) {
    int l = t - 131072;
    int h = l >> 6, k = l & 63;
    float acc = 0.f;
    for (int c = 0; c < 64; c++) acc += av[h * 64 + c] * iw[(h * 64 + c) * 64 + k];
    ws[32768 + h * 64 + k] = acc;
  }
}

// ================== literal-index macros (straight-line code, no dynamic indexing) ==================
#define SC1(KARR, QF, CT, KS, P)                                                        \
  { f32x4 kv_ = unpk(KARR[KS][(CT) >> 1], (CT) & 1);                                    \
    float sp_ = QF[CT][0] * kv_[0] + QF[CT][1] * kv_[1] + QF[CT][2] * kv_[2] +          \
                QF[CT][3] * kv_[3];                                                     \
    sp_ = xs16(sp_);                                                                    \
    P = ((vb >> (KS)) & 1) ? sp_ : -1e30f; }

#define PV1(VARR, CT, KS, P, ACC)                                                       \
  { f32x4 vv_ = unpk(VARR[KS][(CT) >> 1], (CT) & 1);                                    \
    _Pragma("unroll") for (int r = 0; r < 4; r++) ACC[r] = fmaf(P, vv_[r], ACC[r]); }

#define ATT_CT(KARR, VARR, QF, CT, OD)                                                  \
  {                                                                                     \
    float p0, p1, p2, p3, p4;                                                           \
    SC1(KARR, QF, CT, 0, p0); SC1(KARR, QF, CT, 1, p1); SC1(KARR, QF, CT, 2, p2);       \
    SC1(KARR, QF, CT, 3, p3); SC1(KARR, QF, CT, 4, p4);                                 \
    float mx_ = fmaxf(fmaxf(fmaxf(p0, p1), fmaxf(p2, p3)), p4);                         \
    p0 = exp2f(p0 - mx_); p1 = exp2f(p1 - mx_); p2 = exp2f(p2 - mx_);                   \
    p3 = exp2f(p3 - mx_); p4 = exp2f(p4 - mx_);                                         \
    float ri_ = 1.0f / (p0 + p1 + p2 + p3 + p4);                                        \
    p0 *= ri_; p1 *= ri_; p2 *= ri_; p3 *= ri_; p4 *= ri_;                              \
    OD = (f32x4){0.f, 0.f, 0.f, 0.f};                                                   \
    PV1(VARR, CT, 0, p0, OD); PV1(VARR, CT, 1, p1, OD); PV1(VARR, CT, 2, p2, OD);       \
    PV1(VARR, CT, 3, p3, OD); PV1(VARR, CT, 4, p4, OD);                                 \
  }

#define KV_STAGE(S)                                                                     \
  {                                                                                     \
    f32x4 t[4], y[4];                                                                   \
    const bool vd = (vb >> (S)) & 1;                                                    \
    const float* fp = features + (size_t)min(ids[S], N - 1) * 64;                       \
    _Pragma("unroll")                                                                   \
    for (int ct = 0; ct < 4; ct++) {                                                    \
      f32x4 f = ld4(fp + 16 * ct + 4 * quad);                                           \
      f32x4 pv = ld4(pos_emb + (S) * 64 + 16 * ct + 4 * quad);                          \
      _Pragma("unroll")                                                                 \
      for (int r = 0; r < 4; r++) t[ct][r] = vd ? (f[r] + pv[r]) : 0.f;                 \
    }                                                                                   \
    lnT(t, y, sa_ln1_g, sa_ln1_b, quad);                                                \
    bf16x8 xl0 = mkpair(y[0], y[1]), xl1 = mkpair(y[2], y[3]);                          \
    f32x4 kt[4], vt[4];                                                                 \
    _Pragma("unroll")                                                                   \
    for (int ct = 0; ct < 4; ct++) {                                                    \
      f32x4 c = {0.f, 0.f, 0.f, 0.f};                                                   \
      c = MF(WSI[((4 + ct) * 2 + 0) * 64 + lane], xl0, c);                              \
      c = MF(WSI[((4 + ct) * 2 + 1) * 64 + lane], xl1, c);                              \
      f32x4 bb = ld4(self_in_b + 64 + 16 * ct + 4 * quad);                              \
      _Pragma("unroll")                                                                 \
      for (int r = 0; r < 4; r++) kt[ct][r] = c[r] + bb[r];                             \
      f32x4 c2 = {0.f, 0.f, 0.f, 0.f};                                                  \
      c2 = MF(WSI[((8 + ct) * 2 + 0) * 64 + lane], xl0, c2);                            \
      c2 = MF(WSI[((8 + ct) * 2 + 1) * 64 + lane], xl1, c2);                            \
      f32x4 bb2 = ld4(self_in_b + 128 + 16 * ct + 4 * quad);                            \
      _Pragma("unroll")                                                                 \
      for (int r = 0; r < 4; r++) vt[ct][r] = c2[r] + bb2[r];                           \
    }                                                                                   \
    Kp[S][0] = mkpair(kt[0], kt[1]); Kp[S][1] = mkpair(kt[2], kt[3]);                   \
    Vp[S][0] = mkpair(vt[0], vt[1]); Vp[S][1] = mkpair(vt[2], vt[3]);                   \
  }

#define Q_STAGE(S)                                                                      \
  {                                                                                     \
    const bool vd = (vb >> (S)) & 1;                                                    \
    const float* fp = features + (size_t)min(ids[S], N - 1) * 64;                       \
    f32x4 t[4], y[4];                                                                   \
    _Pragma("unroll")                                                                   \
    for (int ct = 0; ct < 4; ct++) {                                                    \
      f32x4 f = ld4(fp + 16 * ct + 4 * quad);                                           \
      f32x4 pv = ld4(pos_emb + (S) * 64 + 16 * ct + 4 * quad);                          \
      _Pragma("unroll")                                                                 \
      for (int r = 0; r < 4; r++) t[ct][r] = vd ? (f[r] + pv[r]) : 0.f;                 \
    }                                                                                   \
    lnT(t, y, sa_ln1_g, sa_ln1_b, quad);                                                \
    bf16x8 xl0 = mkpair(y[0], y[1]), xl1 = mkpair(y[2], y[3]);                          \
    f32x4 qf[4];                                                                        \
    _Pragma("unroll")                                                                   \
    for (int ct = 0; ct < 4; ct++) {                                                    \
      f32x4 c = {0.f, 0.f, 0.f, 0.f};                                                   \
      c = MF(WSI[(ct * 2 + 0) * 64 + lane], xl0, c);                                    \
      c = MF(WSI[(ct * 2 + 1) * 64 + lane], xl1, c);                                    \
      f32x4 bb = ld4(self_in_b + 16 * ct + 4 * quad);                                   \
      _Pragma("unroll")                                                                 \
      for (int r = 0; r < 4; r++) qf[ct][r] = (c[r] + bb[r]) * QSCALE;                  \
    }                                                                                   \
    f32x4 oa0, oa1, oa2, oa3;                                                           \
    ATT_CT(Kp, Vp, qf, 0, oa0); ATT_CT(Kp, Vp, qf, 1, oa1);                             \
    ATT_CT(Kp, Vp, qf, 2, oa2); ATT_CT(Kp, Vp, qf, 3, oa3);                             \
    bf16x8 op0 = mkpair(oa0, oa1), op1 = mkpair(oa2, oa3);                              \
    f32x4 tpc[4];                                                                       \
    _Pragma("unroll")                                                                   \
    for (int ct = 0; ct < 4; ct++) {                                                    \
      f32x4 c = {0.f, 0.f, 0.f, 0.f};                                                   \
      c = MF(WSO[(ct * 2 + 0) * 64 + lane], op0, c);                                    \
      c = MF(WSO[(ct * 2 + 1) * 64 + lane], op1, c);                                    \
      f32x4 bb = ld4(self_out_b + 16 * ct + 4 * quad);                                  \
      _Pragma("unroll")                                                                 \
      for (int r = 0; r < 4; r++) {                                                     \
        float tp_ = c[r] + bb[r] + t[ct][r];                                            \
        tpc[ct][r] = tp_;                                                               \
        pool[ct][r] += vd ? tp_ : 0.f;                                                  \
      }                                                                                 \
    }                                                                                   \
    TP[S][0] = mkpair(tpc[0], tpc[1]); TP[S][1] = mkpair(tpc[2], tpc[3]);               \
  }

#define CKV_STAGE(S)                                                                    \
  {                                                                                     \
    f32x4 kt[4], vt[4];                                                                 \
    _Pragma("unroll")                                                                   \
    for (int ct = 0; ct < 4; ct++) {                                                    \
      f32x4 c = {0.f, 0.f, 0.f, 0.f};                                                   \
      c = MF(WCI[((4 + ct) * 2 + 0) * 64 + lane], TP[S][0], c);                         \
      c = MF(WCI[((4 + ct) * 2 + 1) * 64 + lane], TP[S][1], c);                         \
      f32x4 bb = ld4(cross_in_b + 64 + 16 * ct + 4 * quad);                             \
      _Pragma("unroll")                                                                 \
      for (int r = 0; r < 4; r++) kt[ct][r] = c[r] + bb[r];                             \
      f32x4 c2 = {0.f, 0.f, 0.f, 0.f};                                                  \
      c2 = MF(WCI[((8 + ct) * 2 + 0) * 64 + lane], TP[S][0], c2);                       \
      c2 = MF(WCI[((8 + ct) * 2 + 1) * 64 + lane], TP[S][1], c2);                       \
      f32x4 bb2 = ld4(cross_in_b + 128 + 16 * ct + 4 * quad);                           \
      _Pragma("unroll")                                                                 \
      for (int r = 0; r < 4; r++) vt[ct][r] = c2[r] + bb2[r];                           \
    }                                                                                   \
    Kc[S][0] = mkpair(kt[0], kt[1]); Kc[S][1] = mkpair(kt[2], kt[3]);                   \
    Vc[S][0] = mkpair(vt[0], vt[1]); Vc[S][1] = mkpair(vt[2], vt[3]);                   \
  }

#define FF_H2(CT, HD)                                                                   \
  { f32x4 c = {0.f, 0.f, 0.f, 0.f};                                                     \
    c = MF(W1[((CT) * 2 + 0) * 64 + lane], x0, c);                                      \
    c = MF(W1[((CT) * 2 + 1) * 64 + lane], x1, c);                                      \
    f32x4 bb = ld4(b1 + 16 * (CT) + 4 * quad);                                          \
    _Pragma("unroll")                                                                   \
    for (int r = 0; r < 4; r++) {                                                       \
      float v = c[r] + bb[r];                                                           \
      HD[r] = 0.5f * v * (1.0f + erff(v * 0.70710678118654752440f));                    \
    } }

#define FF_O(CT)                                                                        \
  { f32x4 c = {0.f, 0.f, 0.f, 0.f};                                                     \
    c = MF(W2[((CT) * 8 + 0) * 64 + lane], Hp0, c);                                     \
    c = MF(W2[((CT) * 8 + 1) * 64 + lane], Hp1, c);                                     \
    c = MF(W2[((CT) * 8 + 2) * 64 + lane], Hp2, c);                                     \
    c = MF(W2[((CT) * 8 + 3) * 64 + lane], Hp3, c);                                     \
    c = MF(W2[((CT) * 8 + 4) * 64 + lane], Hp4, c);                                     \
    c = MF(W2[((CT) * 8 + 5) * 64 + lane], Hp5, c);                                     \
    c = MF(W2[((CT) * 8 + 6) * 64 + lane], Hp6, c);                                     \
    c = MF(W2[((CT) * 8 + 7) * 64 + lane], Hp7, c);                                     \
    f32x4 bb = ld4(b2 + 16 * (CT) + 4 * quad);                                          \
    _Pragma("unroll")                                                                   \
    for (int r = 0; r < 4; r++) inst[CT][r] += c[r] + bb[r]; }

__device__ __forceinline__ void ffnT(f32x4 (&inst)[4],
                                     const float* __restrict__ g, const float* __restrict__ b,
                                     const bf16x8* __restrict__ W1, const bf16x8* __restrict__ W2,
                                     const float* __restrict__ b1, const float* __restrict__ b2,
                                     int lane, int quad) {
  f32x4 y[4];
  lnT(inst, y, g, b, quad);
  bf16x8 x0 = mkpair(y[0], y[1]), x1 = mkpair(y[2], y[3]);
  f32x4 ha, hb;
  FF_H2(0, ha);  FF_H2(1, hb);  bf16x8 Hp0 = mkpair(ha, hb);
  FF_H2(2, ha);  FF_H2(3, hb);  bf16x8 Hp1 = mkpair(ha, hb);
  FF_H2(4, ha);  FF_H2(5, hb);  bf16x8 Hp2 = mkpair(ha, hb);
  FF_H2(6, ha);  FF_H2(7, hb);  bf16x8 Hp3 = mkpair(ha, hb);
  FF_H2(8, ha);  FF_H2(9, hb);  bf16x8 Hp4 = mkpair(ha, hb);
  FF_H2(10, ha); FF_H2(11, hb); bf16x8 Hp5 = mkpair(ha, hb);
  FF_H2(12, ha); FF_H2(13, hb); bf16x8 Hp6 = mkpair(ha, hb);
  FF_H2(14, ha); FF_H2(15, hb); bf16x8 Hp7 = mkpair(ha, hb);
  FF_O(0); FF_O(1); FF_O(2); FF_O(3);
}

#define ASC(H)                                                                          \
  { float sp = 0.f;                                                                     \
    _Pragma("unroll")                                                                   \
    for (int ct = 0; ct < 4; ct++) {                                                    \
      f32x4 uu = ld4(uvec + (H) * 64 + 16 * ct + 4 * quad);                             \
      _Pragma("unroll")                                                                 \
      for (int r = 0; r < 4; r++) sp = fmaf(inst[ct][r], uu[r], sp);                    \
    }                                                                                   \
    sp = qsum(sp);                                                                      \
    a##H = sp > 0.f ? sp : 0.01f * sp; }

// ---------- per-edge transformer: one wave = 16 edges, fully register-resident ----------
__global__ __launch_bounds__(64, 1)
void edge_kernel(const float* __restrict__ features, const float* __restrict__ pos_emb,
                 const float* __restrict__ self_in_b, const float* __restrict__ self_out_b,
                 const float* __restrict__ cross_in_b, const float* __restrict__ cross_out_b,
                 const float* __restrict__ sa_ln1_g, const float* __restrict__ sa_ln1_b,
                 const float* __restrict__ sa_ln2_g, const float* __restrict__ sa_ln2_b,
                 const float* __restrict__ ca_ln1_g, const float* __restrict__ ca_ln1_b,
                 const float* __restrict__ ca_ln2_g, const float* __restrict__ ca_ln2_b,
                 const float* __restrict__ sa_ff_b1, const float* __restrict__ sa_ff_b2,
                 const float* __restrict__ ca_ff_b1, const float* __restrict__ ca_ff_b2,
                 const int* __restrict__ midx, const int* __restrict__ dstv,
                 const float* __restrict__ ws,
                 float* __restrict__ inst_out, float* __restrict__ a_out, int E, int N) {
  const int lane = threadIdx.x;
  const int quad = lane >> 4, lo = lane & 15;
  const int e0 = blockIdx.x * 16;
  __shared__ float xp[16 * 68];

  const ushort_t* bw = (const ushort_t*)(ws + 33280);
  const bf16x8* WSI = (const bf16x8*)(bw);
  const bf16x8* WSO = (const bf16x8*)(bw + 12288);
  const bf16x8* W1S = (const bf16x8*)(bw + 16384);
  const bf16x8* W2S = (const bf16x8*)(bw + 32768);
  const bf16x8* WCI = (const bf16x8*)(bw + 49152);
  const bf16x8* WCO = (const bf16x8*)(bw + 61440);
  const bf16x8* W1C = (const bf16x8*)(bw + 65536);
  const bf16x8* W2C = (const bf16x8*)(bw + 81920);
  const float* uvec = ws + 32768;

  const bool ge = (e0 + lo) < E;
  const int eIdx = min(e0 + lo, E - 1);
  int ids[5];
  ids[0] = midx[eIdx * 5 + 0];
  ids[1] = midx[eIdx * 5 + 1];
  ids[2] = midx[eIdx * 5 + 2];
  ids[3] = midx[eIdx * 5 + 3];
  ids[4] = midx[eIdx * 5 + 4];
  int vb = 0;
  if (ids[0] != N && ge) vb |= 1;
  if (ids[1] != N && ge) vb |= 2;
  if (ids[2] != N && ge) vb |= 4;
  if (ids[3] != N && ge) vb |= 8;
  if (ids[4] != N && ge) vb |= 16;
  const int nv = __popc(vb);
  const int lp = max(nv - 1, 0);
  int lid = ids[0];
  lid = (lp == 1) ? ids[1] : lid;
  lid = (lp == 2) ? ids[2] : lid;
  lid = (lp == 3) ? ids[3] : lid;
  lid = (lp == 4) ? ids[4] : lid;

  bf16x8 Kp[5][2], Vp[5][2];
  KV_STAGE(0); KV_STAGE(1); KV_STAGE(2); KV_STAGE(3); KV_STAGE(4);

  f32x4 pool[4];
#pragma unroll
  for (int ct = 0; ct < 4; ct++) pool[ct] = (f32x4){0.f, 0.f, 0.f, 0.f};
  bf16x8 TP[5][2];
  Q_STAGE(0); Q_STAGE(1); Q_STAGE(2); Q_STAGE(3); Q_STAGE(4);

  f32x4 inst[4];
  {
    float rn = 1.0f / (float)max(nv, 1);
#pragma unroll
    for (int ct = 0; ct < 4; ct++)
#pragma unroll
      for (int r = 0; r < 4; r++) inst[ct][r] = pool[ct][r] * rn;
  }

  ffnT(inst, sa_ln2_g, sa_ln2_b, W1S, W2S, sa_ff_b1, sa_ff_b2, lane, quad);

  {
    f32x4 tf[4], xq[4];
    const bool vdl = lid != N;
    const float* fp = features + (size_t)min(lid, N - 1) * 64;
#pragma unroll
    for (int ct = 0; ct < 4; ct++) {
      f32x4 f = ld4(fp + 16 * ct + 4 * quad);
#pragma unroll
      for (int r = 0; r < 4; r++) tf[ct][r] = vdl ? f[r] : 0.f;
    }
    lnT(tf, xq, ca_ln1_g, ca_ln1_b, quad);
    bf16x8 xq0 = mkpair(xq[0], xq[1]), xq1 = mkpair(xq[2], xq[3]);
    f32x4 qcf[4];
#pragma unroll
    for (int ct = 0; ct < 4; ct++) {
      f32x4 c = {0.f, 0.f, 0.f, 0.f};
      c = MF(WCI[(ct * 2 + 0) * 64 + lane], xq0, c);
      c = MF(WCI[(ct * 2 + 1) * 64 + lane], xq1, c);
      f32x4 bb = ld4(cross_in_b + 16 * ct + 4 * quad);
#pragma unroll
      for (int r = 0; r < 4; r++) qcf[ct][r] = (c[r] + bb[r]) * QSCALE;
    }
    bf16x8 Kc[5][2], Vc[5][2];
    CKV_STAGE(0); CKV_STAGE(1); CKV_STAGE(2); CKV_STAGE(3); CKV_STAGE(4);
    f32x4 cc0, cc1, cc2, cc3;
    ATT_CT(Kc, Vc, qcf, 0, cc0); ATT_CT(Kc, Vc, qcf, 1, cc1);
    ATT_CT(Kc, Vc, qcf, 2, cc2); ATT_CT(Kc, Vc, qcf, 3, cc3);
    bf16x8 cp0 = mkpair(cc0, cc1), cp1 = mkpair(cc2, cc3);
#pragma unroll
    for (int ct = 0; ct < 4; ct++) {
      f32x4 c = {0.f, 0.f, 0.f, 0.f};
      c = MF(WCO[(ct * 2 + 0) * 64 + lane], cp0, c);
      c = MF(WCO[(ct * 2 + 1) * 64 + lane], cp1, c);
      f32x4 bb = ld4(cross_out_b + 16 * ct + 4 * quad);
#pragma unroll
      for (int r = 0; r < 4; r++) inst[ct][r] += c[r] + bb[r];
    }
  }

  ffnT(inst, ca_ln2_g, ca_ln2_b, W1C, W2C, ca_ff_b1, ca_ff_b2, lane, quad);

  float a0, a1, a2, a3, a4, a5, a6, a7;
  ASC(0); ASC(1); ASC(2); ASC(3); ASC(4); ASC(5); ASC(6); ASC(7);
  if (ge && quad < 2) {
    f32x4 st = (quad == 0) ? (f32x4){a0, a1, a2, a3} : (f32x4){a4, a5, a6, a7};
    *(f32x4*)(a_out + (size_t)(e0 + lo) * 8 + 4 * quad) = st;
  }

#pragma unroll
  for (int ct = 0; ct < 4; ct++)
    *(f32x4*)(&xp[lo * 68 + 16 * ct + 4 * quad]) = inst[ct];
  __syncthreads();
  {
    int er = lane >> 2, cb = (lane & 3) * 16;
    if (e0 + er < E) {
#pragma unroll
      for (int u = 0; u < 4; u++) {
        f32x4 v = *(const f32x4*)(&xp[er * 68 + cb + 4 * u]);
        *(f32x4*)(inst_out + (size_t)(e0 + er) * 64 + cb + 4 * u) = v;
      }
    }
  }
}

// ================== CSR-by-dst build ==================
__global__ void csr_count_kernel(const int* __restrict__ dstv, unsigned int* __restrict__ cnt,
                                 int E) {
  int e = blockIdx.x * blockDim.x + threadIdx.x;
  if (e < E) atomicAdd(&cnt[dstv[e]], 1u);
}

__global__ void scan1_kernel(unsigned int* __restrict__ off, unsigned int* __restrict__ bsum,
                             int N) {
  __shared__ unsigned int sd[256];
  int t = threadIdx.x, n = blockIdx.x * 256 + t;
  unsigned int v = (n < N) ? off[n] : 0u;
  sd[t] = v;
  __syncthreads();
  for (int o = 1; o < 256; o <<= 1) {
    unsigned int x = (t >= o) ? sd[t - o] : 0u;
    __syncthreads();
    sd[t] += x;
    __syncthreads();
  }
  if (n < N) off[n] = sd[t] - v;  // local exclusive
  if (t == 255) bsum[blockIdx.x] = sd[255];
}

__global__ void scan2_kernel(unsigned int* __restrict__ bsum, int nb) {
  __shared__ unsigned int sd[1024];
  int t = threadIdx.x;
  unsigned int v = (t < nb) ? bsum[t] : 0u;
  sd[t] = v;
  __syncthreads();
  for (int o = 1; o < 1024; o <<= 1) {
    unsigned int x = (t >= o) ? sd[t - o] : 0u;
    __syncthreads();
    sd[t] += x;
    __syncthreads();
  }
  if (t < nb) bsum[t] = sd[t] - v;  // exclusive
}

__global__ void scan3_kernel(unsigned int* __restrict__ off, unsigned int* __restrict__ cur,
                             const unsigned int* __restrict__ bsum, int N, int E) {
  int n = blockIdx.x * 256 + threadIdx.x;
  if (n < N) {
    unsigned int o = off[n] + bsum[blockIdx.x];
    off[n] = o;
    cur[n] = o;
  }
  if (n == 0) off[N] = (unsigned int)E;
}

__global__ void csr_fill_kernel(const int* __restrict__ dstv, unsigned int* __restrict__ cur,
                                unsigned int* __restrict__ elist, int E) {
  int e = blockIdx.x * blockDim.x + threadIdx.x;
  if (e < E) {
    unsigned int p = atomicAdd(&cur[dstv[e]], 1u);
    elist[p] = (unsigned int)e;
  }
}

// ================== per-node edge-softmax: a[e][0..7] -> unnormalized w, sinv[n][0..7]=1/s ==================
// Thread per node; segment loop runs 2 passes total (v1 gather ran 16: 8 h-blocks x 2).
// In-place overwrite of a is safe: each edge belongs to exactly one dst segment.
__global__ __launch_bounds__(256)
void att_kernel(const unsigned int* __restrict__ off, const unsigned int* __restrict__ elist,
                float* __restrict__ a, float* __restrict__ sinv, int N) {
  int n = blockIdx.x * blockDim.x + threadIdx.x;
  if (n >= N) return;
  const unsigned int s0 = off[n], s1 = off[n + 1];
  f32x4 m0 = {-3.0e38f, -3.0e38f, -3.0e38f, -3.0e38f}, m1 = m0;
  for (unsigned int i = s0; i < s1; i++) {
    const float* ap = a + (size_t)elist[i] * 8;
    f32x4 x0 = ld4(ap), x1 = ld4(ap + 4);
#pragma unroll
    for (int r = 0; r < 4; r++) { m0[r] = fmaxf(m0[r], x0[r]); m1[r] = fmaxf(m1[r], x1[r]); }
  }
  f32x4 t0 = {0.f, 0.f, 0.f, 0.f}, t1 = t0;
  for (unsigned int i = s0; i < s1; i++) {
    float* ap = a + (size_t)elist[i] * 8;
    f32x4 x0 = ld4(ap), x1 = ld4(ap + 4);
    f32x4 w0, w1;
#pragma unroll
    for (int r = 0; r < 4; r++) {
      w0[r] = __expf(x0[r] - m0[r]);
      w1[r] = __expf(x1[r] - m1[r]);
      t0[r] += w0[r];
      t1[r] += w1[r];
    }
    *(f32x4*)ap = w0;
    *(f32x4*)(ap + 4) = w1;
  }
  f32x4 r0, r1;
#pragma unroll
  for (int r = 0; r < 4; r++) {
    r0[r] = (t0[r] > 0.f) ? 1.0f / t0[r] : 0.f;
    r1[r] = (t1[r] > 0.f) ? 1.0f / t1[r] : 0.f;
  }
  *(f32x4*)(sinv + (size_t)n * 8) = r0;
  *(f32x4*)(sinv + (size_t)n * 8 + 4) = r1;
}

// ================== fused gather: per (h, node) weighted sum + head transform ==================
// Single segment pass (w precomputed by att_kernel); W_h held in 64 VGPRs per wave,
// amortized over ~N/1024 nodes. Writes every (n,h) row -> no pre-zero of out needed.
__global__ __launch_bounds__(256)
void gather_kernel(const float* __restrict__ T_iw, const unsigned int* __restrict__ off,
                   const unsigned int* __restrict__ elist, const float* __restrict__ a,
                   const float* __restrict__ sinv, const float* __restrict__ inst_emb,
                   float* __restrict__ out, int N) {
  const int lane = threadIdx.x & 63;
  const int widx = threadIdx.x >> 6;
  const int h = blockIdx.y;
  const vf4* P = (const vf4*)T_iw;
  vf4 wr[16];
#pragma unroll
  for (int k = 0; k < 16; k++) wr[k] = P[k * 512 + h * 64 + lane];  // W_h[lane][4k..4k+3]
  const int stride = gridDim.x * 4;
  for (int n = blockIdx.x * 4 + widx; n < N; n += stride) {
    const unsigned int s0 = off[n], s1 = off[n + 1];
    float z = 0.f;
    for (unsigned int i = s0; i < s1; i++) {
      unsigned int e = elist[i];
      z = fmaf(a[(size_t)e * 8 + h], inst_emb[(size_t)e * 64 + lane], z);
    }
    z *= sinv[(size_t)n * 8 + h];
    float o = 0.f;
#pragma unroll
    for (int k = 0; k < 16; k++) {
#pragma unroll
      for (int u = 0; u < 4; u++) o = fmaf(bcast(z, k * 4 + u), wr[k][u], o);
    }
    out[(size_t)n * 512 + h * 64 + lane] = o;
  }
}

extern "C" void kernel_launch(void* const* d_in, const int* in_sizes, int n_in,
                              void* d_out, int out_size, void* d_ws, size_t ws_size,
                              hipStream_t stream) {
  const float* features   = (const float*)d_in[0];
  const float* pos_emb    = (const float*)d_in[1];
  const float* self_in_w  = (const float*)d_in[2];
  const float* self_in_b  = (const float*)d_in[3];
  const float* self_out_w = (const float*)d_in[4];
  const float* self_out_b = (const float*)d_in[5];
  const float* cross_in_w = (const float*)d_in[6];
  const float* cross_in_b = (const float*)d_in[7];
  const float* cross_out_w= (const float*)d_in[8];
  const float* cross_out_b= (const float*)d_in[9];
  const float* sa_ln1_g = (const float*)d_in[10];
  const float* sa_ln1_b = (const float*)d_in[11];
  const float* sa_ln2_g = (const float*)d_in[12];
  const float* sa_ln2_b = (const float*)d_in[13];
  const float* ca_ln1_g = (const float*)d_in[14];
  const float* ca_ln1_b = (const float*)d_in[15];
  const float* ca_ln2_g = (const float*)d_in[16];
  const float* ca_ln2_b = (const float*)d_in[17];
  const float* sa_ff_w1 = (const float*)d_in[18];
  const float* sa_ff_b1 = (const float*)d_in[19];
  const float* sa_ff_w2 = (const float*)d_in[20];
  const float* sa_ff_b2 = (const float*)d_in[21];
  const float* ca_ff_w1 = (const float*)d_in[22];
  const float* ca_ff_b1 = (const float*)d_in[23];
  const float* ca_ff_w2 = (const float*)d_in[24];
  const float* ca_ff_b2 = (const float*)d_in[25];
  const float* inst_w   = (const float*)d_in[26];
  const float* attn_vec = (const float*)d_in[27];
  const int* midx = (const int*)d_in[28];
  const int* dstv = (const int*)d_in[29];

  const int N = in_sizes[0] / 64;
  const int E = in_sizes[29];

  // ws floats: [0..32767] T_iw | [32768..33279] u | [33280..82431] bf16 A-frag packs
  //            [131072...] inst_emb[E*64] | a[E*8] | off[N+1] | cur[N] | bsum[1024]
  //            | elist[E] | sinv[N*8]
  float* wsf = (float*)d_ws;
  float* inst_emb = wsf + 131072;
  float* a_arr = inst_emb + (size_t)E * 64;
  unsigned int* off = (unsigned int*)(a_arr + (size_t)E * 8);
  unsigned int* cur = off + (size_t)(N + 1);
  unsigned int* bsum = cur + (size_t)N;
  unsigned int* elist = bsum + 1024;
  float* sinv = (float*)(elist + (size_t)E);

  const int nb1 = (N + 255) / 256;

  {
    // zero off (= cnt) region; rounding up into cur is harmless (cur set in scan3)
    int n4 = (N + 1 + 3) / 4;
    zero_kernel<<<(n4 + 255) / 256, 256, 0, stream>>>((float4*)off, n4);
  }

  prep_kernel<<<(131584 + 255) / 256, 256, 0, stream>>>(
      self_in_w, self_out_w, sa_ff_w1, sa_ff_w2, cross_in_w, cross_out_w, ca_ff_w1, ca_ff_w2,
      inst_w, attn_vec, wsf);

  // CSR build (independent of edge_kernel results)
  csr_count_kernel<<<(E + 255) / 256, 256, 0, stream>>>(dstv, off, E);
  scan1_kernel<<<nb1, 256, 0, stream>>>(off, bsum, N);
  scan2_kernel<<<1, 1024, 0, stream>>>(bsum, nb1);
  scan3_kernel<<<nb1, 256, 0, stream>>>(off, cur, bsum, N, E);
  csr_fill_kernel<<<(E + 255) / 256, 256, 0, stream>>>(dstv, cur, elist, E);

  int nblk = (E + 15) / 16;  // 1 wave/block, 16 edges/wave
  edge_kernel<<<nblk, 64, 0, stream>>>(
      features, pos_emb, self_in_b, self_out_b, cross_in_b, cross_out_b, sa_ln1_g, sa_ln1_b,
      sa_ln2_g, sa_ln2_b, ca_ln1_g, ca_ln1_b, ca_ln2_g, ca_ln2_b, sa_ff_b1, sa_ff_b2, ca_ff_b1,
      ca_ff_b2, midx, dstv, wsf, inst_emb, a_arr, E, N);

  att_kernel<<<nb1, 256, 0, stream>>>(off, elist, a_arr, sinv, N);

  dim3 ggrid(256, 8);
  gather_kernel<<<ggrid, 256, 0, stream>>>(wsf, off, elist, a_arr, sinv, inst_emb,
                                           (float*)d_out, N);
}